// Round 1
// baseline (4047.868 us; speedup 1.0000x reference)
//
#include <hip/hip_runtime.h>
#include <hip/hip_bf16.h>
#include <math.h>

// ---------------- problem constants ----------------
constexpr int B    = 8;
constexpr int NPG  = 10000;           // nodes per graph (stage 1)
constexpr int F    = 128;             // feature dim (F_IN == H == 128)
constexpr int OUTD = 64;
constexpr int E    = B * NPG * 16;    // 1,280,000 edges
constexpr int N0   = B * NPG;         // 80000
constexpr int K1   = 5000, K2 = 2500, K3 = 1250;
constexpr int N1   = B * K1;          // 40000
constexpr int N2   = B * K2;          // 20000
constexpr int N3   = B * K3;          // 10000
constexpr int SPLIT = 16;             // summarize row-split

// ---------------- ws layout (float units) ----------------
constexpr size_t OFF_A    = 0;                          // 80000*128 (agg -> h in place; also x3/agg3/x4 sub-regions)
constexpr size_t SZ_A     = (size_t)N0 * F;
constexpr size_t OFF_X2   = OFF_A + SZ_A;               // 40000*128
constexpr size_t SZ_X2    = (size_t)N1 * F;
constexpr size_t OFF_DEG  = OFF_X2 + SZ_X2;             // 80000
constexpr size_t OFF_SC   = OFF_DEG + N0;               // 80000
constexpr size_t OFF_KEY  = OFF_SC + N0;                // 80000 (u32)
constexpr size_t OFF_MAP  = OFF_KEY + N0;               // 80000 (i32)
constexpr size_t OFF_SEL  = OFF_MAP + N0;               // 40000 (i32)
constexpr size_t OFF_VAL  = OFF_SEL + N1;               // 40000
constexpr size_t OFF_E2S  = OFF_VAL + N1;               // E (i32)
constexpr size_t OFF_E2D  = OFF_E2S + E;
constexpr size_t OFF_E3S  = OFF_E2D + E;
constexpr size_t OFF_E3D  = OFF_E3S + E;
constexpr size_t OFF_PART = OFF_E3D + E;                // B*SPLIT*2*128
constexpr size_t OFF_SUM  = OFF_PART + (size_t)B * SPLIT * 2 * F;  // 2048
constexpr size_t OFF_MISC = OFF_SUM + (size_t)B * 2 * F;
// misc ints/floats: [0..2] edge counts, [4..11] kth keys, [12..19] eq_needed, [20] norm

// ---------------- helpers ----------------
__device__ inline unsigned f2key(float f) {
    unsigned u = __float_as_uint(f);
    return (u & 0x80000000u) ? ~u : (u | 0x80000000u);
}

// ---------------- kernels ----------------
__global__ void k_init(float* summary, int* cnts) {
    int t = blockIdx.x * blockDim.x + threadIdx.x;
    if (t < B * 2 * F) summary[t] = 0.0f;
    if (t == 0) { cnts[0] = E; cnts[1] = 0; cnts[2] = 0; }
}

__global__ void k_zero(float* p, long n4) {
    long t = blockIdx.x * (long)blockDim.x + threadIdx.x;
    if (t < n4) ((float4*)p)[t] = make_float4(0, 0, 0, 0);
}

__global__ void k_norm(const float* __restrict__ w, float* out) {
    int t = threadIdx.x;               // 64 threads
    float v = 0.0f;
    for (int j = t; j < F; j += 64) { float a = w[j]; v += a * a; }
    for (int o = 32; o > 0; o >>= 1) v += __shfl_down(v, o);
    if (t == 0) *out = sqrtf(v);
}

// edge-parallel scatter-add: 32 threads per edge, float4 each
__global__ __launch_bounds__(256) void k_aggregate(
    const float* __restrict__ x, const int* __restrict__ src,
    const int* __restrict__ dst, const int* __restrict__ ecnt, int emax,
    float* __restrict__ agg, float* __restrict__ deg) {
    long tid = blockIdx.x * (long)blockDim.x + threadIdx.x;
    int e = (int)(tid >> 5), lane = (int)(tid & 31);
    if (e >= emax) return;
    int cnt = *ecnt;
    if (e >= cnt) return;
    int s = src[e], d = dst[e];
    float4 v = ((const float4*)(x + (size_t)s * F))[lane];
    float* ad = agg + (size_t)d * F + lane * 4;
    atomicAdd(ad + 0, v.x);
    atomicAdd(ad + 1, v.y);
    atomicAdd(ad + 2, v.z);
    atomicAdd(ad + 3, v.w);
    if (lane == 0) atomicAdd(&deg[d], 1.0f);
}

// h[i,:] = (agg[i,:]/max(deg,1)) @ Wl^T + x[i,:] @ Wr^T + bl   (optional relu)
// 64-row x 128-col tile, K-tiles of 32, K-major LDS. h may alias agg (in-place).
__global__ __launch_bounds__(256) void k_sage(
    const float* __restrict__ x, const float* __restrict__ agg,
    const float* __restrict__ deg, const float* __restrict__ Wl,
    const float* __restrict__ bl, const float* __restrict__ Wr,
    float* __restrict__ h, int n, int relu) {
    __shared__ float xs[32][68];
    __shared__ float as_[32][68];
    __shared__ float wls[32][132];
    __shared__ float wrs[32][132];
    int tid = threadIdx.x;
    int tx = tid & 31, ty = tid >> 5;
    int row0 = blockIdx.x * 64;
    float acc[8][4];
#pragma unroll
    for (int r = 0; r < 8; r++)
#pragma unroll
        for (int c = 0; c < 4; c++) acc[r][c] = 0.0f;

    for (int kt = 0; kt < 4; kt++) {
        int k0 = kt * 32;
#pragma unroll
        for (int l = 0; l < 2; l++) {        // x/agg tiles: 64 rows x 32 k
            int idx = l * 256 + tid;         // 0..511
            int row = idx >> 3, j = idx & 7;
            int grow = row0 + row;
            float4 xv = make_float4(0, 0, 0, 0), av = make_float4(0, 0, 0, 0);
            if (grow < n) {
                xv = *(const float4*)(x + (size_t)grow * F + k0 + j * 4);
                av = *(const float4*)(agg + (size_t)grow * F + k0 + j * 4);
                float rd = 1.0f / fmaxf(deg[grow], 1.0f);
                av.x *= rd; av.y *= rd; av.z *= rd; av.w *= rd;
            }
            xs[j * 4 + 0][row] = xv.x; xs[j * 4 + 1][row] = xv.y;
            xs[j * 4 + 2][row] = xv.z; xs[j * 4 + 3][row] = xv.w;
            as_[j * 4 + 0][row] = av.x; as_[j * 4 + 1][row] = av.y;
            as_[j * 4 + 2][row] = av.z; as_[j * 4 + 3][row] = av.w;
        }
#pragma unroll
        for (int l = 0; l < 4; l++) {        // W tiles: 128 cols x 32 k
            int idx = l * 256 + tid;         // 0..1023
            int col = idx >> 3, j = idx & 7;
            float4 wv = *(const float4*)(Wl + (size_t)col * F + k0 + j * 4);
            float4 uv = *(const float4*)(Wr + (size_t)col * F + k0 + j * 4);
            wls[j * 4 + 0][col] = wv.x; wls[j * 4 + 1][col] = wv.y;
            wls[j * 4 + 2][col] = wv.z; wls[j * 4 + 3][col] = wv.w;
            wrs[j * 4 + 0][col] = uv.x; wrs[j * 4 + 1][col] = uv.y;
            wrs[j * 4 + 2][col] = uv.z; wrs[j * 4 + 3][col] = uv.w;
        }
        __syncthreads();
#pragma unroll
        for (int kk = 0; kk < 32; kk++) {
            float4 xlo = *(const float4*)&xs[kk][ty * 8];
            float4 xhi = *(const float4*)&xs[kk][ty * 8 + 4];
            float4 alo = *(const float4*)&as_[kk][ty * 8];
            float4 ahi = *(const float4*)&as_[kk][ty * 8 + 4];
            float4 wl4 = *(const float4*)&wls[kk][tx * 4];
            float4 wr4 = *(const float4*)&wrs[kk][tx * 4];
            float xv[8] = {xlo.x, xlo.y, xlo.z, xlo.w, xhi.x, xhi.y, xhi.z, xhi.w};
            float av[8] = {alo.x, alo.y, alo.z, alo.w, ahi.x, ahi.y, ahi.z, ahi.w};
            float wlv[4] = {wl4.x, wl4.y, wl4.z, wl4.w};
            float wrv[4] = {wr4.x, wr4.y, wr4.z, wr4.w};
#pragma unroll
            for (int r = 0; r < 8; r++)
#pragma unroll
                for (int c = 0; c < 4; c++)
                    acc[r][c] += av[r] * wlv[c] + xv[r] * wrv[c];
        }
        __syncthreads();
    }
    float4 bv = *(const float4*)(bl + tx * 4);
    float blv[4] = {bv.x, bv.y, bv.z, bv.w};
#pragma unroll
    for (int r = 0; r < 8; r++) {
        int grow = row0 + ty * 8 + r;
        if (grow < n) {
            float4 o;
            o.x = acc[r][0] + blv[0]; o.y = acc[r][1] + blv[1];
            o.z = acc[r][2] + blv[2]; o.w = acc[r][3] + blv[3];
            if (relu) {
                o.x = fmaxf(o.x, 0.f); o.y = fmaxf(o.y, 0.f);
                o.z = fmaxf(o.z, 0.f); o.w = fmaxf(o.w, 0.f);
            }
            *(float4*)(h + (size_t)grow * F + tx * 4) = o;
        }
    }
}

__global__ void k_scores(const float* __restrict__ h, const float* __restrict__ w,
                         const float* __restrict__ norm, float* __restrict__ sc,
                         unsigned* __restrict__ key, int n) {
    int i = blockIdx.x * blockDim.x + threadIdx.x;
    if (i >= n) return;
    float nv = *norm;
    const float4* hr = (const float4*)(h + (size_t)i * F);
    const float4* wr = (const float4*)w;
    float acc = 0.0f;
#pragma unroll
    for (int j = 0; j < F / 4; j++) {
        float4 a = hr[j], b = wr[j];
        acc += a.x * b.x + a.y * b.y + a.z * b.z + a.w * b.w;
    }
    float s = tanhf(acc / nv);
    sc[i] = s;
    key[i] = f2key(s);
}

// per-graph 4-pass radix select: kth largest key + #equal-needed
__global__ __launch_bounds__(256) void k_select(const unsigned* __restrict__ keys,
                                                int n_per, int k,
                                                unsigned* kth_out, int* eqneed_out) {
    int g = blockIdx.x;
    const unsigned* kk = keys + (size_t)g * n_per;
    __shared__ int hist[256];
    __shared__ unsigned sprefix;
    __shared__ int sr;
    if (threadIdx.x == 0) { sprefix = 0; sr = k; }
    for (int b = 3; b >= 0; b--) {
        for (int i = threadIdx.x; i < 256; i += blockDim.x) hist[i] = 0;
        __syncthreads();
        unsigned pfx = sprefix;
        unsigned maskhi = (b == 3) ? 0u : (0xFFFFFFFFu << ((b + 1) * 8));
        for (int i = threadIdx.x; i < n_per; i += blockDim.x) {
            unsigned key = kk[i];
            if ((key & maskhi) == (pfx & maskhi))
                atomicAdd(&hist[(key >> (b * 8)) & 255], 1);
        }
        __syncthreads();
        if (threadIdx.x == 0) {
            int r = sr, c = 0, v = 255;
            for (; v > 0; v--) { if (c + hist[v] >= r) break; c += hist[v]; }
            sr = r - c;
            sprefix = pfx | ((unsigned)v << (b * 8));
        }
        __syncthreads();
    }
    if (threadIdx.x == 0) { kth_out[g] = sprefix; eqneed_out[g] = sr; }
}

// deterministic index-order compaction of the selected set (ties: lower index first)
__global__ __launch_bounds__(256) void k_compact(
    const unsigned* __restrict__ keys, const float* __restrict__ sc,
    int n_per, int k, const unsigned* __restrict__ kth, const int* __restrict__ eqneed,
    int* __restrict__ node_map, int* __restrict__ sel_old, float* __restrict__ vals) {
    int g = blockIdx.x, tid = threadIdx.x;
    const unsigned* kk = keys + (size_t)g * n_per;
    const float* ss = sc + (size_t)g * n_per;
    unsigned K = kth[g];
    int need = eqneed[g];
    __shared__ int s1[256], s2[256];
    __shared__ int carry_pos, carry_eq;
    if (tid == 0) { carry_pos = 0; carry_eq = 0; }
    __syncthreads();
    int nchunks = (n_per + 255) / 256;
    for (int ch = 0; ch < nchunks; ch++) {
        int i = ch * 256 + tid;
        int is_eq = 0, is_gt = 0;
        if (i < n_per) {
            unsigned key = kk[i];
            is_gt = key > K;
            is_eq = key == K;
        }
        s1[tid] = is_eq;
        __syncthreads();
        for (int off = 1; off < 256; off <<= 1) {
            int v = s1[tid] + ((tid >= off) ? s1[tid - off] : 0);
            __syncthreads();
            s1[tid] = v;
            __syncthreads();
        }
        int eq_excl = s1[tid] - is_eq;
        int sel = is_gt || (is_eq && (carry_eq + eq_excl) < need);
        s2[tid] = sel;
        __syncthreads();
        for (int off = 1; off < 256; off <<= 1) {
            int v = s2[tid] + ((tid >= off) ? s2[tid - off] : 0);
            __syncthreads();
            s2[tid] = v;
            __syncthreads();
        }
        int pos = carry_pos + s2[tid] - sel;
        if (i < n_per) {
            if (sel) {
                int ni = g * k + pos;
                node_map[(size_t)g * n_per + i] = ni;
                sel_old[ni] = g * n_per + i;
                vals[ni] = ss[i];
            } else {
                node_map[(size_t)g * n_per + i] = -1;
            }
        }
        __syncthreads();
        if (tid == 0) { carry_pos += s2[255]; carry_eq += s1[255]; }
        __syncthreads();
    }
}

__global__ void k_gather(const float* __restrict__ h, const int* __restrict__ sel_old,
                         const float* __restrict__ vals, float* __restrict__ xout, int m) {
    long t = blockIdx.x * (long)blockDim.x + threadIdx.x;
    int i = (int)(t >> 5), lane = (int)(t & 31);
    if (i >= m) return;
    int oi = sel_old[i];
    float v = vals[i];
    float4 r = ((const float4*)(h + (size_t)oi * F))[lane];
    r.x *= v; r.y *= v; r.z *= v; r.w *= v;
    ((float4*)(xout + (size_t)i * F))[lane] = r;
}

__global__ void k_partial(const float* __restrict__ x, int k, float* __restrict__ part) {
    int g = blockIdx.x / SPLIT, s = blockIdx.x % SPLIT;
    int f = threadIdx.x;                 // 128 threads
    int rows = (k + SPLIT - 1) / SPLIT;
    int r0 = s * rows, r1 = min(k, r0 + rows);
    float sum = 0.0f, mx = -INFINITY;
    for (int r = r0; r < r1; r++) {
        float v = x[((size_t)(g * k + r)) * F + f];
        sum += v;
        mx = fmaxf(mx, v);
    }
    part[((size_t)(g * SPLIT + s) * 2 + 0) * F + f] = sum;
    part[((size_t)(g * SPLIT + s) * 2 + 1) * F + f] = mx;
}

__global__ void k_sumreduce(const float* __restrict__ part, int k, float* __restrict__ summary) {
    int g = blockIdx.x, f = threadIdx.x; // 128 threads
    float sum = 0.0f, mx = -INFINITY;
    for (int s = 0; s < SPLIT; s++) {
        sum += part[((size_t)(g * SPLIT + s) * 2 + 0) * F + f];
        mx = fmaxf(mx, part[((size_t)(g * SPLIT + s) * 2 + 1) * F + f]);
    }
    summary[g * 2 * F + f] += sum / (float)k;
    summary[g * 2 * F + F + f] += mx;
}

__global__ void k_remap(const int* __restrict__ src, const int* __restrict__ dst,
                        const int* __restrict__ cnt_in, int emax,
                        const int* __restrict__ node_map,
                        int* __restrict__ nsrc, int* __restrict__ ndst,
                        int* __restrict__ cnt_out) {
    int e = blockIdx.x * blockDim.x + threadIdx.x;
    if (e >= emax) return;
    if (e >= *cnt_in) return;
    int a = node_map[src[e]], b = node_map[dst[e]];
    if (a >= 0 && b >= 0) {
        int p = atomicAdd(cnt_out, 1);
        nsrc[p] = a;
        ndst[p] = b;
    }
}

__global__ void k_out(const float* __restrict__ summary, const float* __restrict__ W,
                      const float* __restrict__ bias, float* __restrict__ out) {
    int g = blockIdx.x, j = threadIdx.x;  // 8 blocks x 64 threads
    float acc = bias[j];
    for (int t = 0; t < 2 * F; t++) acc += summary[g * 2 * F + t] * W[j * 2 * F + t];
    out[g * OUTD + j] = acc;
}

// ---------------- host launch ----------------
static inline int cdiv(long a, long b) { return (int)((a + b - 1) / b); }

extern "C" void kernel_launch(void* const* d_in, const int* in_sizes, int n_in,
                              void* d_out, int out_size, void* d_ws, size_t ws_size,
                              hipStream_t stream) {
    const float* x_in = (const float*)d_in[0];
    const int* ei     = (const int*)d_in[1];    // [2, E] -> src = ei, dst = ei+E
    const float* w1lW = (const float*)d_in[2];
    const float* w1lb = (const float*)d_in[3];
    const float* w1rW = (const float*)d_in[4];
    const float* p1w  = (const float*)d_in[5];
    const float* w2lW = (const float*)d_in[6];
    const float* w2lb = (const float*)d_in[7];
    const float* w2rW = (const float*)d_in[8];
    const float* p2w  = (const float*)d_in[9];
    const float* w3lW = (const float*)d_in[10];
    const float* w3lb = (const float*)d_in[11];
    const float* w3rW = (const float*)d_in[12];
    const float* p3w  = (const float*)d_in[13];
    const float* outW = (const float*)d_in[14];
    const float* outb = (const float*)d_in[15];
    float* out = (float*)d_out;

    float* ws = (float*)d_ws;
    float* bufA  = ws + OFF_A;
    float* bufX2 = ws + OFF_X2;
    float* deg   = ws + OFF_DEG;
    float* sc    = ws + OFF_SC;
    unsigned* key = (unsigned*)(ws + OFF_KEY);
    int* nmap    = (int*)(ws + OFF_MAP);
    int* selo    = (int*)(ws + OFF_SEL);
    float* vals  = ws + OFF_VAL;
    int* e2s = (int*)(ws + OFF_E2S);
    int* e2d = (int*)(ws + OFF_E2D);
    int* e3s = (int*)(ws + OFF_E3S);
    int* e3d = (int*)(ws + OFF_E3D);
    float* part    = ws + OFF_PART;
    float* summary = ws + OFF_SUM;
    int* misc_i    = (int*)(ws + OFF_MISC);
    int* cnt_e1 = misc_i + 0;
    int* cnt_e2 = misc_i + 1;
    int* cnt_e3 = misc_i + 2;
    unsigned* kth = (unsigned*)(misc_i + 4);
    int* eqneed   = misc_i + 12;
    float* normv  = (float*)(misc_i + 20);

    float* x3   = bufA + (size_t)N1 * F;   // 20000x128 region
    float* agg3 = bufA + (size_t)(N1 + N2) * F;
    float* x4   = bufA;                    // 10000x128 region (h2 dead by then)

    const int edge_grid = cdiv((long)E * 32, 256);

    k_init<<<8, 256, 0, stream>>>(summary, misc_i);

    // ================= stage 1 =================
    k_zero<<<cdiv((long)N0 * F / 4, 256), 256, 0, stream>>>(bufA, (long)N0 * F / 4);
    k_zero<<<cdiv((long)N0 / 4, 256), 256, 0, stream>>>(deg, (long)N0 / 4);
    k_norm<<<1, 64, 0, stream>>>(p1w, normv);
    k_aggregate<<<edge_grid, 256, 0, stream>>>(x_in, ei, ei + E, cnt_e1, E, bufA, deg);
    k_sage<<<cdiv(N0, 64), 256, 0, stream>>>(x_in, bufA, deg, w1lW, w1lb, w1rW, bufA, N0, 0);
    k_scores<<<cdiv(N0, 256), 256, 0, stream>>>(bufA, p1w, normv, sc, key, N0);
    k_select<<<B, 256, 0, stream>>>(key, NPG, K1, kth, eqneed);
    k_compact<<<B, 256, 0, stream>>>(key, sc, NPG, K1, kth, eqneed, nmap, selo, vals);
    k_gather<<<cdiv((long)N1 * 32, 256), 256, 0, stream>>>(bufA, selo, vals, bufX2, N1);
    k_partial<<<B * SPLIT, F, 0, stream>>>(bufX2, K1, part);
    k_sumreduce<<<B, F, 0, stream>>>(part, K1, summary);
    k_remap<<<cdiv(E, 256), 256, 0, stream>>>(ei, ei + E, cnt_e1, E, nmap, e2s, e2d, cnt_e2);

    // ================= stage 2 =================
    k_zero<<<cdiv((long)N1 * F / 4, 256), 256, 0, stream>>>(bufA, (long)N1 * F / 4);
    k_zero<<<cdiv((long)N1 / 4, 256), 256, 0, stream>>>(deg, (long)N1 / 4);
    k_norm<<<1, 64, 0, stream>>>(p2w, normv);
    k_aggregate<<<edge_grid, 256, 0, stream>>>(bufX2, e2s, e2d, cnt_e2, E, bufA, deg);
    k_sage<<<cdiv(N1, 64), 256, 0, stream>>>(bufX2, bufA, deg, w2lW, w2lb, w2rW, bufA, N1, 1);
    k_scores<<<cdiv(N1, 256), 256, 0, stream>>>(bufA, p2w, normv, sc, key, N1);
    k_select<<<B, 256, 0, stream>>>(key, K1, K2, kth, eqneed);
    k_compact<<<B, 256, 0, stream>>>(key, sc, K1, K2, kth, eqneed, nmap, selo, vals);
    k_gather<<<cdiv((long)N2 * 32, 256), 256, 0, stream>>>(bufA, selo, vals, x3, N2);
    k_partial<<<B * SPLIT, F, 0, stream>>>(x3, K2, part);
    k_sumreduce<<<B, F, 0, stream>>>(part, K2, summary);
    k_remap<<<cdiv(E, 256), 256, 0, stream>>>(e2s, e2d, cnt_e2, E, nmap, e3s, e3d, cnt_e3);

    // ================= stage 3 =================
    k_zero<<<cdiv((long)N2 * F / 4, 256), 256, 0, stream>>>(agg3, (long)N2 * F / 4);
    k_zero<<<cdiv((long)N2 / 4, 256), 256, 0, stream>>>(deg, (long)N2 / 4);
    k_norm<<<1, 64, 0, stream>>>(p3w, normv);
    k_aggregate<<<edge_grid, 256, 0, stream>>>(x3, e3s, e3d, cnt_e3, E, agg3, deg);
    k_sage<<<cdiv(N2, 64), 256, 0, stream>>>(x3, agg3, deg, w3lW, w3lb, w3rW, agg3, N2, 0);
    k_scores<<<cdiv(N2, 256), 256, 0, stream>>>(agg3, p3w, normv, sc, key, N2);
    k_select<<<B, 256, 0, stream>>>(key, K2, K3, kth, eqneed);
    k_compact<<<B, 256, 0, stream>>>(key, sc, K2, K3, kth, eqneed, nmap, selo, vals);
    k_gather<<<cdiv((long)N3 * 32, 256), 256, 0, stream>>>(agg3, selo, vals, x4, N3);
    k_partial<<<B * SPLIT, F, 0, stream>>>(x4, K3, part);
    k_sumreduce<<<B, F, 0, stream>>>(part, K3, summary);

    // ================= output =================
    k_out<<<B, OUTD, 0, stream>>>(summary, outW, outb, out);
}

// Round 2
// 1356.287 us; speedup vs baseline: 2.9845x; 2.9845x over previous
//
#include <hip/hip_runtime.h>
#include <hip/hip_bf16.h>
#include <math.h>

// ---------------- problem constants ----------------
constexpr int B    = 8;
constexpr int NPG  = 10000;           // nodes per graph (stage 1)
constexpr int F    = 128;             // feature dim (F_IN == H == 128)
constexpr int OUTD = 64;
constexpr int E    = B * NPG * 16;    // 1,280,000 edges
constexpr int N0   = B * NPG;         // 80000
constexpr int K1   = 5000, K2 = 2500, K3 = 1250;
constexpr int N1   = B * K1;          // 40000
constexpr int N2   = B * K2;          // 20000
constexpr int N3   = B * K3;          // 10000
constexpr int SPLIT = 16;             // summarize row-split

// ---------------- ws layout (float units) ----------------
constexpr size_t OFF_A    = 0;                          // 80000*128 (agg -> h in place; also x3/agg3/x4 sub-regions)
constexpr size_t SZ_A     = (size_t)N0 * F;
constexpr size_t OFF_X2   = OFF_A + SZ_A;               // 40000*128
constexpr size_t SZ_X2    = (size_t)N1 * F;
constexpr size_t OFF_SC   = OFF_X2 + SZ_X2;             // 80000
constexpr size_t OFF_KEY  = OFF_SC + N0;                // 80000 (u32)
constexpr size_t OFF_MAP  = OFF_KEY + N0;               // 80000 (i32)
constexpr size_t OFF_SEL  = OFF_MAP + N0;               // 40000 (i32)
constexpr size_t OFF_VAL  = OFF_SEL + N1;               // 40000
constexpr size_t OFF_E2S  = OFF_VAL + N1;               // E (i32)
constexpr size_t OFF_E2D  = OFF_E2S + E;
constexpr size_t OFF_E3S  = OFF_E2D + E;
constexpr size_t OFF_E3D  = OFF_E3S + E;                // also CSR scratch stages 1-2
constexpr size_t OFF_PART = OFF_E3D + E;                // B*SPLIT*2*128
constexpr size_t OFF_SUM  = OFF_PART + (size_t)B * SPLIT * 2 * F;  // 2048
constexpr size_t OFF_MISC = OFF_SUM + (size_t)B * 2 * F;
// misc ints/floats: [0..2] edge counts, [4..11] kth keys, [12..19] eq_needed, [20] norm
constexpr size_t OFF_HIST = OFF_MISC + 64;              // N0 ints
constexpr size_t OFF_INCL = OFF_HIST + N0;              // N0 ints
constexpr size_t OFF_BSUM = OFF_INCL + N0;              // 512 ints
constexpr size_t OFF_RS   = OFF_BSUM + 512;             // N0+1 ints
constexpr size_t OFF_CUR  = OFF_RS + N0 + 64;           // N0 ints

// ---------------- helpers ----------------
__device__ inline unsigned f2key(float f) {
    unsigned u = __float_as_uint(f);
    return (u & 0x80000000u) ? ~u : (u | 0x80000000u);
}

// ---------------- kernels ----------------
__global__ void k_init(float* summary, int* cnts) {
    int t = blockIdx.x * blockDim.x + threadIdx.x;
    if (t < B * 2 * F) summary[t] = 0.0f;
    if (t == 0) { cnts[0] = E; cnts[1] = 0; cnts[2] = 0; }
}

__global__ void k_zero_i(int* p, int n) {
    int t = blockIdx.x * blockDim.x + threadIdx.x;
    if (t < n) p[t] = 0;
}

__global__ void k_norm(const float* __restrict__ w, float* out) {
    int t = threadIdx.x;               // 64 threads
    float v = 0.0f;
    for (int j = t; j < F; j += 64) { float a = w[j]; v += a * a; }
    for (int o = 32; o > 0; o >>= 1) v += __shfl_down(v, o);
    if (t == 0) *out = sqrtf(v);
}

// -------- CSR build: histogram -> 3-kernel scan -> cursor scatter --------
__global__ void k_hist(const int* __restrict__ dst, const int* __restrict__ cnt,
                       int emax, int* __restrict__ hist) {
    int e = blockIdx.x * blockDim.x + threadIdx.x;
    if (e >= emax) return;
    if (e >= *cnt) return;
    atomicAdd(&hist[dst[e]], 1);
}

__global__ __launch_bounds__(256) void k_scan1(const int* __restrict__ in, int n,
                                               int* __restrict__ incl, int* __restrict__ bsum) {
    __shared__ int s[256];
    int i = blockIdx.x * 256 + threadIdx.x;
    int v = (i < n) ? in[i] : 0;
    s[threadIdx.x] = v;
    __syncthreads();
    for (int off = 1; off < 256; off <<= 1) {
        int t = s[threadIdx.x] + ((threadIdx.x >= off) ? s[threadIdx.x - off] : 0);
        __syncthreads();
        s[threadIdx.x] = t;
        __syncthreads();
    }
    if (i < n) incl[i] = s[threadIdx.x];
    if (threadIdx.x == 255) bsum[blockIdx.x] = s[255];
}

__global__ __launch_bounds__(512) void k_scan2(int* __restrict__ bsum, int nb) {
    __shared__ int s[512];
    int t = threadIdx.x;
    int v = (t < nb) ? bsum[t] : 0;
    s[t] = v;
    __syncthreads();
    for (int off = 1; off < 512; off <<= 1) {
        int u = s[t] + ((t >= off) ? s[t - off] : 0);
        __syncthreads();
        s[t] = u;
        __syncthreads();
    }
    if (t < nb) bsum[t] = s[t] - v;   // exclusive
}

__global__ void k_scan3(const int* __restrict__ in, const int* __restrict__ incl,
                        const int* __restrict__ bsum, int n,
                        int* __restrict__ rowstart, int* __restrict__ cursor) {
    int i = blockIdx.x * 256 + threadIdx.x;
    if (i >= n) return;
    int ex = incl[i] - in[i] + bsum[blockIdx.x];
    rowstart[i] = ex;
    cursor[i] = ex;
    if (i == n - 1) rowstart[n] = ex + in[i];
}

__global__ void k_csr(const int* __restrict__ src, const int* __restrict__ dst,
                      const int* __restrict__ cnt, int emax,
                      int* __restrict__ cursor, int* __restrict__ csr) {
    int e = blockIdx.x * blockDim.x + threadIdx.x;
    if (e >= emax) return;
    if (e >= *cnt) return;
    int p = atomicAdd(&cursor[dst[e]], 1);
    csr[p] = src[e];
}

// gather-aggregate: 32 lanes per node, 8 nodes per block; one clean write per row
__global__ __launch_bounds__(256) void k_agg2(const float* __restrict__ x,
                                              const int* __restrict__ rowstart,
                                              const int* __restrict__ csr,
                                              float* __restrict__ agg, int n) {
    int t = blockIdx.x * blockDim.x + threadIdx.x;
    int i = t >> 5, lane = t & 31;
    if (i >= n) return;
    int b = rowstart[i], e = rowstart[i + 1];
    float4 acc = make_float4(0, 0, 0, 0);
    int j = b;
    for (; j + 2 <= e; j += 2) {      // 2-way ILP on the row loads
        int s0 = csr[j], s1 = csr[j + 1];
        float4 v0 = ((const float4*)(x + (size_t)s0 * F))[lane];
        float4 v1 = ((const float4*)(x + (size_t)s1 * F))[lane];
        acc.x += v0.x + v1.x; acc.y += v0.y + v1.y;
        acc.z += v0.z + v1.z; acc.w += v0.w + v1.w;
    }
    if (j < e) {
        int s0 = csr[j];
        float4 v0 = ((const float4*)(x + (size_t)s0 * F))[lane];
        acc.x += v0.x; acc.y += v0.y; acc.z += v0.z; acc.w += v0.w;
    }
    ((float4*)(agg + (size_t)i * F))[lane] = acc;
}

// h[i,:] = (agg[i,:]/max(deg,1)) @ Wl^T + x[i,:] @ Wr^T + bl   (optional relu)
// deg[i] = rowstart[i+1]-rowstart[i]. h may alias agg (in-place).
__global__ __launch_bounds__(256) void k_sage(
    const float* __restrict__ x, const float* __restrict__ agg,
    const int* __restrict__ rs, const float* __restrict__ Wl,
    const float* __restrict__ bl, const float* __restrict__ Wr,
    float* __restrict__ h, int n, int relu) {
    __shared__ float xs[32][68];
    __shared__ float as_[32][68];
    __shared__ float wls[32][132];
    __shared__ float wrs[32][132];
    int tid = threadIdx.x;
    int tx = tid & 31, ty = tid >> 5;
    int row0 = blockIdx.x * 64;
    float acc[8][4];
#pragma unroll
    for (int r = 0; r < 8; r++)
#pragma unroll
        for (int c = 0; c < 4; c++) acc[r][c] = 0.0f;

    for (int kt = 0; kt < 4; kt++) {
        int k0 = kt * 32;
#pragma unroll
        for (int l = 0; l < 2; l++) {        // x/agg tiles: 64 rows x 32 k
            int idx = l * 256 + tid;         // 0..511
            int row = idx >> 3, j = idx & 7;
            int grow = row0 + row;
            float4 xv = make_float4(0, 0, 0, 0), av = make_float4(0, 0, 0, 0);
            if (grow < n) {
                xv = *(const float4*)(x + (size_t)grow * F + k0 + j * 4);
                av = *(const float4*)(agg + (size_t)grow * F + k0 + j * 4);
                float rd = 1.0f / fmaxf((float)(rs[grow + 1] - rs[grow]), 1.0f);
                av.x *= rd; av.y *= rd; av.z *= rd; av.w *= rd;
            }
            xs[j * 4 + 0][row] = xv.x; xs[j * 4 + 1][row] = xv.y;
            xs[j * 4 + 2][row] = xv.z; xs[j * 4 + 3][row] = xv.w;
            as_[j * 4 + 0][row] = av.x; as_[j * 4 + 1][row] = av.y;
            as_[j * 4 + 2][row] = av.z; as_[j * 4 + 3][row] = av.w;
        }
#pragma unroll
        for (int l = 0; l < 4; l++) {        // W tiles: 128 cols x 32 k
            int idx = l * 256 + tid;         // 0..1023
            int col = idx >> 3, j = idx & 7;
            float4 wv = *(const float4*)(Wl + (size_t)col * F + k0 + j * 4);
            float4 uv = *(const float4*)(Wr + (size_t)col * F + k0 + j * 4);
            wls[j * 4 + 0][col] = wv.x; wls[j * 4 + 1][col] = wv.y;
            wls[j * 4 + 2][col] = wv.z; wls[j * 4 + 3][col] = wv.w;
            wrs[j * 4 + 0][col] = uv.x; wrs[j * 4 + 1][col] = uv.y;
            wrs[j * 4 + 2][col] = uv.z; wrs[j * 4 + 3][col] = uv.w;
        }
        __syncthreads();
#pragma unroll
        for (int kk = 0; kk < 32; kk++) {
            float4 xlo = *(const float4*)&xs[kk][ty * 8];
            float4 xhi = *(const float4*)&xs[kk][ty * 8 + 4];
            float4 alo = *(const float4*)&as_[kk][ty * 8];
            float4 ahi = *(const float4*)&as_[kk][ty * 8 + 4];
            float4 wl4 = *(const float4*)&wls[kk][tx * 4];
            float4 wr4 = *(const float4*)&wrs[kk][tx * 4];
            float xv[8] = {xlo.x, xlo.y, xlo.z, xlo.w, xhi.x, xhi.y, xhi.z, xhi.w};
            float av[8] = {alo.x, alo.y, alo.z, alo.w, ahi.x, ahi.y, ahi.z, ahi.w};
            float wlv[4] = {wl4.x, wl4.y, wl4.z, wl4.w};
            float wrv[4] = {wr4.x, wr4.y, wr4.z, wr4.w};
#pragma unroll
            for (int r = 0; r < 8; r++)
#pragma unroll
                for (int c = 0; c < 4; c++)
                    acc[r][c] += av[r] * wlv[c] + xv[r] * wrv[c];
        }
        __syncthreads();
    }
    float4 bv = *(const float4*)(bl + tx * 4);
    float blv[4] = {bv.x, bv.y, bv.z, bv.w};
#pragma unroll
    for (int r = 0; r < 8; r++) {
        int grow = row0 + ty * 8 + r;
        if (grow < n) {
            float4 o;
            o.x = acc[r][0] + blv[0]; o.y = acc[r][1] + blv[1];
            o.z = acc[r][2] + blv[2]; o.w = acc[r][3] + blv[3];
            if (relu) {
                o.x = fmaxf(o.x, 0.f); o.y = fmaxf(o.y, 0.f);
                o.z = fmaxf(o.z, 0.f); o.w = fmaxf(o.w, 0.f);
            }
            *(float4*)(h + (size_t)grow * F + tx * 4) = o;
        }
    }
}

__global__ void k_scores(const float* __restrict__ h, const float* __restrict__ w,
                         const float* __restrict__ norm, float* __restrict__ sc,
                         unsigned* __restrict__ key, int n) {
    int i = blockIdx.x * blockDim.x + threadIdx.x;
    if (i >= n) return;
    float nv = *norm;
    const float4* hr = (const float4*)(h + (size_t)i * F);
    const float4* wr = (const float4*)w;
    float acc = 0.0f;
#pragma unroll
    for (int j = 0; j < F / 4; j++) {
        float4 a = hr[j], b = wr[j];
        acc += a.x * b.x + a.y * b.y + a.z * b.z + a.w * b.w;
    }
    float s = tanhf(acc / nv);
    sc[i] = s;
    key[i] = f2key(s);
}

// per-graph 4-pass radix select: kth largest key + #equal-needed
__global__ __launch_bounds__(256) void k_select(const unsigned* __restrict__ keys,
                                                int n_per, int k,
                                                unsigned* kth_out, int* eqneed_out) {
    int g = blockIdx.x;
    const unsigned* kk = keys + (size_t)g * n_per;
    __shared__ int hist[256];
    __shared__ unsigned sprefix;
    __shared__ int sr;
    if (threadIdx.x == 0) { sprefix = 0; sr = k; }
    for (int b = 3; b >= 0; b--) {
        for (int i = threadIdx.x; i < 256; i += blockDim.x) hist[i] = 0;
        __syncthreads();
        unsigned pfx = sprefix;
        unsigned maskhi = (b == 3) ? 0u : (0xFFFFFFFFu << ((b + 1) * 8));
        for (int i = threadIdx.x; i < n_per; i += blockDim.x) {
            unsigned key = kk[i];
            if ((key & maskhi) == (pfx & maskhi))
                atomicAdd(&hist[(key >> (b * 8)) & 255], 1);
        }
        __syncthreads();
        if (threadIdx.x == 0) {
            int r = sr, c = 0, v = 255;
            for (; v > 0; v--) { if (c + hist[v] >= r) break; c += hist[v]; }
            sr = r - c;
            sprefix = pfx | ((unsigned)v << (b * 8));
        }
        __syncthreads();
    }
    if (threadIdx.x == 0) { kth_out[g] = sprefix; eqneed_out[g] = sr; }
}

// deterministic index-order compaction of the selected set (ties: lower index first)
__global__ __launch_bounds__(256) void k_compact(
    const unsigned* __restrict__ keys, const float* __restrict__ sc,
    int n_per, int k, const unsigned* __restrict__ kth, const int* __restrict__ eqneed,
    int* __restrict__ node_map, int* __restrict__ sel_old, float* __restrict__ vals) {
    int g = blockIdx.x, tid = threadIdx.x;
    const unsigned* kk = keys + (size_t)g * n_per;
    const float* ss = sc + (size_t)g * n_per;
    unsigned K = kth[g];
    int need = eqneed[g];
    __shared__ int s1[256], s2[256];
    __shared__ int carry_pos, carry_eq;
    if (tid == 0) { carry_pos = 0; carry_eq = 0; }
    __syncthreads();
    int nchunks = (n_per + 255) / 256;
    for (int ch = 0; ch < nchunks; ch++) {
        int i = ch * 256 + tid;
        int is_eq = 0, is_gt = 0;
        if (i < n_per) {
            unsigned key = kk[i];
            is_gt = key > K;
            is_eq = key == K;
        }
        s1[tid] = is_eq;
        __syncthreads();
        for (int off = 1; off < 256; off <<= 1) {
            int v = s1[tid] + ((tid >= off) ? s1[tid - off] : 0);
            __syncthreads();
            s1[tid] = v;
            __syncthreads();
        }
        int eq_excl = s1[tid] - is_eq;
        int sel = is_gt || (is_eq && (carry_eq + eq_excl) < need);
        s2[tid] = sel;
        __syncthreads();
        for (int off = 1; off < 256; off <<= 1) {
            int v = s2[tid] + ((tid >= off) ? s2[tid - off] : 0);
            __syncthreads();
            s2[tid] = v;
            __syncthreads();
        }
        int pos = carry_pos + s2[tid] - sel;
        if (i < n_per) {
            if (sel) {
                int ni = g * k + pos;
                node_map[(size_t)g * n_per + i] = ni;
                sel_old[ni] = g * n_per + i;
                vals[ni] = ss[i];
            } else {
                node_map[(size_t)g * n_per + i] = -1;
            }
        }
        __syncthreads();
        if (tid == 0) { carry_pos += s2[255]; carry_eq += s1[255]; }
        __syncthreads();
    }
}

__global__ void k_gather(const float* __restrict__ h, const int* __restrict__ sel_old,
                         const float* __restrict__ vals, float* __restrict__ xout, int m) {
    long t = blockIdx.x * (long)blockDim.x + threadIdx.x;
    int i = (int)(t >> 5), lane = (int)(t & 31);
    if (i >= m) return;
    int oi = sel_old[i];
    float v = vals[i];
    float4 r = ((const float4*)(h + (size_t)oi * F))[lane];
    r.x *= v; r.y *= v; r.z *= v; r.w *= v;
    ((float4*)(xout + (size_t)i * F))[lane] = r;
}

__global__ void k_partial(const float* __restrict__ x, int k, float* __restrict__ part) {
    int g = blockIdx.x / SPLIT, s = blockIdx.x % SPLIT;
    int f = threadIdx.x;                 // 128 threads
    int rows = (k + SPLIT - 1) / SPLIT;
    int r0 = s * rows, r1 = min(k, r0 + rows);
    float sum = 0.0f, mx = -INFINITY;
    for (int r = r0; r < r1; r++) {
        float v = x[((size_t)(g * k + r)) * F + f];
        sum += v;
        mx = fmaxf(mx, v);
    }
    part[((size_t)(g * SPLIT + s) * 2 + 0) * F + f] = sum;
    part[((size_t)(g * SPLIT + s) * 2 + 1) * F + f] = mx;
}

__global__ void k_sumreduce(const float* __restrict__ part, int k, float* __restrict__ summary) {
    int g = blockIdx.x, f = threadIdx.x; // 128 threads
    float sum = 0.0f, mx = -INFINITY;
    for (int s = 0; s < SPLIT; s++) {
        sum += part[((size_t)(g * SPLIT + s) * 2 + 0) * F + f];
        mx = fmaxf(mx, part[((size_t)(g * SPLIT + s) * 2 + 1) * F + f]);
    }
    summary[g * 2 * F + f] += sum / (float)k;
    summary[g * 2 * F + F + f] += mx;
}

__global__ void k_remap(const int* __restrict__ src, const int* __restrict__ dst,
                        const int* __restrict__ cnt_in, int emax,
                        const int* __restrict__ node_map,
                        int* __restrict__ nsrc, int* __restrict__ ndst,
                        int* __restrict__ cnt_out) {
    int e = blockIdx.x * blockDim.x + threadIdx.x;
    if (e >= emax) return;
    if (e >= *cnt_in) return;
    int a = node_map[src[e]], b = node_map[dst[e]];
    if (a >= 0 && b >= 0) {
        int p = atomicAdd(cnt_out, 1);
        nsrc[p] = a;
        ndst[p] = b;
    }
}

__global__ void k_out(const float* __restrict__ summary, const float* __restrict__ W,
                      const float* __restrict__ bias, float* __restrict__ out) {
    int g = blockIdx.x, j = threadIdx.x;  // 8 blocks x 64 threads
    float acc = bias[j];
    for (int t = 0; t < 2 * F; t++) acc += summary[g * 2 * F + t] * W[j * 2 * F + t];
    out[g * OUTD + j] = acc;
}

// ---------------- host launch ----------------
static inline int cdiv(long a, long b) { return (int)((a + b - 1) / b); }

extern "C" void kernel_launch(void* const* d_in, const int* in_sizes, int n_in,
                              void* d_out, int out_size, void* d_ws, size_t ws_size,
                              hipStream_t stream) {
    const float* x_in = (const float*)d_in[0];
    const int* ei     = (const int*)d_in[1];    // [2, E] -> src = ei, dst = ei+E
    const float* w1lW = (const float*)d_in[2];
    const float* w1lb = (const float*)d_in[3];
    const float* w1rW = (const float*)d_in[4];
    const float* p1w  = (const float*)d_in[5];
    const float* w2lW = (const float*)d_in[6];
    const float* w2lb = (const float*)d_in[7];
    const float* w2rW = (const float*)d_in[8];
    const float* p2w  = (const float*)d_in[9];
    const float* w3lW = (const float*)d_in[10];
    const float* w3lb = (const float*)d_in[11];
    const float* w3rW = (const float*)d_in[12];
    const float* p3w  = (const float*)d_in[13];
    const float* outW = (const float*)d_in[14];
    const float* outb = (const float*)d_in[15];
    float* out = (float*)d_out;

    float* ws = (float*)d_ws;
    float* bufA  = ws + OFF_A;
    float* bufX2 = ws + OFF_X2;
    float* sc    = ws + OFF_SC;
    unsigned* key = (unsigned*)(ws + OFF_KEY);
    int* nmap    = (int*)(ws + OFF_MAP);
    int* selo    = (int*)(ws + OFF_SEL);
    float* vals  = ws + OFF_VAL;
    int* e2s = (int*)(ws + OFF_E2S);
    int* e2d = (int*)(ws + OFF_E2D);
    int* e3s = (int*)(ws + OFF_E3S);
    int* e3d = (int*)(ws + OFF_E3D);
    float* part    = ws + OFF_PART;
    float* summary = ws + OFF_SUM;
    int* misc_i    = (int*)(ws + OFF_MISC);
    int* cnt_e1 = misc_i + 0;
    int* cnt_e2 = misc_i + 1;
    int* cnt_e3 = misc_i + 2;
    unsigned* kth = (unsigned*)(misc_i + 4);
    int* eqneed   = misc_i + 12;
    float* normv  = (float*)(misc_i + 20);
    int* hist = (int*)(ws + OFF_HIST);
    int* incl = (int*)(ws + OFF_INCL);
    int* bsum = (int*)(ws + OFF_BSUM);
    int* rs   = (int*)(ws + OFF_RS);
    int* cur  = (int*)(ws + OFF_CUR);

    float* x3   = bufA + (size_t)N1 * F;   // 20000x128 region
    float* agg3 = bufA + (size_t)(N1 + N2) * F;
    float* x4   = bufA;                    // 10000x128 region (h2 dead by then)

    const int eg = cdiv(E, 256);           // edge-grid (1 thread/edge)

    k_init<<<8, 256, 0, stream>>>(summary, misc_i);

    // ================= stage 1 =================
    {
        int n = N0, nb = cdiv(n, 256);
        int* csr = e3d;                    // dead region during stage 1
        k_zero_i<<<nb, 256, 0, stream>>>(hist, n);
        k_norm<<<1, 64, 0, stream>>>(p1w, normv);
        k_hist<<<eg, 256, 0, stream>>>(ei + E, cnt_e1, E, hist);
        k_scan1<<<nb, 256, 0, stream>>>(hist, n, incl, bsum);
        k_scan2<<<1, 512, 0, stream>>>(bsum, nb);
        k_scan3<<<nb, 256, 0, stream>>>(hist, incl, bsum, n, rs, cur);
        k_csr<<<eg, 256, 0, stream>>>(ei, ei + E, cnt_e1, E, cur, csr);
        k_agg2<<<cdiv((long)n * 32, 256), 256, 0, stream>>>(x_in, rs, csr, bufA, n);
        k_sage<<<cdiv(n, 64), 256, 0, stream>>>(x_in, bufA, rs, w1lW, w1lb, w1rW, bufA, n, 0);
        k_scores<<<cdiv(n, 256), 256, 0, stream>>>(bufA, p1w, normv, sc, key, n);
        k_select<<<B, 256, 0, stream>>>(key, NPG, K1, kth, eqneed);
        k_compact<<<B, 256, 0, stream>>>(key, sc, NPG, K1, kth, eqneed, nmap, selo, vals);
        k_gather<<<cdiv((long)N1 * 32, 256), 256, 0, stream>>>(bufA, selo, vals, bufX2, N1);
        k_partial<<<B * SPLIT, F, 0, stream>>>(bufX2, K1, part);
        k_sumreduce<<<B, F, 0, stream>>>(part, K1, summary);
        k_remap<<<eg, 256, 0, stream>>>(ei, ei + E, cnt_e1, E, nmap, e2s, e2d, cnt_e2);
    }

    // ================= stage 2 =================
    {
        int n = N1, nb = cdiv(n, 256);
        int* csr = e3d;                    // consumed before stage-2 remap writes e3d
        k_zero_i<<<nb, 256, 0, stream>>>(hist, n);
        k_norm<<<1, 64, 0, stream>>>(p2w, normv);
        k_hist<<<eg, 256, 0, stream>>>(e2d, cnt_e2, E, hist);
        k_scan1<<<nb, 256, 0, stream>>>(hist, n, incl, bsum);
        k_scan2<<<1, 512, 0, stream>>>(bsum, nb);
        k_scan3<<<nb, 256, 0, stream>>>(hist, incl, bsum, n, rs, cur);
        k_csr<<<eg, 256, 0, stream>>>(e2s, e2d, cnt_e2, E, cur, csr);
        k_agg2<<<cdiv((long)n * 32, 256), 256, 0, stream>>>(bufX2, rs, csr, bufA, n);
        k_sage<<<cdiv(n, 64), 256, 0, stream>>>(bufX2, bufA, rs, w2lW, w2lb, w2rW, bufA, n, 1);
        k_scores<<<cdiv(n, 256), 256, 0, stream>>>(bufA, p2w, normv, sc, key, n);
        k_select<<<B, 256, 0, stream>>>(key, K1, K2, kth, eqneed);
        k_compact<<<B, 256, 0, stream>>>(key, sc, K1, K2, kth, eqneed, nmap, selo, vals);
        k_gather<<<cdiv((long)N2 * 32, 256), 256, 0, stream>>>(bufA, selo, vals, x3, N2);
        k_partial<<<B * SPLIT, F, 0, stream>>>(x3, K2, part);
        k_sumreduce<<<B, F, 0, stream>>>(part, K2, summary);
        k_remap<<<eg, 256, 0, stream>>>(e2s, e2d, cnt_e2, E, nmap, e3s, e3d, cnt_e3);
    }

    // ================= stage 3 =================
    {
        int n = N2, nb = cdiv(n, 256);
        int* csr = e2d;                    // e2 lists dead after stage-2 remap
        k_zero_i<<<nb, 256, 0, stream>>>(hist, n);
        k_norm<<<1, 64, 0, stream>>>(p3w, normv);
        k_hist<<<eg, 256, 0, stream>>>(e3d, cnt_e3, E, hist);
        k_scan1<<<nb, 256, 0, stream>>>(hist, n, incl, bsum);
        k_scan2<<<1, 512, 0, stream>>>(bsum, nb);
        k_scan3<<<nb, 256, 0, stream>>>(hist, incl, bsum, n, rs, cur);
        k_csr<<<eg, 256, 0, stream>>>(e3s, e3d, cnt_e3, E, cur, csr);
        k_agg2<<<cdiv((long)n * 32, 256), 256, 0, stream>>>(x3, rs, csr, agg3, n);
        k_sage<<<cdiv(n, 64), 256, 0, stream>>>(x3, agg3, rs, w3lW, w3lb, w3rW, agg3, n, 0);
        k_scores<<<cdiv(n, 256), 256, 0, stream>>>(agg3, p3w, normv, sc, key, n);
        k_select<<<B, 256, 0, stream>>>(key, K2, K3, kth, eqneed);
        k_compact<<<B, 256, 0, stream>>>(key, sc, K2, K3, kth, eqneed, nmap, selo, vals);
        k_gather<<<cdiv((long)N3 * 32, 256), 256, 0, stream>>>(agg3, selo, vals, x4, N3);
        k_partial<<<B * SPLIT, F, 0, stream>>>(x4, K3, part);
        k_sumreduce<<<B, F, 0, stream>>>(part, K3, summary);
    }

    // ================= output =================
    k_out<<<B, OUTD, 0, stream>>>(summary, outW, outb, out);
}

// Round 3
// 1090.973 us; speedup vs baseline: 3.7103x; 1.2432x over previous
//
#include <hip/hip_runtime.h>
#include <hip/hip_bf16.h>
#include <math.h>

// ---------------- problem constants ----------------
constexpr int B    = 8;
constexpr int NPG  = 10000;           // nodes per graph (stage 1)
constexpr int F    = 128;             // feature dim (F_IN == H == 128)
constexpr int OUTD = 64;
constexpr int E    = B * NPG * 16;    // 1,280,000 edges
constexpr int N0   = B * NPG;         // 80000
constexpr int K1   = 5000, K2 = 2500, K3 = 1250;
constexpr int N1   = B * K1;          // 40000
constexpr int N2   = B * K2;          // 20000
constexpr int N3   = B * K3;          // 10000
constexpr int SPLIT = 16;             // summarize row-split

// ---------------- ws layout (float units) ----------------
constexpr size_t OFF_A    = 0;                          // 80000*128 (agg -> h in place; also x3/agg3/x4 sub-regions)
constexpr size_t SZ_A     = (size_t)N0 * F;
constexpr size_t OFF_X2   = OFF_A + SZ_A;               // 40000*128
constexpr size_t SZ_X2    = (size_t)N1 * F;
constexpr size_t OFF_SC   = OFF_X2 + SZ_X2;             // 80000
constexpr size_t OFF_KEY  = OFF_SC + N0;                // 80000 (u32)
constexpr size_t OFF_MAP  = OFF_KEY + N0;               // 80000 (i32)  nmap1 / cmap (in-place compose)
constexpr size_t OFF_MAP2 = OFF_MAP + N0;               // 40000 (i32)  nmap2 / stage-3 scratch map
constexpr size_t OFF_SEL  = OFF_MAP2 + N1;              // 40000 (i32)
constexpr size_t OFF_VAL  = OFF_SEL + N1;               // 40000
constexpr size_t OFF_CSR  = OFF_VAL + N1;               // E (i32) CSR adjacency scratch
constexpr size_t OFF_PART = OFF_CSR + E;                // B*SPLIT*2*128
constexpr size_t OFF_SUM  = OFF_PART + (size_t)B * SPLIT * 2 * F;  // 2048
constexpr size_t OFF_MISC = OFF_SUM + (size_t)B * 2 * F;
// misc: [4..11] kth keys, [12..19] eq_needed, [20] norm
constexpr size_t OFF_HIST = OFF_MISC + 64;              // N0 ints
constexpr size_t OFF_INCL = OFF_HIST + N0;              // N0 ints
constexpr size_t OFF_BSUM = OFF_INCL + N0;              // 512 ints
constexpr size_t OFF_RS   = OFF_BSUM + 512;             // N0+1 ints
constexpr size_t OFF_CUR  = OFF_RS + N0 + 64;           // N0 ints

// ---------------- helpers ----------------
__device__ inline unsigned f2key(float f) {
    unsigned u = __float_as_uint(f);
    return (u & 0x80000000u) ? ~u : (u | 0x80000000u);
}

// ---------------- kernels ----------------
__global__ void k_init(float* summary) {
    int t = blockIdx.x * blockDim.x + threadIdx.x;
    if (t < B * 2 * F) summary[t] = 0.0f;
}

__global__ void k_zero_i(int* p, int n) {
    int t = blockIdx.x * blockDim.x + threadIdx.x;
    if (t < n) p[t] = 0;
}

__global__ void k_norm(const float* __restrict__ w, float* out) {
    int t = threadIdx.x;               // 64 threads
    float v = 0.0f;
    for (int j = t; j < F; j += 64) { float a = w[j]; v += a * a; }
    for (int o = 32; o > 0; o >>= 1) v += __shfl_down(v, o);
    if (t == 0) *out = sqrtf(v);
}

// -------- CSR build: histogram -> 3-kernel scan -> cursor scatter --------
// direct (stage 1): all E edges valid, identity node ids
__global__ void k_hist_d(const int* __restrict__ dst, int* __restrict__ hist) {
    int e = blockIdx.x * blockDim.x + threadIdx.x;
    if (e >= E) return;
    atomicAdd(&hist[dst[e]], 1);
}

// mapped (stages 2-3): node-map gathered on both endpoints; <0 = dropped
__global__ void k_hist_m(const int* __restrict__ src, const int* __restrict__ dst,
                         const int* __restrict__ map, int* __restrict__ hist) {
    int e = blockIdx.x * blockDim.x + threadIdx.x;
    if (e >= E) return;
    int a = map[src[e]], b = map[dst[e]];
    if (a >= 0 && b >= 0) atomicAdd(&hist[b], 1);
}

__global__ __launch_bounds__(256) void k_scan1(const int* __restrict__ in, int n,
                                               int* __restrict__ incl, int* __restrict__ bsum) {
    __shared__ int s[256];
    int i = blockIdx.x * 256 + threadIdx.x;
    int v = (i < n) ? in[i] : 0;
    s[threadIdx.x] = v;
    __syncthreads();
    for (int off = 1; off < 256; off <<= 1) {
        int t = s[threadIdx.x] + ((threadIdx.x >= off) ? s[threadIdx.x - off] : 0);
        __syncthreads();
        s[threadIdx.x] = t;
        __syncthreads();
    }
    if (i < n) incl[i] = s[threadIdx.x];
    if (threadIdx.x == 255) bsum[blockIdx.x] = s[255];
}

__global__ __launch_bounds__(512) void k_scan2(int* __restrict__ bsum, int nb) {
    __shared__ int s[512];
    int t = threadIdx.x;
    int v = (t < nb) ? bsum[t] : 0;
    s[t] = v;
    __syncthreads();
    for (int off = 1; off < 512; off <<= 1) {
        int u = s[t] + ((t >= off) ? s[t - off] : 0);
        __syncthreads();
        s[t] = u;
        __syncthreads();
    }
    if (t < nb) bsum[t] = s[t] - v;   // exclusive
}

__global__ void k_scan3(const int* __restrict__ in, const int* __restrict__ incl,
                        const int* __restrict__ bsum, int n,
                        int* __restrict__ rowstart, int* __restrict__ cursor) {
    int i = blockIdx.x * 256 + threadIdx.x;
    if (i >= n) return;
    int ex = incl[i] - in[i] + bsum[blockIdx.x];
    rowstart[i] = ex;
    cursor[i] = ex;
    if (i == n - 1) rowstart[n] = ex + in[i];
}

__global__ void k_csr_d(const int* __restrict__ src, const int* __restrict__ dst,
                        int* __restrict__ cursor, int* __restrict__ csr) {
    int e = blockIdx.x * blockDim.x + threadIdx.x;
    if (e >= E) return;
    int p = atomicAdd(&cursor[dst[e]], 1);
    csr[p] = src[e];
}

__global__ void k_csr_m(const int* __restrict__ src, const int* __restrict__ dst,
                        const int* __restrict__ map,
                        int* __restrict__ cursor, int* __restrict__ csr) {
    int e = blockIdx.x * blockDim.x + threadIdx.x;
    if (e >= E) return;
    int a = map[src[e]], b = map[dst[e]];
    if (a >= 0 && b >= 0) {
        int p = atomicAdd(&cursor[b], 1);
        csr[p] = a;
    }
}

// compose maps: cmap[i] = m1[i]>=0 ? m2[m1[i]] : -1  (in-place over m1 is safe)
__global__ void k_compose(int* __restrict__ m1, const int* __restrict__ m2, int n) {
    int i = blockIdx.x * blockDim.x + threadIdx.x;
    if (i >= n) return;
    int a = m1[i];
    m1[i] = (a >= 0) ? m2[a] : -1;
}

// gather-aggregate: 32 lanes per node, 8 nodes per block; one clean write per row
__global__ __launch_bounds__(256) void k_agg2(const float* __restrict__ x,
                                              const int* __restrict__ rowstart,
                                              const int* __restrict__ csr,
                                              float* __restrict__ agg, int n) {
    int t = blockIdx.x * blockDim.x + threadIdx.x;
    int i = t >> 5, lane = t & 31;
    if (i >= n) return;
    int b = rowstart[i], e = rowstart[i + 1];
    float4 acc = make_float4(0, 0, 0, 0);
    int j = b;
    for (; j + 2 <= e; j += 2) {      // 2-way ILP on the row loads
        int s0 = csr[j], s1 = csr[j + 1];
        float4 v0 = ((const float4*)(x + (size_t)s0 * F))[lane];
        float4 v1 = ((const float4*)(x + (size_t)s1 * F))[lane];
        acc.x += v0.x + v1.x; acc.y += v0.y + v1.y;
        acc.z += v0.z + v1.z; acc.w += v0.w + v1.w;
    }
    if (j < e) {
        int s0 = csr[j];
        float4 v0 = ((const float4*)(x + (size_t)s0 * F))[lane];
        acc.x += v0.x; acc.y += v0.y; acc.z += v0.z; acc.w += v0.w;
    }
    ((float4*)(agg + (size_t)i * F))[lane] = acc;
}

// h[i,:] = (agg[i,:]/max(deg,1)) @ Wl^T + x[i,:] @ Wr^T + bl   (optional relu)
// deg[i] = rowstart[i+1]-rowstart[i]. h may alias agg (in-place).
__global__ __launch_bounds__(256) void k_sage(
    const float* __restrict__ x, const float* __restrict__ agg,
    const int* __restrict__ rs, const float* __restrict__ Wl,
    const float* __restrict__ bl, const float* __restrict__ Wr,
    float* __restrict__ h, int n, int relu) {
    __shared__ float xs[32][68];
    __shared__ float as_[32][68];
    __shared__ float wls[32][132];
    __shared__ float wrs[32][132];
    int tid = threadIdx.x;
    int tx = tid & 31, ty = tid >> 5;
    int row0 = blockIdx.x * 64;
    float acc[8][4];
#pragma unroll
    for (int r = 0; r < 8; r++)
#pragma unroll
        for (int c = 0; c < 4; c++) acc[r][c] = 0.0f;

    for (int kt = 0; kt < 4; kt++) {
        int k0 = kt * 32;
#pragma unroll
        for (int l = 0; l < 2; l++) {        // x/agg tiles: 64 rows x 32 k
            int idx = l * 256 + tid;         // 0..511
            int row = idx >> 3, j = idx & 7;
            int grow = row0 + row;
            float4 xv = make_float4(0, 0, 0, 0), av = make_float4(0, 0, 0, 0);
            if (grow < n) {
                xv = *(const float4*)(x + (size_t)grow * F + k0 + j * 4);
                av = *(const float4*)(agg + (size_t)grow * F + k0 + j * 4);
                float rd = 1.0f / fmaxf((float)(rs[grow + 1] - rs[grow]), 1.0f);
                av.x *= rd; av.y *= rd; av.z *= rd; av.w *= rd;
            }
            xs[j * 4 + 0][row] = xv.x; xs[j * 4 + 1][row] = xv.y;
            xs[j * 4 + 2][row] = xv.z; xs[j * 4 + 3][row] = xv.w;
            as_[j * 4 + 0][row] = av.x; as_[j * 4 + 1][row] = av.y;
            as_[j * 4 + 2][row] = av.z; as_[j * 4 + 3][row] = av.w;
        }
#pragma unroll
        for (int l = 0; l < 4; l++) {        // W tiles: 128 cols x 32 k
            int idx = l * 256 + tid;         // 0..1023
            int col = idx >> 3, j = idx & 7;
            float4 wv = *(const float4*)(Wl + (size_t)col * F + k0 + j * 4);
            float4 uv = *(const float4*)(Wr + (size_t)col * F + k0 + j * 4);
            wls[j * 4 + 0][col] = wv.x; wls[j * 4 + 1][col] = wv.y;
            wls[j * 4 + 2][col] = wv.z; wls[j * 4 + 3][col] = wv.w;
            wrs[j * 4 + 0][col] = uv.x; wrs[j * 4 + 1][col] = uv.y;
            wrs[j * 4 + 2][col] = uv.z; wrs[j * 4 + 3][col] = uv.w;
        }
        __syncthreads();
#pragma unroll
        for (int kk = 0; kk < 32; kk++) {
            float4 xlo = *(const float4*)&xs[kk][ty * 8];
            float4 xhi = *(const float4*)&xs[kk][ty * 8 + 4];
            float4 alo = *(const float4*)&as_[kk][ty * 8];
            float4 ahi = *(const float4*)&as_[kk][ty * 8 + 4];
            float4 wl4 = *(const float4*)&wls[kk][tx * 4];
            float4 wr4 = *(const float4*)&wrs[kk][tx * 4];
            float xv[8] = {xlo.x, xlo.y, xlo.z, xlo.w, xhi.x, xhi.y, xhi.z, xhi.w};
            float av[8] = {alo.x, alo.y, alo.z, alo.w, ahi.x, ahi.y, ahi.z, ahi.w};
            float wlv[4] = {wl4.x, wl4.y, wl4.z, wl4.w};
            float wrv[4] = {wr4.x, wr4.y, wr4.z, wr4.w};
#pragma unroll
            for (int r = 0; r < 8; r++)
#pragma unroll
                for (int c = 0; c < 4; c++)
                    acc[r][c] += av[r] * wlv[c] + xv[r] * wrv[c];
        }
        __syncthreads();
    }
    float4 bv = *(const float4*)(bl + tx * 4);
    float blv[4] = {bv.x, bv.y, bv.z, bv.w};
#pragma unroll
    for (int r = 0; r < 8; r++) {
        int grow = row0 + ty * 8 + r;
        if (grow < n) {
            float4 o;
            o.x = acc[r][0] + blv[0]; o.y = acc[r][1] + blv[1];
            o.z = acc[r][2] + blv[2]; o.w = acc[r][3] + blv[3];
            if (relu) {
                o.x = fmaxf(o.x, 0.f); o.y = fmaxf(o.y, 0.f);
                o.z = fmaxf(o.z, 0.f); o.w = fmaxf(o.w, 0.f);
            }
            *(float4*)(h + (size_t)grow * F + tx * 4) = o;
        }
    }
}

__global__ void k_scores(const float* __restrict__ h, const float* __restrict__ w,
                         const float* __restrict__ norm, float* __restrict__ sc,
                         unsigned* __restrict__ key, int n) {
    int i = blockIdx.x * blockDim.x + threadIdx.x;
    if (i >= n) return;
    float nv = *norm;
    const float4* hr = (const float4*)(h + (size_t)i * F);
    const float4* wr = (const float4*)w;
    float acc = 0.0f;
#pragma unroll
    for (int j = 0; j < F / 4; j++) {
        float4 a = hr[j], b = wr[j];
        acc += a.x * b.x + a.y * b.y + a.z * b.z + a.w * b.w;
    }
    float s = tanhf(acc / nv);
    sc[i] = s;
    key[i] = f2key(s);
}

// per-graph 4-pass radix select: kth largest key + #equal-needed
__global__ __launch_bounds__(256) void k_select(const unsigned* __restrict__ keys,
                                                int n_per, int k,
                                                unsigned* kth_out, int* eqneed_out) {
    int g = blockIdx.x;
    const unsigned* kk = keys + (size_t)g * n_per;
    __shared__ int hist[256];
    __shared__ unsigned sprefix;
    __shared__ int sr;
    if (threadIdx.x == 0) { sprefix = 0; sr = k; }
    for (int b = 3; b >= 0; b--) {
        for (int i = threadIdx.x; i < 256; i += blockDim.x) hist[i] = 0;
        __syncthreads();
        unsigned pfx = sprefix;
        unsigned maskhi = (b == 3) ? 0u : (0xFFFFFFFFu << ((b + 1) * 8));
        for (int i = threadIdx.x; i < n_per; i += blockDim.x) {
            unsigned key = kk[i];
            if ((key & maskhi) == (pfx & maskhi))
                atomicAdd(&hist[(key >> (b * 8)) & 255], 1);
        }
        __syncthreads();
        if (threadIdx.x == 0) {
            int r = sr, c = 0, v = 255;
            for (; v > 0; v--) { if (c + hist[v] >= r) break; c += hist[v]; }
            sr = r - c;
            sprefix = pfx | ((unsigned)v << (b * 8));
        }
        __syncthreads();
    }
    if (threadIdx.x == 0) { kth_out[g] = sprefix; eqneed_out[g] = sr; }
}

// deterministic index-order compaction of the selected set (ties: lower index first)
__global__ __launch_bounds__(256) void k_compact(
    const unsigned* __restrict__ keys, const float* __restrict__ sc,
    int n_per, int k, const unsigned* __restrict__ kth, const int* __restrict__ eqneed,
    int* __restrict__ node_map, int* __restrict__ sel_old, float* __restrict__ vals) {
    int g = blockIdx.x, tid = threadIdx.x;
    const unsigned* kk = keys + (size_t)g * n_per;
    const float* ss = sc + (size_t)g * n_per;
    unsigned K = kth[g];
    int need = eqneed[g];
    __shared__ int s1[256], s2[256];
    __shared__ int carry_pos, carry_eq;
    if (tid == 0) { carry_pos = 0; carry_eq = 0; }
    __syncthreads();
    int nchunks = (n_per + 255) / 256;
    for (int ch = 0; ch < nchunks; ch++) {
        int i = ch * 256 + tid;
        int is_eq = 0, is_gt = 0;
        if (i < n_per) {
            unsigned key = kk[i];
            is_gt = key > K;
            is_eq = key == K;
        }
        s1[tid] = is_eq;
        __syncthreads();
        for (int off = 1; off < 256; off <<= 1) {
            int v = s1[tid] + ((tid >= off) ? s1[tid - off] : 0);
            __syncthreads();
            s1[tid] = v;
            __syncthreads();
        }
        int eq_excl = s1[tid] - is_eq;
        int sel = is_gt || (is_eq && (carry_eq + eq_excl) < need);
        s2[tid] = sel;
        __syncthreads();
        for (int off = 1; off < 256; off <<= 1) {
            int v = s2[tid] + ((tid >= off) ? s2[tid - off] : 0);
            __syncthreads();
            s2[tid] = v;
            __syncthreads();
        }
        int pos = carry_pos + s2[tid] - sel;
        if (i < n_per) {
            if (sel) {
                int ni = g * k + pos;
                node_map[(size_t)g * n_per + i] = ni;
                sel_old[ni] = g * n_per + i;
                vals[ni] = ss[i];
            } else {
                node_map[(size_t)g * n_per + i] = -1;
            }
        }
        __syncthreads();
        if (tid == 0) { carry_pos += s2[255]; carry_eq += s1[255]; }
        __syncthreads();
    }
}

__global__ void k_gather(const float* __restrict__ h, const int* __restrict__ sel_old,
                         const float* __restrict__ vals, float* __restrict__ xout, int m) {
    long t = blockIdx.x * (long)blockDim.x + threadIdx.x;
    int i = (int)(t >> 5), lane = (int)(t & 31);
    if (i >= m) return;
    int oi = sel_old[i];
    float v = vals[i];
    float4 r = ((const float4*)(h + (size_t)oi * F))[lane];
    r.x *= v; r.y *= v; r.z *= v; r.w *= v;
    ((float4*)(xout + (size_t)i * F))[lane] = r;
}

__global__ void k_partial(const float* __restrict__ x, int k, float* __restrict__ part) {
    int g = blockIdx.x / SPLIT, s = blockIdx.x % SPLIT;
    int f = threadIdx.x;                 // 128 threads
    int rows = (k + SPLIT - 1) / SPLIT;
    int r0 = s * rows, r1 = min(k, r0 + rows);
    float sum = 0.0f, mx = -INFINITY;
    for (int r = r0; r < r1; r++) {
        float v = x[((size_t)(g * k + r)) * F + f];
        sum += v;
        mx = fmaxf(mx, v);
    }
    part[((size_t)(g * SPLIT + s) * 2 + 0) * F + f] = sum;
    part[((size_t)(g * SPLIT + s) * 2 + 1) * F + f] = mx;
}

__global__ void k_sumreduce(const float* __restrict__ part, int k, float* __restrict__ summary) {
    int g = blockIdx.x, f = threadIdx.x; // 128 threads
    float sum = 0.0f, mx = -INFINITY;
    for (int s = 0; s < SPLIT; s++) {
        sum += part[((size_t)(g * SPLIT + s) * 2 + 0) * F + f];
        mx = fmaxf(mx, part[((size_t)(g * SPLIT + s) * 2 + 1) * F + f]);
    }
    summary[g * 2 * F + f] += sum / (float)k;
    summary[g * 2 * F + F + f] += mx;
}

__global__ void k_out(const float* __restrict__ summary, const float* __restrict__ W,
                      const float* __restrict__ bias, float* __restrict__ out) {
    int g = blockIdx.x, j = threadIdx.x;  // 8 blocks x 64 threads
    float acc = bias[j];
    for (int t = 0; t < 2 * F; t++) acc += summary[g * 2 * F + t] * W[j * 2 * F + t];
    out[g * OUTD + j] = acc;
}

// ---------------- host launch ----------------
static inline int cdiv(long a, long b) { return (int)((a + b - 1) / b); }

extern "C" void kernel_launch(void* const* d_in, const int* in_sizes, int n_in,
                              void* d_out, int out_size, void* d_ws, size_t ws_size,
                              hipStream_t stream) {
    const float* x_in = (const float*)d_in[0];
    const int* ei     = (const int*)d_in[1];    // [2, E] -> src = ei, dst = ei+E
    const float* w1lW = (const float*)d_in[2];
    const float* w1lb = (const float*)d_in[3];
    const float* w1rW = (const float*)d_in[4];
    const float* p1w  = (const float*)d_in[5];
    const float* w2lW = (const float*)d_in[6];
    const float* w2lb = (const float*)d_in[7];
    const float* w2rW = (const float*)d_in[8];
    const float* p2w  = (const float*)d_in[9];
    const float* w3lW = (const float*)d_in[10];
    const float* w3lb = (const float*)d_in[11];
    const float* w3rW = (const float*)d_in[12];
    const float* p3w  = (const float*)d_in[13];
    const float* outW = (const float*)d_in[14];
    const float* outb = (const float*)d_in[15];
    float* out = (float*)d_out;

    float* ws = (float*)d_ws;
    float* bufA  = ws + OFF_A;
    float* bufX2 = ws + OFF_X2;
    float* sc    = ws + OFF_SC;
    unsigned* key = (unsigned*)(ws + OFF_KEY);
    int* nmap1   = (int*)(ws + OFF_MAP);    // stage-1 map; becomes composed map
    int* nmap2   = (int*)(ws + OFF_MAP2);   // stage-2 map; stage-3 scratch map
    int* selo    = (int*)(ws + OFF_SEL);
    float* vals  = ws + OFF_VAL;
    int* csr     = (int*)(ws + OFF_CSR);
    float* part    = ws + OFF_PART;
    float* summary = ws + OFF_SUM;
    int* misc_i    = (int*)(ws + OFF_MISC);
    unsigned* kth = (unsigned*)(misc_i + 4);
    int* eqneed   = misc_i + 12;
    float* normv  = (float*)(misc_i + 20);
    int* hist = (int*)(ws + OFF_HIST);
    int* incl = (int*)(ws + OFF_INCL);
    int* bsum = (int*)(ws + OFF_BSUM);
    int* rs   = (int*)(ws + OFF_RS);
    int* cur  = (int*)(ws + OFF_CUR);

    float* x3   = bufA + (size_t)N1 * F;   // 20000x128 region
    float* agg3 = bufA + (size_t)(N1 + N2) * F;
    float* x4   = bufA;                    // 10000x128 region (h2 dead by then)

    const int eg = cdiv(E, 256);           // edge-grid (1 thread/edge)
    const int* esrc = ei;
    const int* edst = ei + E;

    k_init<<<8, 256, 0, stream>>>(summary);

    // ================= stage 1 =================
    {
        int n = N0, nb = cdiv(n, 256);
        k_zero_i<<<nb, 256, 0, stream>>>(hist, n);
        k_norm<<<1, 64, 0, stream>>>(p1w, normv);
        k_hist_d<<<eg, 256, 0, stream>>>(edst, hist);
        k_scan1<<<nb, 256, 0, stream>>>(hist, n, incl, bsum);
        k_scan2<<<1, 512, 0, stream>>>(bsum, nb);
        k_scan3<<<nb, 256, 0, stream>>>(hist, incl, bsum, n, rs, cur);
        k_csr_d<<<eg, 256, 0, stream>>>(esrc, edst, cur, csr);
        k_agg2<<<cdiv((long)n * 32, 256), 256, 0, stream>>>(x_in, rs, csr, bufA, n);
        k_sage<<<cdiv(n, 64), 256, 0, stream>>>(x_in, bufA, rs, w1lW, w1lb, w1rW, bufA, n, 0);
        k_scores<<<cdiv(n, 256), 256, 0, stream>>>(bufA, p1w, normv, sc, key, n);
        k_select<<<B, 256, 0, stream>>>(key, NPG, K1, kth, eqneed);
        k_compact<<<B, 256, 0, stream>>>(key, sc, NPG, K1, kth, eqneed, nmap1, selo, vals);
        k_gather<<<cdiv((long)N1 * 32, 256), 256, 0, stream>>>(bufA, selo, vals, bufX2, N1);
        k_partial<<<B * SPLIT, F, 0, stream>>>(bufX2, K1, part);
        k_sumreduce<<<B, F, 0, stream>>>(part, K1, summary);
    }

    // ================= stage 2 (edges = original list + nmap1) =================
    {
        int n = N1, nb = cdiv(n, 256);
        k_zero_i<<<nb, 256, 0, stream>>>(hist, n);
        k_norm<<<1, 64, 0, stream>>>(p2w, normv);
        k_hist_m<<<eg, 256, 0, stream>>>(esrc, edst, nmap1, hist);
        k_scan1<<<nb, 256, 0, stream>>>(hist, n, incl, bsum);
        k_scan2<<<1, 512, 0, stream>>>(bsum, nb);
        k_scan3<<<nb, 256, 0, stream>>>(hist, incl, bsum, n, rs, cur);
        k_csr_m<<<eg, 256, 0, stream>>>(esrc, edst, nmap1, cur, csr);
        k_agg2<<<cdiv((long)n * 32, 256), 256, 0, stream>>>(bufX2, rs, csr, bufA, n);
        k_sage<<<cdiv(n, 64), 256, 0, stream>>>(bufX2, bufA, rs, w2lW, w2lb, w2rW, bufA, n, 1);
        k_scores<<<cdiv(n, 256), 256, 0, stream>>>(bufA, p2w, normv, sc, key, n);
        k_select<<<B, 256, 0, stream>>>(key, K1, K2, kth, eqneed);
        k_compact<<<B, 256, 0, stream>>>(key, sc, K1, K2, kth, eqneed, nmap2, selo, vals);
        k_gather<<<cdiv((long)N2 * 32, 256), 256, 0, stream>>>(bufA, selo, vals, x3, N2);
        k_partial<<<B * SPLIT, F, 0, stream>>>(x3, K2, part);
        k_sumreduce<<<B, F, 0, stream>>>(part, K2, summary);
        // fold stage-2 selection into the stage-1 map (in-place)
        k_compose<<<cdiv(N0, 256), 256, 0, stream>>>(nmap1, nmap2, N0);
    }

    // ================= stage 3 (edges = original list + composed map) =================
    {
        int n = N2, nb = cdiv(n, 256);
        k_zero_i<<<nb, 256, 0, stream>>>(hist, n);
        k_norm<<<1, 64, 0, stream>>>(p3w, normv);
        k_hist_m<<<eg, 256, 0, stream>>>(esrc, edst, nmap1, hist);
        k_scan1<<<nb, 256, 0, stream>>>(hist, n, incl, bsum);
        k_scan2<<<1, 512, 0, stream>>>(bsum, nb);
        k_scan3<<<nb, 256, 0, stream>>>(hist, incl, bsum, n, rs, cur);
        k_csr_m<<<eg, 256, 0, stream>>>(esrc, edst, nmap1, cur, csr);
        k_agg2<<<cdiv((long)n * 32, 256), 256, 0, stream>>>(x3, rs, csr, agg3, n);
        k_sage<<<cdiv(n, 64), 256, 0, stream>>>(x3, agg3, rs, w3lW, w3lb, w3rW, agg3, n, 0);
        k_scores<<<cdiv(n, 256), 256, 0, stream>>>(agg3, p3w, normv, sc, key, n);
        k_select<<<B, 256, 0, stream>>>(key, K2, K3, kth, eqneed);
        k_compact<<<B, 256, 0, stream>>>(key, sc, K2, K3, kth, eqneed, nmap2, selo, vals);
        k_gather<<<cdiv((long)N3 * 32, 256), 256, 0, stream>>>(agg3, selo, vals, x4, N3);
        k_partial<<<B * SPLIT, F, 0, stream>>>(x4, K3, part);
        k_sumreduce<<<B, F, 0, stream>>>(part, K3, summary);
    }

    // ================= output =================
    k_out<<<B, OUTD, 0, stream>>>(summary, outW, outb, out);
}

// Round 4
// 648.694 us; speedup vs baseline: 6.2400x; 1.6818x over previous
//
#include <hip/hip_runtime.h>
#include <hip/hip_bf16.h>
#include <math.h>

// ---------------- problem constants ----------------
constexpr int B    = 8;
constexpr int NPG  = 10000;           // nodes per graph (stage 1)
constexpr int F    = 128;             // feature dim (F_IN == H == 128)
constexpr int OUTD = 64;
constexpr int E    = B * NPG * 16;    // 1,280,000 edges
constexpr int N0   = B * NPG;         // 80000
constexpr int K1   = 5000, K2 = 2500, K3 = 1250;
constexpr int N1   = B * K1;          // 40000
constexpr int N2   = B * K2;          // 20000
constexpr int N3   = B * K3;          // 10000
constexpr int SPLIT = 16;             // summarize row-split

// ---------------- ws layout (float units) ----------------
// IN slab: [80000][256] bf16 = (mean | x) combined GEMM input. Stage s+1's
// buffer aliases the slab (stage-s IN is dead once sage_s has run).
constexpr size_t OFF_IN   = 0;
constexpr size_t SZ_IN    = (size_t)N0 * 256 / 2;       // bf16 pairs -> floats
constexpr size_t OFF_HB   = OFF_IN + SZ_IN;             // h bf16 [80000][128]
constexpr size_t SZ_HB    = (size_t)N0 * F / 2;
constexpr size_t OFF_SC   = OFF_HB + SZ_HB;             // 80000 f32
constexpr size_t OFF_KEY  = OFF_SC + N0;                // 80000 u32
constexpr size_t OFF_MAP  = OFF_KEY + N0;               // 80000 i32 (nmap1/composed)
constexpr size_t OFF_MAP2 = OFF_MAP + N0;               // 40000 i32
constexpr size_t OFF_SEL  = OFF_MAP2 + N1;              // 40000 i32
constexpr size_t OFF_VAL  = OFF_SEL + N1;               // 40000 f32
constexpr size_t OFF_CSR  = OFF_VAL + N1;               // E i32
constexpr size_t OFF_HIST = OFF_CSR + E;                // N0 i32
constexpr size_t OFF_INCL = OFF_HIST + N0;              // N0 i32
constexpr size_t OFF_BSUM = OFF_INCL + N0;              // 512 i32
constexpr size_t OFF_RS   = OFF_BSUM + 512;             // N0+1 i32 (+pad)
constexpr size_t OFF_CUR  = OFF_RS + N0 + 64;           // N0 i32
constexpr size_t OFF_PART = OFF_CUR + N0;               // B*SPLIT*2*128 f32
constexpr size_t OFF_SUM  = OFF_PART + (size_t)B * SPLIT * 2 * F;
constexpr size_t OFF_WCAT = OFF_SUM + (size_t)B * 2 * F; // [128][256] bf16
constexpr size_t OFF_MISC = OFF_WCAT + 128 * 256 / 2;
// misc: [4..11] kth keys, [12..19] eq_needed, [20] norm

typedef __attribute__((ext_vector_type(8))) short short8;
typedef __attribute__((ext_vector_type(4))) float floatx4;

// ---------------- helpers ----------------
__device__ inline unsigned f2key(float f) {
    unsigned u = __float_as_uint(f);
    return (u & 0x80000000u) ? ~u : (u | 0x80000000u);
}
__device__ inline unsigned short f2b(float f) {      // RNE f32->bf16
    unsigned u = __float_as_uint(f);
    return (unsigned short)((u + 0x7FFFu + ((u >> 16) & 1u)) >> 16);
}
__device__ inline float b2f(unsigned short u) {
    return __uint_as_float((unsigned)u << 16);
}

// ---------------- kernels ----------------
__global__ void k_init(float* summary) {
    int t = blockIdx.x * blockDim.x + threadIdx.x;
    if (t < B * 2 * F) summary[t] = 0.0f;
}

__global__ void k_norm(const float* __restrict__ w, float* out) {
    int t = threadIdx.x;               // 64 threads
    float v = 0.0f;
    for (int j = t; j < F; j += 64) { float a = w[j]; v += a * a; }
    for (int o = 32; o > 0; o >>= 1) v += __shfl_down(v, o);
    if (t == 0) *out = sqrtf(v);
}

// Wcat[o][0..127] = Wl[o][:], Wcat[o][128..255] = Wr[o][:]  (bf16)
__global__ void k_wcat(const float* __restrict__ Wl, const float* __restrict__ Wr,
                       unsigned short* __restrict__ Wcat) {
    int t = blockIdx.x * blockDim.x + threadIdx.x;   // 8192 threads, 4 elems each
    int idx = t * 4;
    if (idx >= 128 * 256) return;
    int o = idx >> 8, k = idx & 255;
    const float* p = (k < 128) ? (Wl + o * 128 + k) : (Wr + o * 128 + (k - 128));
    float4 v = *(const float4*)p;
    ushort4 u;
    u.x = f2b(v.x); u.y = f2b(v.y); u.z = f2b(v.z); u.w = f2b(v.w);
    *(ushort4*)(Wcat + idx) = u;
}

// x f32 -> bf16 into IN slab x-half
__global__ void k_cvt(const float* __restrict__ x, unsigned short* __restrict__ IN, int n) {
    long t = blockIdx.x * (long)blockDim.x + threadIdx.x;
    int i = (int)(t >> 5), lane = (int)(t & 31);
    if (i >= n) return;
    float4 v = ((const float4*)(x + (size_t)i * F))[lane];
    ushort4 u;
    u.x = f2b(v.x); u.y = f2b(v.y); u.z = f2b(v.z); u.w = f2b(v.w);
    *(ushort4*)(IN + (size_t)i * 256 + 128 + lane * 4) = u;
}

// -------- CSR build: histogram -> 3-kernel scan -> cursor scatter --------
__global__ void k_hist_d(const int* __restrict__ dst, int* __restrict__ hist) {
    int e = blockIdx.x * blockDim.x + threadIdx.x;
    if (e >= E) return;
    atomicAdd(&hist[dst[e]], 1);
}

__global__ void k_hist_m(const int* __restrict__ src, const int* __restrict__ dst,
                         const int* __restrict__ map, int* __restrict__ hist) {
    int e = blockIdx.x * blockDim.x + threadIdx.x;
    if (e >= E) return;
    int a = map[src[e]], b = map[dst[e]];
    if (a >= 0 && b >= 0) atomicAdd(&hist[b], 1);
}

__global__ __launch_bounds__(256) void k_scan1(const int* __restrict__ in, int n,
                                               int* __restrict__ incl, int* __restrict__ bsum) {
    __shared__ int s[256];
    int i = blockIdx.x * 256 + threadIdx.x;
    int v = (i < n) ? in[i] : 0;
    s[threadIdx.x] = v;
    __syncthreads();
    for (int off = 1; off < 256; off <<= 1) {
        int t = s[threadIdx.x] + ((threadIdx.x >= off) ? s[threadIdx.x - off] : 0);
        __syncthreads();
        s[threadIdx.x] = t;
        __syncthreads();
    }
    if (i < n) incl[i] = s[threadIdx.x];
    if (threadIdx.x == 255) bsum[blockIdx.x] = s[255];
}

__global__ __launch_bounds__(512) void k_scan2(int* __restrict__ bsum, int nb) {
    __shared__ int s[512];
    int t = threadIdx.x;
    int v = (t < nb) ? bsum[t] : 0;
    s[t] = v;
    __syncthreads();
    for (int off = 1; off < 512; off <<= 1) {
        int u = s[t] + ((t >= off) ? s[t - off] : 0);
        __syncthreads();
        s[t] = u;
        __syncthreads();
    }
    if (t < nb) bsum[t] = s[t] - v;   // exclusive
}

__global__ void k_scan3(const int* __restrict__ in, const int* __restrict__ incl,
                        const int* __restrict__ bsum, int n,
                        int* __restrict__ rowstart, int* __restrict__ cursor) {
    int i = blockIdx.x * 256 + threadIdx.x;
    if (i >= n) return;
    int ex = incl[i] - in[i] + bsum[blockIdx.x];
    rowstart[i] = ex;
    cursor[i] = ex;
    if (i == n - 1) rowstart[n] = ex + in[i];
}

__global__ void k_csr_d(const int* __restrict__ src, const int* __restrict__ dst,
                        int* __restrict__ cursor, int* __restrict__ csr) {
    int e = blockIdx.x * blockDim.x + threadIdx.x;
    if (e >= E) return;
    int p = atomicAdd(&cursor[dst[e]], 1);
    csr[p] = src[e];
}

__global__ void k_csr_m(const int* __restrict__ src, const int* __restrict__ dst,
                        const int* __restrict__ map,
                        int* __restrict__ cursor, int* __restrict__ csr) {
    int e = blockIdx.x * blockDim.x + threadIdx.x;
    if (e >= E) return;
    int a = map[src[e]], b = map[dst[e]];
    if (a >= 0 && b >= 0) {
        int p = atomicAdd(&cursor[b], 1);
        csr[p] = a;
    }
}

__global__ void k_compose(int* __restrict__ m1, const int* __restrict__ m2, int n) {
    int i = blockIdx.x * blockDim.x + threadIdx.x;
    if (i >= n) return;
    int a = m1[i];
    m1[i] = (a >= 0) ? m2[a] : -1;
}

// gather-aggregate in bf16: reads x-half of IN, writes mean into mean-half
__global__ __launch_bounds__(256) void k_agg2b(unsigned short* __restrict__ IN,
                                               const int* __restrict__ rowstart,
                                               const int* __restrict__ csr, int n) {
    int t = blockIdx.x * blockDim.x + threadIdx.x;
    int i = t >> 5, lane = t & 31;
    if (i >= n) return;
    int b = rowstart[i], e = rowstart[i + 1];
    float a0 = 0, a1 = 0, a2 = 0, a3 = 0;
    int j = b;
    for (; j + 2 <= e; j += 2) {
        int s0 = csr[j], s1 = csr[j + 1];
        ushort4 u0 = *(const ushort4*)(IN + (size_t)s0 * 256 + 128 + lane * 4);
        ushort4 u1 = *(const ushort4*)(IN + (size_t)s1 * 256 + 128 + lane * 4);
        a0 += b2f(u0.x) + b2f(u1.x); a1 += b2f(u0.y) + b2f(u1.y);
        a2 += b2f(u0.z) + b2f(u1.z); a3 += b2f(u0.w) + b2f(u1.w);
    }
    if (j < e) {
        int s0 = csr[j];
        ushort4 u0 = *(const ushort4*)(IN + (size_t)s0 * 256 + 128 + lane * 4);
        a0 += b2f(u0.x); a1 += b2f(u0.y); a2 += b2f(u0.z); a3 += b2f(u0.w);
    }
    float rd = 1.0f / fmaxf((float)(e - b), 1.0f);
    ushort4 o;
    o.x = f2b(a0 * rd); o.y = f2b(a1 * rd); o.z = f2b(a2 * rd); o.w = f2b(a3 * rd);
    *(ushort4*)(IN + (size_t)i * 256 + lane * 4) = o;
}

// MFMA SAGE: h = IN[n x 256] @ Wcat[128 x 256]^T + bias (opt relu), fused scores.
// A frag: row = lane&15, k = 8*(lane>>4)+j. B frag: col = lane&15, same k.
// D frag: col = lane&15, row = 4*(lane>>4)+reg  (m89-verified mapping).
__global__ __launch_bounds__(256) void k_sage_b(
    const unsigned short* __restrict__ IN, const unsigned short* __restrict__ Wcat,
    const float* __restrict__ bias, const float* __restrict__ poolw,
    const float* __restrict__ normv,
    unsigned short* __restrict__ hb, float* __restrict__ sc,
    unsigned* __restrict__ key, int n, int relu) {
    __shared__ float lds[64][132];
    int tid = threadIdx.x;
    int wid = tid >> 6, lane = tid & 63;
    int q = lane >> 4, l15 = lane & 15;
    int rowbase = blockIdx.x * 64 + wid * 16;

    floatx4 acc[8];
#pragma unroll
    for (int c = 0; c < 8; c++) acc[c] = (floatx4){0.f, 0.f, 0.f, 0.f};

    const unsigned short* abase = IN + (size_t)(rowbase + l15) * 256 + q * 8;
    const unsigned short* bbase = Wcat + (size_t)l15 * 256 + q * 8;
#pragma unroll
    for (int ks = 0; ks < 8; ks++) {
        short8 a = *(const short8*)(abase + (ks << 5));
#pragma unroll
        for (int c = 0; c < 8; c++) {
            short8 b = *(const short8*)(bbase + (c << 12) + (ks << 5));
            acc[c] = __builtin_amdgcn_mfma_f32_16x16x32_bf16(a, b, acc[c], 0, 0, 0);
        }
    }

    // epilogue: bias (+relu), fused pool-score partials, stage h into LDS
    float p0 = 0, p1 = 0, p2 = 0, p3 = 0;
#pragma unroll
    for (int c = 0; c < 8; c++) {
        int col = (c << 4) + l15;
        float bv = bias[col];
        float wv = poolw[col];
        floatx4 v = acc[c];
        v[0] += bv; v[1] += bv; v[2] += bv; v[3] += bv;
        if (relu) {
            v[0] = fmaxf(v[0], 0.f); v[1] = fmaxf(v[1], 0.f);
            v[2] = fmaxf(v[2], 0.f); v[3] = fmaxf(v[3], 0.f);
        }
        p0 += v[0] * wv; p1 += v[1] * wv; p2 += v[2] * wv; p3 += v[3] * wv;
        int lr = wid * 16 + q * 4;
        lds[lr + 0][col] = v[0];
        lds[lr + 1][col] = v[1];
        lds[lr + 2][col] = v[2];
        lds[lr + 3][col] = v[3];
    }
#pragma unroll
    for (int off = 1; off < 16; off <<= 1) {
        p0 += __shfl_xor(p0, off);
        p1 += __shfl_xor(p1, off);
        p2 += __shfl_xor(p2, off);
        p3 += __shfl_xor(p3, off);
    }
    if (l15 == 0) {
        float invn = 1.0f / (*normv);
        int r0 = rowbase + q * 4;
        float ps[4] = {p0, p1, p2, p3};
#pragma unroll
        for (int j = 0; j < 4; j++) {
            int r = r0 + j;
            if (r < n) {
                float s = tanhf(ps[j] * invn);
                sc[r] = s;
                key[r] = f2key(s);
            }
        }
    }
    __syncthreads();
    // coalesced bf16 store of h: 64 rows x 16 groups of 8 cols
#pragma unroll
    for (int it = 0; it < 4; it++) {
        int task = it * 256 + tid;
        int r = task >> 4, grp = task & 15;
        int gr = blockIdx.x * 64 + r;
        if (gr < n) {
            float4 lo = *(const float4*)&lds[r][grp * 8];
            float4 hi = *(const float4*)&lds[r][grp * 8 + 4];
            short8 u;
            u[0] = (short)f2b(lo.x); u[1] = (short)f2b(lo.y);
            u[2] = (short)f2b(lo.z); u[3] = (short)f2b(lo.w);
            u[4] = (short)f2b(hi.x); u[5] = (short)f2b(hi.y);
            u[6] = (short)f2b(hi.z); u[7] = (short)f2b(hi.w);
            *(short8*)(hb + (size_t)gr * 128 + grp * 8) = u;
        }
    }
}

// per-graph 4-pass radix select (1024 threads, parallel bin search)
__global__ __launch_bounds__(1024) void k_select(const unsigned* __restrict__ keys,
                                                 int n_per, int k,
                                                 unsigned* kth_out, int* eqneed_out) {
    int g = blockIdx.x, tid = threadIdx.x;
    const unsigned* kk = keys + (size_t)g * n_per;
    __shared__ int hist[256];
    __shared__ int suf[256];
    __shared__ unsigned sprefix;
    __shared__ int sr, sfound;
    if (tid == 0) { sprefix = 0; sr = k; }
    __syncthreads();
    for (int b = 3; b >= 0; b--) {
        if (tid < 256) hist[tid] = 0;
        __syncthreads();
        unsigned pfx = sprefix;
        unsigned maskhi = (b == 3) ? 0u : (0xFFFFFFFFu << ((b + 1) * 8));
        for (int i = tid; i < n_per; i += 1024) {
            unsigned kv = kk[i];
            if ((kv & maskhi) == (pfx & maskhi))
                atomicAdd(&hist[(kv >> (b * 8)) & 255], 1);
        }
        __syncthreads();
        if (tid < 256) suf[tid] = hist[tid];
        __syncthreads();
        for (int off = 1; off < 256; off <<= 1) {
            int t = 0;
            if (tid < 256) t = suf[tid] + ((tid + off < 256) ? suf[tid + off] : 0);
            __syncthreads();
            if (tid < 256) suf[tid] = t;
            __syncthreads();
        }
        int r = sr;
        if (tid < 256) {
            int hi = (tid == 255) ? 0 : suf[tid + 1];
            if (hi < r && suf[tid] >= r) sfound = tid;   // unique
        }
        __syncthreads();
        if (tid == 0) {
            int v = sfound;
            int hi = (v == 255) ? 0 : suf[v + 1];
            sr = r - hi;
            sprefix = pfx | ((unsigned)v << (b * 8));
        }
        __syncthreads();
    }
    if (tid == 0) { kth_out[g] = sprefix; eqneed_out[g] = sr; }
}

// deterministic index-order compaction, 1024 threads, wave-shfl scans
__global__ __launch_bounds__(1024) void k_compact(
    const unsigned* __restrict__ keys, const float* __restrict__ sc,
    int n_per, int k, const unsigned* __restrict__ kth, const int* __restrict__ eqneed,
    int* __restrict__ node_map, int* __restrict__ sel_old, float* __restrict__ vals) {
    int g = blockIdx.x, tid = threadIdx.x;
    int lane = tid & 63, wid = tid >> 6;      // 16 waves
    const unsigned* kk = keys + (size_t)g * n_per;
    const float* ss = sc + (size_t)g * n_per;
    unsigned K = kth[g];
    int need = eqneed[g];
    __shared__ int we[16], wsl[16], we2[16], ws2[16];
    __shared__ int carry_pos, carry_eq;
    if (tid == 0) { carry_pos = 0; carry_eq = 0; }
    __syncthreads();
    int nch = (n_per + 1023) >> 10;
    for (int ch = 0; ch < nch; ch++) {
        int i = (ch << 10) + tid;
        int valid = (i < n_per);
        unsigned kv = valid ? kk[i] : 0u;
        int is_gt = valid && (kv > K);
        int is_eq = valid && (kv == K);
        int e_incl = is_eq;
#pragma unroll
        for (int off = 1; off < 64; off <<= 1) {
            int t = __shfl_up(e_incl, off);
            e_incl += (lane >= off) ? t : 0;
        }
        if (lane == 63) we[wid] = e_incl;
        __syncthreads();
        if (tid < 16) {
            int v = we[tid];
#pragma unroll
            for (int off = 1; off < 16; off <<= 1) {
                int t = __shfl_up(v, off);
                v += (tid >= off) ? t : 0;
            }
            we2[tid] = v;
        }
        __syncthreads();
        int eq_before = carry_eq + (e_incl - is_eq) + (wid ? we2[wid - 1] : 0);
        int sel = is_gt || (is_eq && eq_before < need);
        int s_incl = sel;
#pragma unroll
        for (int off = 1; off < 64; off <<= 1) {
            int t = __shfl_up(s_incl, off);
            s_incl += (lane >= off) ? t : 0;
        }
        if (lane == 63) wsl[wid] = s_incl;
        __syncthreads();
        if (tid < 16) {
            int v = wsl[tid];
#pragma unroll
            for (int off = 1; off < 16; off <<= 1) {
                int t = __shfl_up(v, off);
                v += (tid >= off) ? t : 0;
            }
            ws2[tid] = v;
        }
        __syncthreads();
        int pos = carry_pos + (s_incl - sel) + (wid ? ws2[wid - 1] : 0);
        if (valid) {
            if (sel) {
                int ni = g * k + pos;
                node_map[(size_t)g * n_per + i] = ni;
                sel_old[ni] = g * n_per + i;
                vals[ni] = ss[i];
            } else {
                node_map[(size_t)g * n_per + i] = -1;
            }
        }
        __syncthreads();
        if (tid == 0) { carry_pos += ws2[15]; carry_eq += we2[15]; }
        __syncthreads();
    }
}

// gather selected h rows, scale by score, write bf16 into next IN x-half
__global__ void k_gatherb(const unsigned short* __restrict__ hb,
                          const int* __restrict__ sel_old,
                          const float* __restrict__ vals,
                          unsigned short* __restrict__ INnext, int m) {
    long t = blockIdx.x * (long)blockDim.x + threadIdx.x;
    int i = (int)(t >> 5), lane = (int)(t & 31);
    if (i >= m) return;
    int oi = sel_old[i];
    float v = vals[i];
    ushort4 u = *(const ushort4*)(hb + (size_t)oi * 128 + lane * 4);
    ushort4 o;
    o.x = f2b(b2f(u.x) * v); o.y = f2b(b2f(u.y) * v);
    o.z = f2b(b2f(u.z) * v); o.w = f2b(b2f(u.w) * v);
    *(ushort4*)(INnext + (size_t)i * 256 + 128 + lane * 4) = o;
}

__global__ void k_partialb(const unsigned short* __restrict__ IN, int k,
                           float* __restrict__ part) {
    int g = blockIdx.x / SPLIT, s = blockIdx.x % SPLIT;
    int f = threadIdx.x;                 // 128 threads
    int rows = (k + SPLIT - 1) / SPLIT;
    int r0 = s * rows, r1 = min(k, r0 + rows);
    float sum = 0.0f, mx = -INFINITY;
    for (int r = r0; r < r1; r++) {
        float v = b2f(IN[(size_t)(g * k + r) * 256 + 128 + f]);
        sum += v;
        mx = fmaxf(mx, v);
    }
    part[((size_t)(g * SPLIT + s) * 2 + 0) * F + f] = sum;
    part[((size_t)(g * SPLIT + s) * 2 + 1) * F + f] = mx;
}

__global__ void k_sumreduce(const float* __restrict__ part, int k, float* __restrict__ summary) {
    int g = blockIdx.x, f = threadIdx.x; // 128 threads
    float sum = 0.0f, mx = -INFINITY;
    for (int s = 0; s < SPLIT; s++) {
        sum += part[((size_t)(g * SPLIT + s) * 2 + 0) * F + f];
        mx = fmaxf(mx, part[((size_t)(g * SPLIT + s) * 2 + 1) * F + f]);
    }
    summary[g * 2 * F + f] += sum / (float)k;
    summary[g * 2 * F + F + f] += mx;
}

__global__ void k_out(const float* __restrict__ summary, const float* __restrict__ W,
                      const float* __restrict__ bias, float* __restrict__ out) {
    int g = blockIdx.x, j = threadIdx.x;  // 8 blocks x 64 threads
    float acc = bias[j];
    for (int t = 0; t < 2 * F; t++) acc += summary[g * 2 * F + t] * W[j * 2 * F + t];
    out[g * OUTD + j] = acc;
}

// ---------------- host launch ----------------
static inline int cdiv(long a, long b) { return (int)((a + b - 1) / b); }

extern "C" void kernel_launch(void* const* d_in, const int* in_sizes, int n_in,
                              void* d_out, int out_size, void* d_ws, size_t ws_size,
                              hipStream_t stream) {
    const float* x_in = (const float*)d_in[0];
    const int* ei     = (const int*)d_in[1];    // [2, E] -> src = ei, dst = ei+E
    const float* w1lW = (const float*)d_in[2];
    const float* w1lb = (const float*)d_in[3];
    const float* w1rW = (const float*)d_in[4];
    const float* p1w  = (const float*)d_in[5];
    const float* w2lW = (const float*)d_in[6];
    const float* w2lb = (const float*)d_in[7];
    const float* w2rW = (const float*)d_in[8];
    const float* p2w  = (const float*)d_in[9];
    const float* w3lW = (const float*)d_in[10];
    const float* w3lb = (const float*)d_in[11];
    const float* w3rW = (const float*)d_in[12];
    const float* p3w  = (const float*)d_in[13];
    const float* outW = (const float*)d_in[14];
    const float* outb = (const float*)d_in[15];
    float* out = (float*)d_out;

    float* ws = (float*)d_ws;
    unsigned short* INb  = (unsigned short*)(ws + OFF_IN);   // aliased per stage
    unsigned short* hb   = (unsigned short*)(ws + OFF_HB);
    float* sc    = ws + OFF_SC;
    unsigned* key = (unsigned*)(ws + OFF_KEY);
    int* nmap1   = (int*)(ws + OFF_MAP);
    int* nmap2   = (int*)(ws + OFF_MAP2);
    int* selo    = (int*)(ws + OFF_SEL);
    float* vals  = ws + OFF_VAL;
    int* csr     = (int*)(ws + OFF_CSR);
    int* hist = (int*)(ws + OFF_HIST);
    int* incl = (int*)(ws + OFF_INCL);
    int* bsum = (int*)(ws + OFF_BSUM);
    int* rs   = (int*)(ws + OFF_RS);
    int* cur  = (int*)(ws + OFF_CUR);
    float* part    = ws + OFF_PART;
    float* summary = ws + OFF_SUM;
    unsigned short* wcat = (unsigned short*)(ws + OFF_WCAT);
    int* misc_i    = (int*)(ws + OFF_MISC);
    unsigned* kth = (unsigned*)(misc_i + 4);
    int* eqneed   = misc_i + 12;
    float* normv  = (float*)(misc_i + 20);

    const int eg = cdiv(E, 256);
    const int* esrc = ei;
    const int* edst = ei + E;

    k_init<<<8, 256, 0, stream>>>(summary);

    // ================= stage 1 =================
    {
        int n = N0, nb = cdiv(n, 256);
        k_cvt<<<cdiv((long)n * 32, 256), 256, 0, stream>>>(x_in, INb, n);
        hipMemsetAsync(hist, 0, n * sizeof(int), stream);
        k_norm<<<1, 64, 0, stream>>>(p1w, normv);
        k_wcat<<<32, 256, 0, stream>>>(w1lW, w1rW, wcat);
        k_hist_d<<<eg, 256, 0, stream>>>(edst, hist);
        k_scan1<<<nb, 256, 0, stream>>>(hist, n, incl, bsum);
        k_scan2<<<1, 512, 0, stream>>>(bsum, nb);
        k_scan3<<<nb, 256, 0, stream>>>(hist, incl, bsum, n, rs, cur);
        k_csr_d<<<eg, 256, 0, stream>>>(esrc, edst, cur, csr);
        k_agg2b<<<cdiv((long)n * 32, 256), 256, 0, stream>>>(INb, rs, csr, n);
        k_sage_b<<<cdiv(n, 64), 256, 0, stream>>>(INb, wcat, w1lb, p1w, normv, hb, sc, key, n, 0);
        k_select<<<B, 1024, 0, stream>>>(key, NPG, K1, kth, eqneed);
        k_compact<<<B, 1024, 0, stream>>>(key, sc, NPG, K1, kth, eqneed, nmap1, selo, vals);
        // IN1 dead after sage -> IN2 aliases slab
        k_gatherb<<<cdiv((long)N1 * 32, 256), 256, 0, stream>>>(hb, selo, vals, INb, N1);
        k_partialb<<<B * SPLIT, F, 0, stream>>>(INb, K1, part);
        k_sumreduce<<<B, F, 0, stream>>>(part, K1, summary);
    }

    // ================= stage 2 (original edges + nmap1) =================
    {
        int n = N1, nb = cdiv(n, 256);
        hipMemsetAsync(hist, 0, n * sizeof(int), stream);
        k_norm<<<1, 64, 0, stream>>>(p2w, normv);
        k_wcat<<<32, 256, 0, stream>>>(w2lW, w2rW, wcat);
        k_hist_m<<<eg, 256, 0, stream>>>(esrc, edst, nmap1, hist);
        k_scan1<<<nb, 256, 0, stream>>>(hist, n, incl, bsum);
        k_scan2<<<1, 512, 0, stream>>>(bsum, nb);
        k_scan3<<<nb, 256, 0, stream>>>(hist, incl, bsum, n, rs, cur);
        k_csr_m<<<eg, 256, 0, stream>>>(esrc, edst, nmap1, cur, csr);
        k_agg2b<<<cdiv((long)n * 32, 256), 256, 0, stream>>>(INb, rs, csr, n);
        k_sage_b<<<cdiv(n, 64), 256, 0, stream>>>(INb, wcat, w2lb, p2w, normv, hb, sc, key, n, 1);
        k_select<<<B, 1024, 0, stream>>>(key, K1, K2, kth, eqneed);
        k_compact<<<B, 1024, 0, stream>>>(key, sc, K1, K2, kth, eqneed, nmap2, selo, vals);
        k_gatherb<<<cdiv((long)N2 * 32, 256), 256, 0, stream>>>(hb, selo, vals, INb, N2);
        k_partialb<<<B * SPLIT, F, 0, stream>>>(INb, K2, part);
        k_sumreduce<<<B, F, 0, stream>>>(part, K2, summary);
        k_compose<<<cdiv(N0, 256), 256, 0, stream>>>(nmap1, nmap2, N0);
    }

    // ================= stage 3 (original edges + composed map) =================
    {
        int n = N2, nb = cdiv(n, 256);
        hipMemsetAsync(hist, 0, n * sizeof(int), stream);
        k_norm<<<1, 64, 0, stream>>>(p3w, normv);
        k_wcat<<<32, 256, 0, stream>>>(w3lW, w3rW, wcat);
        k_hist_m<<<eg, 256, 0, stream>>>(esrc, edst, nmap1, hist);
        k_scan1<<<nb, 256, 0, stream>>>(hist, n, incl, bsum);
        k_scan2<<<1, 512, 0, stream>>>(bsum, nb);
        k_scan3<<<nb, 256, 0, stream>>>(hist, incl, bsum, n, rs, cur);
        k_csr_m<<<eg, 256, 0, stream>>>(esrc, edst, nmap1, cur, csr);
        k_agg2b<<<cdiv((long)n * 32, 256), 256, 0, stream>>>(INb, rs, csr, n);
        k_sage_b<<<cdiv(n, 64), 256, 0, stream>>>(INb, wcat, w3lb, p3w, normv, hb, sc, key, n, 0);
        k_select<<<B, 1024, 0, stream>>>(key, K2, K3, kth, eqneed);
        k_compact<<<B, 1024, 0, stream>>>(key, sc, K2, K3, kth, eqneed, nmap2, selo, vals);
        k_gatherb<<<cdiv((long)N3 * 32, 256), 256, 0, stream>>>(hb, selo, vals, INb, N3);
        k_partialb<<<B * SPLIT, F, 0, stream>>>(INb, K3, part);
        k_sumreduce<<<B, F, 0, stream>>>(part, K3, summary);
    }

    // ================= output =================
    k_out<<<B, OUTD, 0, stream>>>(summary, outW, outb, out);
}

// Round 5
// 536.829 us; speedup vs baseline: 7.5403x; 1.2084x over previous
//
#include <hip/hip_runtime.h>
#include <hip/hip_bf16.h>
#include <math.h>

// ---------------- problem constants ----------------
constexpr int B    = 8;
constexpr int NPG  = 10000;           // nodes per graph (stage 1)
constexpr int F    = 128;             // feature dim (F_IN == H == 128)
constexpr int OUTD = 64;
constexpr int E    = B * NPG * 16;    // 1,280,000 edges
constexpr int N0   = B * NPG;         // 80000
constexpr int K1   = 5000, K2 = 2500, K3 = 1250;
constexpr int N1   = B * K1;          // 40000
constexpr int N2   = B * K2;          // 20000
constexpr int N3   = B * K3;          // 10000
constexpr int PSPLIT = 256;           // summarize row-split (per graph)

// ---------------- ws layout (float units) ----------------
constexpr size_t OFF_IN   = 0;                          // [80000][256] bf16 (mean|x)
constexpr size_t SZ_IN    = (size_t)N0 * 256 / 2;
constexpr size_t OFF_HB   = OFF_IN + SZ_IN;             // h bf16 [80000][128]
constexpr size_t SZ_HB    = (size_t)N0 * F / 2;
constexpr size_t OFF_SC   = OFF_HB + SZ_HB;             // 80000 f32
constexpr size_t OFF_KEY  = OFF_SC + N0;                // 80000 u32
constexpr size_t OFF_MAP  = OFF_KEY + N0;               // 80000 i32
constexpr size_t OFF_MAP2 = OFF_MAP + N0;               // 40000 i32
constexpr size_t OFF_SEL  = OFF_MAP2 + N1;              // 40000 i32
constexpr size_t OFF_VAL  = OFF_SEL + N1;               // 40000 f32
constexpr size_t OFF_CSR  = OFF_VAL + N1;               // E i32
constexpr size_t OFF_HIST = OFF_CSR + E;                // N0 i32
constexpr size_t OFF_INCL = OFF_HIST + N0;              // N0 i32
constexpr size_t OFF_BSUM = OFF_INCL + N0;              // 512 i32
constexpr size_t OFF_RS   = OFF_BSUM + 512;             // N0+1 i32 (+pad)
constexpr size_t OFF_CUR  = OFF_RS + N0 + 64;           // N0 i32
constexpr size_t OFF_PART = OFF_CUR + N0;               // B*PSPLIT*2*128 f32
constexpr size_t OFF_SUM  = OFF_PART + (size_t)B * PSPLIT * 2 * F;
constexpr size_t OFF_WCAT = OFF_SUM + (size_t)B * 2 * F; // [128][256] bf16
constexpr size_t OFF_MISC = OFF_WCAT + 128 * 256 / 2;

typedef __attribute__((ext_vector_type(8))) short short8;
typedef __attribute__((ext_vector_type(4))) float floatx4;

// ---------------- helpers ----------------
__device__ inline unsigned f2key(float f) {
    unsigned u = __float_as_uint(f);
    return (u & 0x80000000u) ? ~u : (u | 0x80000000u);
}
__device__ inline unsigned short f2b(float f) {      // RNE f32->bf16
    unsigned u = __float_as_uint(f);
    return (unsigned short)((u + 0x7FFFu + ((u >> 16) & 1u)) >> 16);
}
__device__ inline float b2f(unsigned short u) {
    return __uint_as_float((unsigned)u << 16);
}

// ---------------- kernels ----------------
// norm (block 32) + Wcat bf16 concat (blocks 0..31)
__global__ void k_prep(const float* __restrict__ Wl, const float* __restrict__ Wr,
                       const float* __restrict__ poolw,
                       unsigned short* __restrict__ Wcat, float* __restrict__ normv) {
    if (blockIdx.x == 32) {
        int t = threadIdx.x;
        if (t < 64) {
            float v = 0.0f;
            for (int j = t; j < F; j += 64) { float a = poolw[j]; v += a * a; }
            for (int o = 32; o > 0; o >>= 1) v += __shfl_down(v, o);
            if (t == 0) *normv = sqrtf(v);
        }
        return;
    }
    int idx = (blockIdx.x * 256 + threadIdx.x) * 4;
    int o = idx >> 8, k = idx & 255;
    const float* p = (k < 128) ? (Wl + o * 128 + k) : (Wr + o * 128 + (k - 128));
    float4 v = *(const float4*)p;
    ushort4 u;
    u.x = f2b(v.x); u.y = f2b(v.y); u.z = f2b(v.z); u.w = f2b(v.w);
    *(ushort4*)(Wcat + idx) = u;
}

// x f32 -> bf16 into IN slab x-half
__global__ void k_cvt(const float* __restrict__ x, unsigned short* __restrict__ IN, int n) {
    long t = blockIdx.x * (long)blockDim.x + threadIdx.x;
    int i = (int)(t >> 5), lane = (int)(t & 31);
    if (i >= n) return;
    float4 v = ((const float4*)(x + (size_t)i * F))[lane];
    ushort4 u;
    u.x = f2b(v.x); u.y = f2b(v.y); u.z = f2b(v.z); u.w = f2b(v.w);
    *(ushort4*)(IN + (size_t)i * 256 + 128 + lane * 4) = u;
}

// -------- CSR build --------
__global__ void k_hist_d(const int* __restrict__ dst, int* __restrict__ hist) {
    int e = blockIdx.x * blockDim.x + threadIdx.x;
    if (e >= E) return;
    atomicAdd(&hist[dst[e]], 1);
}

__global__ void k_hist_m(const int* __restrict__ src, const int* __restrict__ dst,
                         const int* __restrict__ map, int* __restrict__ hist) {
    int e = blockIdx.x * blockDim.x + threadIdx.x;
    if (e >= E) return;
    int a = map[src[e]], b = map[dst[e]];
    if (a >= 0 && b >= 0) atomicAdd(&hist[b], 1);
}

__global__ __launch_bounds__(256) void k_scan1(const int* __restrict__ in, int n,
                                               int* __restrict__ incl, int* __restrict__ bsum) {
    __shared__ int s[256];
    int i = blockIdx.x * 256 + threadIdx.x;
    int v = (i < n) ? in[i] : 0;
    s[threadIdx.x] = v;
    __syncthreads();
    for (int off = 1; off < 256; off <<= 1) {
        int t = s[threadIdx.x] + ((threadIdx.x >= off) ? s[threadIdx.x - off] : 0);
        __syncthreads();
        s[threadIdx.x] = t;
        __syncthreads();
    }
    if (i < n) incl[i] = s[threadIdx.x];
    if (threadIdx.x == 255) bsum[blockIdx.x] = s[255];
}

__global__ __launch_bounds__(512) void k_scan2(int* __restrict__ bsum, int nb) {
    __shared__ int s[512];
    int t = threadIdx.x;
    int v = (t < nb) ? bsum[t] : 0;
    s[t] = v;
    __syncthreads();
    for (int off = 1; off < 512; off <<= 1) {
        int u = s[t] + ((t >= off) ? s[t - off] : 0);
        __syncthreads();
        s[t] = u;
        __syncthreads();
    }
    if (t < nb) bsum[t] = s[t] - v;   // exclusive
}

__global__ void k_scan3(const int* __restrict__ in, const int* __restrict__ incl,
                        const int* __restrict__ bsum, int n,
                        int* __restrict__ rowstart, int* __restrict__ cursor) {
    int i = blockIdx.x * 256 + threadIdx.x;
    if (i >= n) return;
    int ex = incl[i] - in[i] + bsum[blockIdx.x];
    rowstart[i] = ex;
    cursor[i] = ex;
    if (i == n - 1) rowstart[n] = ex + in[i];
}

__global__ void k_csr_d(const int* __restrict__ src, const int* __restrict__ dst,
                        int* __restrict__ cursor, int* __restrict__ csr) {
    int e = blockIdx.x * blockDim.x + threadIdx.x;
    if (e >= E) return;
    int p = atomicAdd(&cursor[dst[e]], 1);
    csr[p] = src[e];
}

__global__ void k_csr_m(const int* __restrict__ src, const int* __restrict__ dst,
                        const int* __restrict__ map,
                        int* __restrict__ cursor, int* __restrict__ csr) {
    int e = blockIdx.x * blockDim.x + threadIdx.x;
    if (e >= E) return;
    int a = map[src[e]], b = map[dst[e]];
    if (a >= 0 && b >= 0) {
        int p = atomicAdd(&cursor[b], 1);
        csr[p] = a;
    }
}

__global__ void k_compose(int* __restrict__ m1, const int* __restrict__ m2, int n) {
    int i = blockIdx.x * blockDim.x + threadIdx.x;
    if (i >= n) return;
    int a = m1[i];
    m1[i] = (a >= 0) ? m2[a] : -1;
}

// gather-aggregate bf16: reads x-half of IN, writes mean into mean-half
__global__ __launch_bounds__(256) void k_agg2b(unsigned short* __restrict__ IN,
                                               const int* __restrict__ rowstart,
                                               const int* __restrict__ csr, int n) {
    int t = blockIdx.x * blockDim.x + threadIdx.x;
    int i = t >> 5, lane = t & 31;
    if (i >= n) return;
    int b = rowstart[i], e = rowstart[i + 1];
    float a0 = 0, a1 = 0, a2 = 0, a3 = 0;
    int j = b;
    for (; j + 4 <= e; j += 4) {      // 4-way MLP
        int s0 = csr[j], s1 = csr[j + 1], s2 = csr[j + 2], s3 = csr[j + 3];
        ushort4 u0 = *(const ushort4*)(IN + (size_t)s0 * 256 + 128 + lane * 4);
        ushort4 u1 = *(const ushort4*)(IN + (size_t)s1 * 256 + 128 + lane * 4);
        ushort4 u2 = *(const ushort4*)(IN + (size_t)s2 * 256 + 128 + lane * 4);
        ushort4 u3 = *(const ushort4*)(IN + (size_t)s3 * 256 + 128 + lane * 4);
        a0 += (b2f(u0.x) + b2f(u1.x)) + (b2f(u2.x) + b2f(u3.x));
        a1 += (b2f(u0.y) + b2f(u1.y)) + (b2f(u2.y) + b2f(u3.y));
        a2 += (b2f(u0.z) + b2f(u1.z)) + (b2f(u2.z) + b2f(u3.z));
        a3 += (b2f(u0.w) + b2f(u1.w)) + (b2f(u2.w) + b2f(u3.w));
    }
    for (; j < e; j++) {
        int s0 = csr[j];
        ushort4 u0 = *(const ushort4*)(IN + (size_t)s0 * 256 + 128 + lane * 4);
        a0 += b2f(u0.x); a1 += b2f(u0.y); a2 += b2f(u0.z); a3 += b2f(u0.w);
    }
    float rd = 1.0f / fmaxf((float)(e - b), 1.0f);
    ushort4 o;
    o.x = f2b(a0 * rd); o.y = f2b(a1 * rd); o.z = f2b(a2 * rd); o.w = f2b(a3 * rd);
    *(ushort4*)(IN + (size_t)i * 256 + lane * 4) = o;
}

// MFMA SAGE + fused scores (m89-verified fragment mapping)
__global__ __launch_bounds__(256) void k_sage_b(
    const unsigned short* __restrict__ IN, const unsigned short* __restrict__ Wcat,
    const float* __restrict__ bias, const float* __restrict__ poolw,
    const float* __restrict__ normv,
    unsigned short* __restrict__ hb, float* __restrict__ sc,
    unsigned* __restrict__ key, int n, int relu) {
    __shared__ float lds[64][132];
    int tid = threadIdx.x;
    int wid = tid >> 6, lane = tid & 63;
    int q = lane >> 4, l15 = lane & 15;
    int rowbase = blockIdx.x * 64 + wid * 16;

    floatx4 acc[8];
#pragma unroll
    for (int c = 0; c < 8; c++) acc[c] = (floatx4){0.f, 0.f, 0.f, 0.f};

    const unsigned short* abase = IN + (size_t)(rowbase + l15) * 256 + q * 8;
    const unsigned short* bbase = Wcat + (size_t)l15 * 256 + q * 8;
#pragma unroll
    for (int ks = 0; ks < 8; ks++) {
        short8 a = *(const short8*)(abase + (ks << 5));
#pragma unroll
        for (int c = 0; c < 8; c++) {
            short8 b = *(const short8*)(bbase + (c << 12) + (ks << 5));
            acc[c] = __builtin_amdgcn_mfma_f32_16x16x32_bf16(a, b, acc[c], 0, 0, 0);
        }
    }

    float p0 = 0, p1 = 0, p2 = 0, p3 = 0;
#pragma unroll
    for (int c = 0; c < 8; c++) {
        int col = (c << 4) + l15;
        float bv = bias[col];
        float wv = poolw[col];
        floatx4 v = acc[c];
        v[0] += bv; v[1] += bv; v[2] += bv; v[3] += bv;
        if (relu) {
            v[0] = fmaxf(v[0], 0.f); v[1] = fmaxf(v[1], 0.f);
            v[2] = fmaxf(v[2], 0.f); v[3] = fmaxf(v[3], 0.f);
        }
        p0 += v[0] * wv; p1 += v[1] * wv; p2 += v[2] * wv; p3 += v[3] * wv;
        int lr = wid * 16 + q * 4;
        lds[lr + 0][col] = v[0];
        lds[lr + 1][col] = v[1];
        lds[lr + 2][col] = v[2];
        lds[lr + 3][col] = v[3];
    }
#pragma unroll
    for (int off = 1; off < 16; off <<= 1) {
        p0 += __shfl_xor(p0, off);
        p1 += __shfl_xor(p1, off);
        p2 += __shfl_xor(p2, off);
        p3 += __shfl_xor(p3, off);
    }
    if (l15 == 0) {
        float invn = 1.0f / (*normv);
        int r0 = rowbase + q * 4;
        float ps[4] = {p0, p1, p2, p3};
#pragma unroll
        for (int j = 0; j < 4; j++) {
            int r = r0 + j;
            if (r < n) {
                float s = tanhf(ps[j] * invn);
                sc[r] = s;
                key[r] = f2key(s);
            }
        }
    }
    __syncthreads();
#pragma unroll
    for (int it = 0; it < 4; it++) {
        int task = it * 256 + tid;
        int r = task >> 4, grp = task & 15;
        int gr = blockIdx.x * 64 + r;
        if (gr < n) {
            float4 lo = *(const float4*)&lds[r][grp * 8];
            float4 hi = *(const float4*)&lds[r][grp * 8 + 4];
            short8 u;
            u[0] = (short)f2b(lo.x); u[1] = (short)f2b(lo.y);
            u[2] = (short)f2b(lo.z); u[3] = (short)f2b(lo.w);
            u[4] = (short)f2b(hi.x); u[5] = (short)f2b(hi.y);
            u[6] = (short)f2b(hi.z); u[7] = (short)f2b(hi.w);
            *(short8*)(hb + (size_t)gr * 128 + grp * 8) = u;
        }
    }
}

// merged per-graph top-k: radix select (kth key + eq-needed) then
// deterministic index-order compaction. 1024 threads/graph.
__global__ __launch_bounds__(1024) void k_topk(
    const unsigned* __restrict__ keys, const float* __restrict__ sc,
    int n_per, int k,
    int* __restrict__ node_map, int* __restrict__ sel_old, float* __restrict__ vals) {
    int g = blockIdx.x, tid = threadIdx.x;
    int lane = tid & 63, wid = tid >> 6;      // 16 waves
    const unsigned* kk = keys + (size_t)g * n_per;
    const float* ss = sc + (size_t)g * n_per;
    __shared__ int hist[256];
    __shared__ int suf[256];
    __shared__ unsigned sprefix;
    __shared__ int sr, sfound;
    __shared__ int we2[16], ws2[16];
    __shared__ int carry_pos, carry_eq;
    if (tid == 0) { sprefix = 0; sr = k; carry_pos = 0; carry_eq = 0; }
    __syncthreads();

    // ---- phase 1: radix select ----
    for (int b = 3; b >= 0; b--) {
        if (tid < 256) hist[tid] = 0;
        __syncthreads();
        unsigned pfx = sprefix;
        unsigned maskhi = (b == 3) ? 0u : (0xFFFFFFFFu << ((b + 1) * 8));
        for (int i = tid; i < n_per; i += 1024) {
            unsigned kv = kk[i];
            if ((kv & maskhi) == (pfx & maskhi))
                atomicAdd(&hist[(kv >> (b * 8)) & 255], 1);
        }
        __syncthreads();
        if (tid < 256) suf[tid] = hist[tid];
        __syncthreads();
        for (int off = 1; off < 256; off <<= 1) {
            int t = 0;
            if (tid < 256) t = suf[tid] + ((tid + off < 256) ? suf[tid + off] : 0);
            __syncthreads();
            if (tid < 256) suf[tid] = t;
            __syncthreads();
        }
        int r = sr;
        if (tid < 256) {
            int hi = (tid == 255) ? 0 : suf[tid + 1];
            if (hi < r && suf[tid] >= r) sfound = tid;   // unique
        }
        __syncthreads();
        if (tid == 0) {
            int v = sfound;
            int hi = (v == 255) ? 0 : suf[v + 1];
            sr = r - hi;
            sprefix = pfx | ((unsigned)v << (b * 8));
        }
        __syncthreads();
    }
    unsigned K = sprefix;
    int need = sr;
    __syncthreads();

    // ---- phase 2: compaction (ties: lower index first) ----
    int nch = (n_per + 1023) >> 10;
    for (int ch = 0; ch < nch; ch++) {
        int i = (ch << 10) + tid;
        int valid = (i < n_per);
        unsigned kv = valid ? kk[i] : 0u;
        int is_gt = valid && (kv > K);
        int is_eq = valid && (kv == K);
        int e_incl = is_eq;
#pragma unroll
        for (int off = 1; off < 64; off <<= 1) {
            int t = __shfl_up(e_incl, off);
            e_incl += (lane >= off) ? t : 0;
        }
        if (lane == 63) we2[wid] = e_incl;
        __syncthreads();
        if (tid < 16) {
            int v = we2[tid];
#pragma unroll
            for (int off = 1; off < 16; off <<= 1) {
                int t = __shfl_up(v, off);
                v += ((int)tid >= off) ? t : 0;
            }
            we2[tid] = v;
        }
        __syncthreads();
        int eq_before = carry_eq + (e_incl - is_eq) + (wid ? we2[wid - 1] : 0);
        int sel = is_gt || (is_eq && eq_before < need);
        int s_incl = sel;
#pragma unroll
        for (int off = 1; off < 64; off <<= 1) {
            int t = __shfl_up(s_incl, off);
            s_incl += (lane >= off) ? t : 0;
        }
        if (lane == 63) ws2[wid] = s_incl;
        __syncthreads();
        if (tid < 16) {
            int v = ws2[tid];
#pragma unroll
            for (int off = 1; off < 16; off <<= 1) {
                int t = __shfl_up(v, off);
                v += ((int)tid >= off) ? t : 0;
            }
            ws2[tid] = v;
        }
        __syncthreads();
        int pos = carry_pos + (s_incl - sel) + (wid ? ws2[wid - 1] : 0);
        if (valid) {
            if (sel) {
                int ni = g * k + pos;
                node_map[(size_t)g * n_per + i] = ni;
                sel_old[ni] = g * n_per + i;
                vals[ni] = ss[i];
            } else {
                node_map[(size_t)g * n_per + i] = -1;
            }
        }
        __syncthreads();
        if (tid == 0) { carry_pos += ws2[15]; carry_eq += we2[15]; }
        __syncthreads();
    }
}

// gather selected h rows, scale by score, write bf16 into next IN x-half
__global__ void k_gatherb(const unsigned short* __restrict__ hb,
                          const int* __restrict__ sel_old,
                          const float* __restrict__ vals,
                          unsigned short* __restrict__ INnext, int m) {
    long t = blockIdx.x * (long)blockDim.x + threadIdx.x;
    int i = (int)(t >> 5), lane = (int)(t & 31);
    if (i >= m) return;
    int oi = sel_old[i];
    float v = vals[i];
    ushort4 u = *(const ushort4*)(hb + (size_t)oi * 128 + lane * 4);
    ushort4 o;
    o.x = f2b(b2f(u.x) * v); o.y = f2b(b2f(u.y) * v);
    o.z = f2b(b2f(u.z) * v); o.w = f2b(b2f(u.w) * v);
    *(ushort4*)(INnext + (size_t)i * 256 + 128 + lane * 4) = o;
}

// summarize partials: B*PSPLIT wave-blocks, lane = 2 features (ushort2)
__global__ __launch_bounds__(64) void k_partial2(const unsigned short* __restrict__ IN,
                                                 int k, float* __restrict__ part) {
    int g = blockIdx.x >> 8, s = blockIdx.x & (PSPLIT - 1);
    int lane = threadIdx.x;               // 64 lanes x ushort2 = 128 feats
    int rows = (k + PSPLIT - 1) / PSPLIT;
    int r0 = s * rows, r1 = min(k, r0 + rows);
    float s0 = 0, s1 = 0, m0 = -INFINITY, m1 = -INFINITY;
    for (int r = r0; r < r1; r++) {
        ushort2 u = *(const ushort2*)(IN + (size_t)(g * k + r) * 256 + 128 + lane * 2);
        float v0 = b2f(u.x), v1 = b2f(u.y);
        s0 += v0; s1 += v1;
        m0 = fmaxf(m0, v0); m1 = fmaxf(m1, v1);
    }
    size_t base = ((size_t)(g * PSPLIT + s) * 2) * F;
    *(float2*)&part[base + lane * 2] = make_float2(s0, s1);
    *(float2*)&part[base + F + lane * 2] = make_float2(m0, m1);
}

__global__ __launch_bounds__(256) void k_sumreduce2(const float* __restrict__ part, int k,
                                                    float* __restrict__ summary, int accum) {
    int g = blockIdx.x;
    int half = threadIdx.x >> 7, f = threadIdx.x & 127;  // 0=sum 1=max
    float sum = 0.0f, mx = -INFINITY;
    for (int s = 0; s < PSPLIT; s++) {
        float v = part[((size_t)(g * PSPLIT + s) * 2 + half) * F + f];
        sum += v;
        mx = fmaxf(mx, v);
    }
    float res = half ? mx : (sum / (float)k);
    int idx = g * 2 * F + half * F + f;
    if (accum) summary[idx] += res; else summary[idx] = res;
}

__global__ void k_out(const float* __restrict__ summary, const float* __restrict__ W,
                      const float* __restrict__ bias, float* __restrict__ out) {
    int g = blockIdx.x, j = threadIdx.x;  // 8 blocks x 64 threads
    float acc = bias[j];
    for (int t = 0; t < 2 * F; t++) acc += summary[g * 2 * F + t] * W[j * 2 * F + t];
    out[g * OUTD + j] = acc;
}

// ---------------- host launch ----------------
static inline int cdiv(long a, long b) { return (int)((a + b - 1) / b); }

extern "C" void kernel_launch(void* const* d_in, const int* in_sizes, int n_in,
                              void* d_out, int out_size, void* d_ws, size_t ws_size,
                              hipStream_t stream) {
    const float* x_in = (const float*)d_in[0];
    const int* ei     = (const int*)d_in[1];    // [2, E] -> src = ei, dst = ei+E
    const float* w1lW = (const float*)d_in[2];
    const float* w1lb = (const float*)d_in[3];
    const float* w1rW = (const float*)d_in[4];
    const float* p1w  = (const float*)d_in[5];
    const float* w2lW = (const float*)d_in[6];
    const float* w2lb = (const float*)d_in[7];
    const float* w2rW = (const float*)d_in[8];
    const float* p2w  = (const float*)d_in[9];
    const float* w3lW = (const float*)d_in[10];
    const float* w3lb = (const float*)d_in[11];
    const float* w3rW = (const float*)d_in[12];
    const float* p3w  = (const float*)d_in[13];
    const float* outW = (const float*)d_in[14];
    const float* outb = (const float*)d_in[15];
    float* out = (float*)d_out;

    float* ws = (float*)d_ws;
    unsigned short* INb  = (unsigned short*)(ws + OFF_IN);
    unsigned short* hb   = (unsigned short*)(ws + OFF_HB);
    float* sc    = ws + OFF_SC;
    unsigned* key = (unsigned*)(ws + OFF_KEY);
    int* nmap1   = (int*)(ws + OFF_MAP);
    int* nmap2   = (int*)(ws + OFF_MAP2);
    int* selo    = (int*)(ws + OFF_SEL);
    float* vals  = ws + OFF_VAL;
    int* csr     = (int*)(ws + OFF_CSR);
    int* hist = (int*)(ws + OFF_HIST);
    int* incl = (int*)(ws + OFF_INCL);
    int* bsum = (int*)(ws + OFF_BSUM);
    int* rs   = (int*)(ws + OFF_RS);
    int* cur  = (int*)(ws + OFF_CUR);
    float* part    = ws + OFF_PART;
    float* summary = ws + OFF_SUM;
    unsigned short* wcat = (unsigned short*)(ws + OFF_WCAT);
    int* misc_i    = (int*)(ws + OFF_MISC);
    float* normv  = (float*)(misc_i + 20);

    const int eg = cdiv(E, 256);
    const int* esrc = ei;
    const int* edst = ei + E;

    // ================= stage 1 =================
    {
        int n = N0, nb = cdiv(n, 256);
        k_cvt<<<cdiv((long)n * 32, 256), 256, 0, stream>>>(x_in, INb, n);
        hipMemsetAsync(hist, 0, n * sizeof(int), stream);
        k_prep<<<33, 256, 0, stream>>>(w1lW, w1rW, p1w, wcat, normv);
        k_hist_d<<<eg, 256, 0, stream>>>(edst, hist);
        k_scan1<<<nb, 256, 0, stream>>>(hist, n, incl, bsum);
        k_scan2<<<1, 512, 0, stream>>>(bsum, nb);
        k_scan3<<<nb, 256, 0, stream>>>(hist, incl, bsum, n, rs, cur);
        k_csr_d<<<eg, 256, 0, stream>>>(esrc, edst, cur, csr);
        k_agg2b<<<cdiv((long)n * 32, 256), 256, 0, stream>>>(INb, rs, csr, n);
        k_sage_b<<<cdiv(n, 64), 256, 0, stream>>>(INb, wcat, w1lb, p1w, normv, hb, sc, key, n, 0);
        k_topk<<<B, 1024, 0, stream>>>(key, sc, NPG, K1, nmap1, selo, vals);
        k_gatherb<<<cdiv((long)N1 * 32, 256), 256, 0, stream>>>(hb, selo, vals, INb, N1);
        k_partial2<<<B * PSPLIT, 64, 0, stream>>>(INb, K1, part);
        k_sumreduce2<<<B, 256, 0, stream>>>(part, K1, summary, 0);
    }

    // ================= stage 2 (original edges + nmap1) =================
    {
        int n = N1, nb = cdiv(n, 256);
        hipMemsetAsync(hist, 0, n * sizeof(int), stream);
        k_prep<<<33, 256, 0, stream>>>(w2lW, w2rW, p2w, wcat, normv);
        k_hist_m<<<eg, 256, 0, stream>>>(esrc, edst, nmap1, hist);
        k_scan1<<<nb, 256, 0, stream>>>(hist, n, incl, bsum);
        k_scan2<<<1, 512, 0, stream>>>(bsum, nb);
        k_scan3<<<nb, 256, 0, stream>>>(hist, incl, bsum, n, rs, cur);
        k_csr_m<<<eg, 256, 0, stream>>>(esrc, edst, nmap1, cur, csr);
        k_agg2b<<<cdiv((long)n * 32, 256), 256, 0, stream>>>(INb, rs, csr, n);
        k_sage_b<<<cdiv(n, 64), 256, 0, stream>>>(INb, wcat, w2lb, p2w, normv, hb, sc, key, n, 1);
        k_topk<<<B, 1024, 0, stream>>>(key, sc, K1, K2, nmap2, selo, vals);
        k_gatherb<<<cdiv((long)N2 * 32, 256), 256, 0, stream>>>(hb, selo, vals, INb, N2);
        k_partial2<<<B * PSPLIT, 64, 0, stream>>>(INb, K2, part);
        k_sumreduce2<<<B, 256, 0, stream>>>(part, K2, summary, 1);
        k_compose<<<cdiv(N0, 256), 256, 0, stream>>>(nmap1, nmap2, N0);
    }

    // ================= stage 3 (original edges + composed map) =================
    {
        int n = N2, nb = cdiv(n, 256);
        hipMemsetAsync(hist, 0, n * sizeof(int), stream);
        k_prep<<<33, 256, 0, stream>>>(w3lW, w3rW, p3w, wcat, normv);
        k_hist_m<<<eg, 256, 0, stream>>>(esrc, edst, nmap1, hist);
        k_scan1<<<nb, 256, 0, stream>>>(hist, n, incl, bsum);
        k_scan2<<<1, 512, 0, stream>>>(bsum, nb);
        k_scan3<<<nb, 256, 0, stream>>>(hist, incl, bsum, n, rs, cur);
        k_csr_m<<<eg, 256, 0, stream>>>(esrc, edst, nmap1, cur, csr);
        k_agg2b<<<cdiv((long)n * 32, 256), 256, 0, stream>>>(INb, rs, csr, n);
        k_sage_b<<<cdiv(n, 64), 256, 0, stream>>>(INb, wcat, w3lb, p3w, normv, hb, sc, key, n, 0);
        k_topk<<<B, 1024, 0, stream>>>(key, sc, K2, K3, nmap2, selo, vals);
        k_gatherb<<<cdiv((long)N3 * 32, 256), 256, 0, stream>>>(hb, selo, vals, INb, N3);
        k_partial2<<<B * PSPLIT, 64, 0, stream>>>(INb, K3, part);
        k_sumreduce2<<<B, 256, 0, stream>>>(part, K3, summary, 1);
    }

    // ================= output =================
    k_out<<<B, OUTD, 0, stream>>>(summary, outW, outb, out);
}

// Round 6
// 487.788 us; speedup vs baseline: 8.2984x; 1.1005x over previous
//
#include <hip/hip_runtime.h>
#include <hip/hip_bf16.h>
#include <math.h>

// ---------------- problem constants ----------------
constexpr int B    = 8;
constexpr int NPG  = 10000;           // nodes per graph (stage 1)
constexpr int F    = 128;             // feature dim (F_IN == H == 128)
constexpr int OUTD = 64;
constexpr int E    = B * NPG * 16;    // 1,280,000 edges
constexpr int N0   = B * NPG;         // 80000
constexpr int K1   = 5000, K2 = 2500, K3 = 1250;
constexpr int N1   = B * K1;          // 40000
constexpr int N2   = B * K2;          // 20000
constexpr int N3   = B * K3;          // 10000
constexpr int PSPLIT = 256;           // summarize row-split (per graph)
constexpr int NSH  = 8;               // CSR shards (one per XCD)
constexpr int ESH  = E / NSH;         // 160000 edges per shard
constexpr int BPS  = ESH / 256;       // 625 blocks per shard

// ---------------- ws layout (float units) ----------------
constexpr size_t OFF_IN   = 0;                           // [80000][256] bf16 (mean|x)
constexpr size_t SZ_IN    = (size_t)N0 * 256 / 2;
constexpr size_t OFF_HB   = OFF_IN + SZ_IN;              // h bf16 [80000][128]
constexpr size_t SZ_HB    = (size_t)N0 * F / 2;
constexpr size_t OFF_SC   = OFF_HB + SZ_HB;              // 80000 f32
constexpr size_t OFF_KEY  = OFF_SC + N0;                 // 80000 u32
constexpr size_t OFF_MAP  = OFF_KEY + N0;                // 80000 i32 (nmap1 -> composed)
constexpr size_t OFF_MAP2 = OFF_MAP + N0;                // 40000 i32 (nmap2 / stage-3 scratch)
constexpr size_t OFF_SEL1 = OFF_MAP2 + N1;               // 40000 i32 stage2->orig
constexpr size_t OFF_SEL2 = OFF_SEL1 + N1;               // 20000 i32 stage3->stage2
constexpr size_t OFF_SEL3 = OFF_SEL2 + N2;               // 10000 i32 final->stage3
constexpr size_t OFF_SOC  = OFF_SEL3 + N3;               // 20000 i32 stage3->orig
constexpr size_t OFF_VAL  = OFF_SOC + N2;                // 40000 f32
constexpr size_t OFF_CSR  = OFF_VAL + N1;                // E i32
constexpr size_t OFF_H8   = OFF_CSR + E;                 // NSH*N0 i32
constexpr size_t OFF_HSUM = OFF_H8 + (size_t)NSH * N0;   // N0 i32
constexpr size_t OFF_INCL = OFF_HSUM + N0;               // N0 i32
constexpr size_t OFF_BSUM = OFF_INCL + N0;               // 512 i32
constexpr size_t OFF_RS   = OFF_BSUM + 512;              // N0+1 i32 (+pad)
constexpr size_t OFF_CUR8 = OFF_RS + N0 + 64;            // NSH*N0 i32
constexpr size_t OFF_PART = OFF_CUR8 + (size_t)NSH * N0; // B*PSPLIT*2*128 f32
constexpr size_t OFF_SUM  = OFF_PART + (size_t)B * PSPLIT * 2 * F;
constexpr size_t OFF_WCAT = OFF_SUM + (size_t)B * 2 * F; // [128][256] bf16
constexpr size_t OFF_MISC = OFF_WCAT + 128 * 256 / 2;

typedef __attribute__((ext_vector_type(8))) short short8;
typedef __attribute__((ext_vector_type(4))) float floatx4;

// ---------------- helpers ----------------
__device__ inline unsigned f2key(float f) {
    unsigned u = __float_as_uint(f);
    return (u & 0x80000000u) ? ~u : (u | 0x80000000u);
}
__device__ inline unsigned short f2b(float f) {      // RNE f32->bf16
    unsigned u = __float_as_uint(f);
    return (unsigned short)((u + 0x7FFFu + ((u >> 16) & 1u)) >> 16);
}
__device__ inline float b2f(unsigned short u) {
    return __uint_as_float((unsigned)u << 16);
}

// ---------------- kernels ----------------
// norm (block 32) + Wcat bf16 concat (blocks 0..31)
__global__ void k_prep(const float* __restrict__ Wl, const float* __restrict__ Wr,
                       const float* __restrict__ poolw,
                       unsigned short* __restrict__ Wcat, float* __restrict__ normv) {
    if (blockIdx.x == 32) {
        int t = threadIdx.x;
        if (t < 64) {
            float v = 0.0f;
            for (int j = t; j < F; j += 64) { float a = poolw[j]; v += a * a; }
            for (int o = 32; o > 0; o >>= 1) v += __shfl_down(v, o);
            if (t == 0) *normv = sqrtf(v);
        }
        return;
    }
    int idx = (blockIdx.x * 256 + threadIdx.x) * 4;
    int o = idx >> 8, k = idx & 255;
    const float* p = (k < 128) ? (Wl + o * 128 + k) : (Wr + o * 128 + (k - 128));
    float4 v = *(const float4*)p;
    ushort4 u;
    u.x = f2b(v.x); u.y = f2b(v.y); u.z = f2b(v.z); u.w = f2b(v.w);
    *(ushort4*)(Wcat + idx) = u;
}

// x f32 -> bf16 into IN slab x-half
__global__ void k_cvt(const float* __restrict__ x, unsigned short* __restrict__ IN, int n) {
    long t = blockIdx.x * (long)blockDim.x + threadIdx.x;
    int i = (int)(t >> 5), lane = (int)(t & 31);
    if (i >= n) return;
    float4 v = ((const float4*)(x + (size_t)i * F))[lane];
    ushort4 u;
    u.x = f2b(v.x); u.y = f2b(v.y); u.z = f2b(v.z); u.w = f2b(v.w);
    *(ushort4*)(IN + (size_t)i * 256 + 128 + lane * 4) = u;
}

// -------- XCD-sharded CSR build (stage 1 only) --------
// shard s = blockIdx&7 -> same XCD under round-robin dispatch; shard's hist
// region is XCD-local so atomics stay in one L2.
__global__ void k_hist8(const int* __restrict__ dst, int* __restrict__ hist8) {
    int s = blockIdx.x & 7, local = blockIdx.x >> 3;
    int e = s * ESH + local * 256 + threadIdx.x;
    atomicAdd(&hist8[s * N0 + dst[e]], 1);
}

__global__ void k_sum8(const int* __restrict__ hist8, int* __restrict__ hsum, int n) {
    int i = blockIdx.x * blockDim.x + threadIdx.x;
    if (i >= n) return;
    int t = 0;
#pragma unroll
    for (int s = 0; s < NSH; s++) t += hist8[s * N0 + i];
    hsum[i] = t;
}

__global__ __launch_bounds__(256) void k_scan1(const int* __restrict__ in, int n,
                                               int* __restrict__ incl, int* __restrict__ bsum) {
    __shared__ int s[256];
    int i = blockIdx.x * 256 + threadIdx.x;
    int v = (i < n) ? in[i] : 0;
    s[threadIdx.x] = v;
    __syncthreads();
    for (int off = 1; off < 256; off <<= 1) {
        int t = s[threadIdx.x] + ((threadIdx.x >= off) ? s[threadIdx.x - off] : 0);
        __syncthreads();
        s[threadIdx.x] = t;
        __syncthreads();
    }
    if (i < n) incl[i] = s[threadIdx.x];
    if (threadIdx.x == 255) bsum[blockIdx.x] = s[255];
}

__global__ __launch_bounds__(512) void k_scan2(int* __restrict__ bsum, int nb) {
    __shared__ int s[512];
    int t = threadIdx.x;
    int v = (t < nb) ? bsum[t] : 0;
    s[t] = v;
    __syncthreads();
    for (int off = 1; off < 512; off <<= 1) {
        int u = s[t] + ((t >= off) ? s[t - off] : 0);
        __syncthreads();
        s[t] = u;
        __syncthreads();
    }
    if (t < nb) bsum[t] = s[t] - v;   // exclusive
}

__global__ void k_scan3(const int* __restrict__ in, const int* __restrict__ incl,
                        const int* __restrict__ bsum, int n,
                        int* __restrict__ rowstart) {
    int i = blockIdx.x * 256 + threadIdx.x;
    if (i >= n) return;
    int ex = incl[i] - in[i] + bsum[blockIdx.x];
    rowstart[i] = ex;
    if (i == n - 1) rowstart[n] = ex + in[i];
}

// per-node shard cursors: node i's list = [rs[i], rs[i+1]) split shard-major
__global__ void k_cursor8(const int* __restrict__ rs, const int* __restrict__ hist8,
                          int* __restrict__ cur8, int n) {
    int i = blockIdx.x * blockDim.x + threadIdx.x;
    if (i >= n) return;
    int run = rs[i];
#pragma unroll
    for (int s = 0; s < NSH; s++) {
        cur8[s * N0 + i] = run;
        run += hist8[s * N0 + i];
    }
}

__global__ void k_csr8(const int* __restrict__ src, const int* __restrict__ dst,
                       int* __restrict__ cur8, int* __restrict__ csr) {
    int s = blockIdx.x & 7, local = blockIdx.x >> 3;
    int e = s * ESH + local * 256 + threadIdx.x;
    int p = atomicAdd(&cur8[s * N0 + dst[e]], 1);
    csr[p] = src[e];
}

__global__ void k_compose(int* __restrict__ m1, const int* __restrict__ m2, int n) {
    int i = blockIdx.x * blockDim.x + threadIdx.x;
    if (i >= n) return;
    int a = m1[i];
    m1[i] = (a >= 0) ? m2[a] : -1;
}

__global__ void k_chain(const int* __restrict__ s2, const int* __restrict__ s1,
                        int* __restrict__ soc, int n) {
    int i = blockIdx.x * blockDim.x + threadIdx.x;
    if (i >= n) return;
    soc[i] = s1[s2[i]];
}

// stage-1 gather-aggregate bf16: x-half -> mean-half
__global__ __launch_bounds__(256) void k_agg2b(unsigned short* __restrict__ IN,
                                               const int* __restrict__ rowstart,
                                               const int* __restrict__ csr, int n) {
    int t = blockIdx.x * blockDim.x + threadIdx.x;
    int i = t >> 5, lane = t & 31;
    if (i >= n) return;
    int b = rowstart[i], e = rowstart[i + 1];
    float a0 = 0, a1 = 0, a2 = 0, a3 = 0;
    int j = b;
    for (; j + 4 <= e; j += 4) {      // 4-way MLP
        int s0 = csr[j], s1 = csr[j + 1], s2 = csr[j + 2], s3 = csr[j + 3];
        ushort4 u0 = *(const ushort4*)(IN + (size_t)s0 * 256 + 128 + lane * 4);
        ushort4 u1 = *(const ushort4*)(IN + (size_t)s1 * 256 + 128 + lane * 4);
        ushort4 u2 = *(const ushort4*)(IN + (size_t)s2 * 256 + 128 + lane * 4);
        ushort4 u3 = *(const ushort4*)(IN + (size_t)s3 * 256 + 128 + lane * 4);
        a0 += (b2f(u0.x) + b2f(u1.x)) + (b2f(u2.x) + b2f(u3.x));
        a1 += (b2f(u0.y) + b2f(u1.y)) + (b2f(u2.y) + b2f(u3.y));
        a2 += (b2f(u0.z) + b2f(u1.z)) + (b2f(u2.z) + b2f(u3.z));
        a3 += (b2f(u0.w) + b2f(u1.w)) + (b2f(u2.w) + b2f(u3.w));
    }
    for (; j < e; j++) {
        int s0 = csr[j];
        ushort4 u0 = *(const ushort4*)(IN + (size_t)s0 * 256 + 128 + lane * 4);
        a0 += b2f(u0.x); a1 += b2f(u0.y); a2 += b2f(u0.z); a3 += b2f(u0.w);
    }
    float rd = 1.0f / fmaxf((float)(e - b), 1.0f);
    ushort4 o;
    o.x = f2b(a0 * rd); o.y = f2b(a1 * rd); o.z = f2b(a2 * rd); o.w = f2b(a3 * rd);
    *(ushort4*)(IN + (size_t)i * 256 + lane * 4) = o;
}

// stages 2-3: pull over ORIGINAL neighbors of orig(i), predicated on map.
// deg = count of surviving in-edges (matches reference masked mean).
__global__ __launch_bounds__(256) void k_agg2m(unsigned short* __restrict__ IN,
                                               const int* __restrict__ rowstart,
                                               const int* __restrict__ csr,
                                               const int* __restrict__ map,
                                               const int* __restrict__ orig_of, int n) {
    int t = blockIdx.x * blockDim.x + threadIdx.x;
    int i = t >> 5, lane = t & 31;
    if (i >= n) return;
    int o = orig_of[i];
    int b = rowstart[o], e = rowstart[o + 1];
    float a0 = 0, a1 = 0, a2 = 0, a3 = 0;
    int d = 0;
    int j = b;
    for (; j + 2 <= e; j += 2) {
        int s0 = map[csr[j]], s1 = map[csr[j + 1]];
        if (s0 >= 0) {
            ushort4 u = *(const ushort4*)(IN + (size_t)s0 * 256 + 128 + lane * 4);
            a0 += b2f(u.x); a1 += b2f(u.y); a2 += b2f(u.z); a3 += b2f(u.w);
            d++;
        }
        if (s1 >= 0) {
            ushort4 u = *(const ushort4*)(IN + (size_t)s1 * 256 + 128 + lane * 4);
            a0 += b2f(u.x); a1 += b2f(u.y); a2 += b2f(u.z); a3 += b2f(u.w);
            d++;
        }
    }
    if (j < e) {
        int s0 = map[csr[j]];
        if (s0 >= 0) {
            ushort4 u = *(const ushort4*)(IN + (size_t)s0 * 256 + 128 + lane * 4);
            a0 += b2f(u.x); a1 += b2f(u.y); a2 += b2f(u.z); a3 += b2f(u.w);
            d++;
        }
    }
    float rd = 1.0f / fmaxf((float)d, 1.0f);
    ushort4 out;
    out.x = f2b(a0 * rd); out.y = f2b(a1 * rd); out.z = f2b(a2 * rd); out.w = f2b(a3 * rd);
    *(ushort4*)(IN + (size_t)i * 256 + lane * 4) = out;
}

// MFMA SAGE + fused scores (m89-verified fragment mapping)
__global__ __launch_bounds__(256) void k_sage_b(
    const unsigned short* __restrict__ IN, const unsigned short* __restrict__ Wcat,
    const float* __restrict__ bias, const float* __restrict__ poolw,
    const float* __restrict__ normv,
    unsigned short* __restrict__ hb, float* __restrict__ sc,
    unsigned* __restrict__ key, int n, int relu) {
    __shared__ float lds[64][132];
    int tid = threadIdx.x;
    int wid = tid >> 6, lane = tid & 63;
    int q = lane >> 4, l15 = lane & 15;
    int rowbase = blockIdx.x * 64 + wid * 16;

    floatx4 acc[8];
#pragma unroll
    for (int c = 0; c < 8; c++) acc[c] = (floatx4){0.f, 0.f, 0.f, 0.f};

    const unsigned short* abase = IN + (size_t)(rowbase + l15) * 256 + q * 8;
    const unsigned short* bbase = Wcat + (size_t)l15 * 256 + q * 8;
#pragma unroll
    for (int ks = 0; ks < 8; ks++) {
        short8 a = *(const short8*)(abase + (ks << 5));
#pragma unroll
        for (int c = 0; c < 8; c++) {
            short8 b = *(const short8*)(bbase + (c << 12) + (ks << 5));
            acc[c] = __builtin_amdgcn_mfma_f32_16x16x32_bf16(a, b, acc[c], 0, 0, 0);
        }
    }

    float p0 = 0, p1 = 0, p2 = 0, p3 = 0;
#pragma unroll
    for (int c = 0; c < 8; c++) {
        int col = (c << 4) + l15;
        float bv = bias[col];
        float wv = poolw[col];
        floatx4 v = acc[c];
        v[0] += bv; v[1] += bv; v[2] += bv; v[3] += bv;
        if (relu) {
            v[0] = fmaxf(v[0], 0.f); v[1] = fmaxf(v[1], 0.f);
            v[2] = fmaxf(v[2], 0.f); v[3] = fmaxf(v[3], 0.f);
        }
        p0 += v[0] * wv; p1 += v[1] * wv; p2 += v[2] * wv; p3 += v[3] * wv;
        int lr = wid * 16 + q * 4;
        lds[lr + 0][col] = v[0];
        lds[lr + 1][col] = v[1];
        lds[lr + 2][col] = v[2];
        lds[lr + 3][col] = v[3];
    }
#pragma unroll
    for (int off = 1; off < 16; off <<= 1) {
        p0 += __shfl_xor(p0, off);
        p1 += __shfl_xor(p1, off);
        p2 += __shfl_xor(p2, off);
        p3 += __shfl_xor(p3, off);
    }
    if (l15 == 0) {
        float invn = 1.0f / (*normv);
        int r0 = rowbase + q * 4;
        float ps[4] = {p0, p1, p2, p3};
#pragma unroll
        for (int j = 0; j < 4; j++) {
            int r = r0 + j;
            if (r < n) {
                float s = tanhf(ps[j] * invn);
                sc[r] = s;
                key[r] = f2key(s);
            }
        }
    }
    __syncthreads();
#pragma unroll
    for (int it = 0; it < 4; it++) {
        int task = it * 256 + tid;
        int r = task >> 4, grp = task & 15;
        int gr = blockIdx.x * 64 + r;
        if (gr < n) {
            float4 lo = *(const float4*)&lds[r][grp * 8];
            float4 hi = *(const float4*)&lds[r][grp * 8 + 4];
            short8 u;
            u[0] = (short)f2b(lo.x); u[1] = (short)f2b(lo.y);
            u[2] = (short)f2b(lo.z); u[3] = (short)f2b(lo.w);
            u[4] = (short)f2b(hi.x); u[5] = (short)f2b(hi.y);
            u[6] = (short)f2b(hi.z); u[7] = (short)f2b(hi.w);
            *(short8*)(hb + (size_t)gr * 128 + grp * 8) = u;
        }
    }
}

// merged per-graph top-k: radix select then deterministic compaction
__global__ __launch_bounds__(1024) void k_topk(
    const unsigned* __restrict__ keys, const float* __restrict__ sc,
    int n_per, int k,
    int* __restrict__ node_map, int* __restrict__ sel_old, float* __restrict__ vals) {
    int g = blockIdx.x, tid = threadIdx.x;
    int lane = tid & 63, wid = tid >> 6;      // 16 waves
    const unsigned* kk = keys + (size_t)g * n_per;
    const float* ss = sc + (size_t)g * n_per;
    __shared__ int hist[256];
    __shared__ int suf[256];
    __shared__ unsigned sprefix;
    __shared__ int sr, sfound;
    __shared__ int we2[16], ws2[16];
    __shared__ int carry_pos, carry_eq;
    if (tid == 0) { sprefix = 0; sr = k; carry_pos = 0; carry_eq = 0; }
    __syncthreads();

    for (int b = 3; b >= 0; b--) {
        if (tid < 256) hist[tid] = 0;
        __syncthreads();
        unsigned pfx = sprefix;
        unsigned maskhi = (b == 3) ? 0u : (0xFFFFFFFFu << ((b + 1) * 8));
        for (int i = tid; i < n_per; i += 1024) {
            unsigned kv = kk[i];
            if ((kv & maskhi) == (pfx & maskhi))
                atomicAdd(&hist[(kv >> (b * 8)) & 255], 1);
        }
        __syncthreads();
        if (tid < 256) suf[tid] = hist[tid];
        __syncthreads();
        for (int off = 1; off < 256; off <<= 1) {
            int t = 0;
            if (tid < 256) t = suf[tid] + ((tid + off < 256) ? suf[tid + off] : 0);
            __syncthreads();
            if (tid < 256) suf[tid] = t;
            __syncthreads();
        }
        int r = sr;
        if (tid < 256) {
            int hi = (tid == 255) ? 0 : suf[tid + 1];
            if (hi < r && suf[tid] >= r) sfound = tid;   // unique
        }
        __syncthreads();
        if (tid == 0) {
            int v = sfound;
            int hi = (v == 255) ? 0 : suf[v + 1];
            sr = r - hi;
            sprefix = pfx | ((unsigned)v << (b * 8));
        }
        __syncthreads();
    }
    unsigned K = sprefix;
    int need = sr;
    __syncthreads();

    int nch = (n_per + 1023) >> 10;
    for (int ch = 0; ch < nch; ch++) {
        int i = (ch << 10) + tid;
        int valid = (i < n_per);
        unsigned kv = valid ? kk[i] : 0u;
        int is_gt = valid && (kv > K);
        int is_eq = valid && (kv == K);
        int e_incl = is_eq;
#pragma unroll
        for (int off = 1; off < 64; off <<= 1) {
            int t = __shfl_up(e_incl, off);
            e_incl += (lane >= off) ? t : 0;
        }
        if (lane == 63) we2[wid] = e_incl;
        __syncthreads();
        if (tid < 16) {
            int v = we2[tid];
#pragma unroll
            for (int off = 1; off < 16; off <<= 1) {
                int t = __shfl_up(v, off);
                v += ((int)tid >= off) ? t : 0;
            }
            we2[tid] = v;
        }
        __syncthreads();
        int eq_before = carry_eq + (e_incl - is_eq) + (wid ? we2[wid - 1] : 0);
        int sel = is_gt || (is_eq && eq_before < need);
        int s_incl = sel;
#pragma unroll
        for (int off = 1; off < 64; off <<= 1) {
            int t = __shfl_up(s_incl, off);
            s_incl += (lane >= off) ? t : 0;
        }
        if (lane == 63) ws2[wid] = s_incl;
        __syncthreads();
        if (tid < 16) {
            int v = ws2[tid];
#pragma unroll
            for (int off = 1; off < 16; off <<= 1) {
                int t = __shfl_up(v, off);
                v += ((int)tid >= off) ? t : 0;
            }
            ws2[tid] = v;
        }
        __syncthreads();
        int pos = carry_pos + (s_incl - sel) + (wid ? ws2[wid - 1] : 0);
        if (valid) {
            if (sel) {
                int ni = g * k + pos;
                node_map[(size_t)g * n_per + i] = ni;
                sel_old[ni] = g * n_per + i;
                vals[ni] = ss[i];
            } else {
                node_map[(size_t)g * n_per + i] = -1;
            }
        }
        __syncthreads();
        if (tid == 0) { carry_pos += ws2[15]; carry_eq += we2[15]; }
        __syncthreads();
    }
}

// gather selected h rows, scale by score, write bf16 into next IN x-half
__global__ void k_gatherb(const unsigned short* __restrict__ hb,
                          const int* __restrict__ sel_old,
                          const float* __restrict__ vals,
                          unsigned short* __restrict__ INnext, int m) {
    long t = blockIdx.x * (long)blockDim.x + threadIdx.x;
    int i = (int)(t >> 5), lane = (int)(t & 31);
    if (i >= m) return;
    int oi = sel_old[i];
    float v = vals[i];
    ushort4 u = *(const ushort4*)(hb + (size_t)oi * 128 + lane * 4);
    ushort4 o;
    o.x = f2b(b2f(u.x) * v); o.y = f2b(b2f(u.y) * v);
    o.z = f2b(b2f(u.z) * v); o.w = f2b(b2f(u.w) * v);
    *(ushort4*)(INnext + (size_t)i * 256 + 128 + lane * 4) = o;
}

// summarize partials: B*PSPLIT wave-blocks, lane = 2 features (ushort2)
__global__ __launch_bounds__(64) void k_partial2(const unsigned short* __restrict__ IN,
                                                 int k, float* __restrict__ part) {
    int g = blockIdx.x >> 8, s = blockIdx.x & (PSPLIT - 1);
    int lane = threadIdx.x;               // 64 lanes x ushort2 = 128 feats
    int rows = (k + PSPLIT - 1) / PSPLIT;
    int r0 = s * rows, r1 = min(k, r0 + rows);
    float s0 = 0, s1 = 0, m0 = -INFINITY, m1 = -INFINITY;
    for (int r = r0; r < r1; r++) {
        ushort2 u = *(const ushort2*)(IN + (size_t)(g * k + r) * 256 + 128 + lane * 2);
        float v0 = b2f(u.x), v1 = b2f(u.y);
        s0 += v0; s1 += v1;
        m0 = fmaxf(m0, v0); m1 = fmaxf(m1, v1);
    }
    size_t base = ((size_t)(g * PSPLIT + s) * 2) * F;
    *(float2*)&part[base + lane * 2] = make_float2(s0, s1);
    *(float2*)&part[base + F + lane * 2] = make_float2(m0, m1);
}

__global__ __launch_bounds__(256) void k_sumreduce2(const float* __restrict__ part, int k,
                                                    float* __restrict__ summary, int accum) {
    int g = blockIdx.x;
    int half = threadIdx.x >> 7, f = threadIdx.x & 127;  // 0=sum 1=max
    float sum = 0.0f, mx = -INFINITY;
    for (int s = 0; s < PSPLIT; s++) {
        float v = part[((size_t)(g * PSPLIT + s) * 2 + half) * F + f];
        sum += v;
        mx = fmaxf(mx, v);
    }
    float res = half ? mx : (sum / (float)k);
    int idx = g * 2 * F + half * F + f;
    if (accum) summary[idx] += res; else summary[idx] = res;
}

__global__ void k_out(const float* __restrict__ summary, const float* __restrict__ W,
                      const float* __restrict__ bias, float* __restrict__ out) {
    int g = blockIdx.x, j = threadIdx.x;  // 8 blocks x 64 threads
    float acc = bias[j];
    for (int t = 0; t < 2 * F; t++) acc += summary[g * 2 * F + t] * W[j * 2 * F + t];
    out[g * OUTD + j] = acc;
}

// ---------------- host launch ----------------
static inline int cdiv(long a, long b) { return (int)((a + b - 1) / b); }

extern "C" void kernel_launch(void* const* d_in, const int* in_sizes, int n_in,
                              void* d_out, int out_size, void* d_ws, size_t ws_size,
                              hipStream_t stream) {
    const float* x_in = (const float*)d_in[0];
    const int* ei     = (const int*)d_in[1];    // [2, E] -> src = ei, dst = ei+E
    const float* w1lW = (const float*)d_in[2];
    const float* w1lb = (const float*)d_in[3];
    const float* w1rW = (const float*)d_in[4];
    const float* p1w  = (const float*)d_in[5];
    const float* w2lW = (const float*)d_in[6];
    const float* w2lb = (const float*)d_in[7];
    const float* w2rW = (const float*)d_in[8];
    const float* p2w  = (const float*)d_in[9];
    const float* w3lW = (const float*)d_in[10];
    const float* w3lb = (const float*)d_in[11];
    const float* w3rW = (const float*)d_in[12];
    const float* p3w  = (const float*)d_in[13];
    const float* outW = (const float*)d_in[14];
    const float* outb = (const float*)d_in[15];
    float* out = (float*)d_out;

    float* ws = (float*)d_ws;
    unsigned short* INb  = (unsigned short*)(ws + OFF_IN);
    unsigned short* hb   = (unsigned short*)(ws + OFF_HB);
    float* sc    = ws + OFF_SC;
    unsigned* key = (unsigned*)(ws + OFF_KEY);
    int* nmap1   = (int*)(ws + OFF_MAP);
    int* nmap2   = (int*)(ws + OFF_MAP2);
    int* selo1   = (int*)(ws + OFF_SEL1);
    int* selo2   = (int*)(ws + OFF_SEL2);
    int* selo3   = (int*)(ws + OFF_SEL3);
    int* soc     = (int*)(ws + OFF_SOC);
    float* vals  = ws + OFF_VAL;
    int* csr     = (int*)(ws + OFF_CSR);
    int* hist8   = (int*)(ws + OFF_H8);
    int* hsum    = (int*)(ws + OFF_HSUM);
    int* incl    = (int*)(ws + OFF_INCL);
    int* bsum    = (int*)(ws + OFF_BSUM);
    int* rs      = (int*)(ws + OFF_RS);
    int* cur8    = (int*)(ws + OFF_CUR8);
    float* part    = ws + OFF_PART;
    float* summary = ws + OFF_SUM;
    unsigned short* wcat = (unsigned short*)(ws + OFF_WCAT);
    int* misc_i  = (int*)(ws + OFF_MISC);
    float* normv = (float*)(misc_i + 20);

    const int* esrc = ei;
    const int* edst = ei + E;

    // ================= stage 1 =================
    {
        int n = N0, nb = cdiv(n, 256);
        k_cvt<<<cdiv((long)n * 32, 256), 256, 0, stream>>>(x_in, INb, n);
        hipMemsetAsync(hist8, 0, (size_t)NSH * N0 * sizeof(int), stream);
        k_prep<<<33, 256, 0, stream>>>(w1lW, w1rW, p1w, wcat, normv);
        k_hist8<<<NSH * BPS, 256, 0, stream>>>(edst, hist8);
        k_sum8<<<nb, 256, 0, stream>>>(hist8, hsum, n);
        k_scan1<<<nb, 256, 0, stream>>>(hsum, n, incl, bsum);
        k_scan2<<<1, 512, 0, stream>>>(bsum, nb);
        k_scan3<<<nb, 256, 0, stream>>>(hsum, incl, bsum, n, rs);
        k_cursor8<<<nb, 256, 0, stream>>>(rs, hist8, cur8, n);
        k_csr8<<<NSH * BPS, 256, 0, stream>>>(esrc, edst, cur8, csr);
        k_agg2b<<<cdiv((long)n * 32, 256), 256, 0, stream>>>(INb, rs, csr, n);
        k_sage_b<<<cdiv(n, 64), 256, 0, stream>>>(INb, wcat, w1lb, p1w, normv, hb, sc, key, n, 0);
        k_topk<<<B, 1024, 0, stream>>>(key, sc, NPG, K1, nmap1, selo1, vals);
        k_gatherb<<<cdiv((long)N1 * 32, 256), 256, 0, stream>>>(hb, selo1, vals, INb, N1);
        k_partial2<<<B * PSPLIT, 64, 0, stream>>>(INb, K1, part);
        k_sumreduce2<<<B, 256, 0, stream>>>(part, K1, summary, 0);
    }

    // ================= stage 2 (stage-1 CSR + nmap1 predicate) =================
    {
        int n = N1;
        k_prep<<<33, 256, 0, stream>>>(w2lW, w2rW, p2w, wcat, normv);
        k_agg2m<<<cdiv((long)n * 32, 256), 256, 0, stream>>>(INb, rs, csr, nmap1, selo1, n);
        k_sage_b<<<cdiv(n, 64), 256, 0, stream>>>(INb, wcat, w2lb, p2w, normv, hb, sc, key, n, 1);
        k_topk<<<B, 1024, 0, stream>>>(key, sc, K1, K2, nmap2, selo2, vals);
        k_gatherb<<<cdiv((long)N2 * 32, 256), 256, 0, stream>>>(hb, selo2, vals, INb, N2);
        k_partial2<<<B * PSPLIT, 64, 0, stream>>>(INb, K2, part);
        k_sumreduce2<<<B, 256, 0, stream>>>(part, K2, summary, 1);
        k_compose<<<cdiv(N0, 256), 256, 0, stream>>>(nmap1, nmap2, N0);   // orig->stage3
        k_chain<<<cdiv(N2, 256), 256, 0, stream>>>(selo2, selo1, soc, N2); // stage3->orig
    }

    // ================= stage 3 (stage-1 CSR + composed map) =================
    {
        int n = N2;
        k_prep<<<33, 256, 0, stream>>>(w3lW, w3rW, p3w, wcat, normv);
        k_agg2m<<<cdiv((long)n * 32, 256), 256, 0, stream>>>(INb, rs, csr, nmap1, soc, n);
        k_sage_b<<<cdiv(n, 64), 256, 0, stream>>>(INb, wcat, w3lb, p3w, normv, hb, sc, key, n, 0);
        k_topk<<<B, 1024, 0, stream>>>(key, sc, K2, K3, nmap2, selo3, vals);
        k_gatherb<<<cdiv((long)N3 * 32, 256), 256, 0, stream>>>(hb, selo3, vals, INb, N3);
        k_partial2<<<B * PSPLIT, 64, 0, stream>>>(INb, K3, part);
        k_sumreduce2<<<B, 256, 0, stream>>>(part, K3, summary, 1);
    }

    // ================= output =================
    k_out<<<B, OUTD, 0, stream>>>(summary, outW, outb, out);
}

// Round 7
// 475.030 us; speedup vs baseline: 8.5213x; 1.0269x over previous
//
#include <hip/hip_runtime.h>
#include <hip/hip_bf16.h>
#include <math.h>

// ---------------- problem constants ----------------
constexpr int B    = 8;
constexpr int NPG  = 10000;           // nodes per graph (stage 1)
constexpr int F    = 128;             // feature dim (F_IN == H == 128)
constexpr int OUTD = 64;
constexpr int E    = B * NPG * 16;    // 1,280,000 edges
constexpr int N0   = B * NPG;         // 80000
constexpr int K1   = 5000, K2 = 2500, K3 = 1250;
constexpr int N1   = B * K1;          // 40000
constexpr int N2   = B * K2;          // 20000
constexpr int N3   = B * K3;          // 10000
constexpr int PSPLIT = 256;           // summarize row-split (per graph)
constexpr int NSH  = 8;               // shards == graphs == XCDs (edge list is graph-contiguous)
constexpr int ESH  = E / NSH;         // 160000 edges per graph
constexpr int BPS  = ESH / 256;       // 625 blocks per shard

// ---------------- ws layout (float units) ----------------
constexpr size_t OFF_IN   = 0;                           // [80000][256] bf16 (mean|x)
constexpr size_t SZ_IN    = (size_t)N0 * 256 / 2;
constexpr size_t OFF_HB   = OFF_IN + SZ_IN;              // h bf16 [80000][128]
constexpr size_t SZ_HB    = (size_t)N0 * F / 2;
constexpr size_t OFF_SC   = OFF_HB + SZ_HB;              // 80000 f32
constexpr size_t OFF_KEY  = OFF_SC + N0;                 // 80000 u32 (16B-aligned)
constexpr size_t OFF_MAP  = OFF_KEY + N0;                // 80000 i32 (nmap1 -> composed)
constexpr size_t OFF_MAP2 = OFF_MAP + N0;                // 40000 i32
constexpr size_t OFF_SEL1 = OFF_MAP2 + N1;               // 40000 i32 stage2->orig
constexpr size_t OFF_SEL2 = OFF_SEL1 + N1;               // 20000 i32 stage3->stage2
constexpr size_t OFF_SEL3 = OFF_SEL2 + N2;               // 10000 i32 final->stage3
constexpr size_t OFF_SOC  = OFF_SEL3 + N3;               // 20000 i32 stage3->orig
constexpr size_t OFF_VAL  = OFF_SOC + N2;                // 40000 f32
constexpr size_t OFF_CSR  = OFF_VAL + N1;                // E i32
constexpr size_t OFF_HIST = OFF_CSR + E;                 // N0 i32
constexpr size_t OFF_INCL = OFF_HIST + N0;               // N0 i32
constexpr size_t OFF_BSUM = OFF_INCL + N0;               // 512 i32
constexpr size_t OFF_RS   = OFF_BSUM + 512;              // N0+1 i32 (+pad)
constexpr size_t OFF_CUR  = OFF_RS + N0 + 64;            // N0 i32
constexpr size_t OFF_PART = OFF_CUR + N0;                // B*PSPLIT*2*128 f32
constexpr size_t OFF_SUM  = OFF_PART + (size_t)B * PSPLIT * 2 * F;
constexpr size_t OFF_WCAT = OFF_SUM + (size_t)B * 2 * F; // 3 x [128][256] bf16
constexpr size_t OFF_MISC = OFF_WCAT + 3 * 128 * 256 / 2;

typedef __attribute__((ext_vector_type(8))) short short8;
typedef __attribute__((ext_vector_type(4))) float floatx4;

// ---------------- helpers ----------------
__device__ inline unsigned f2key(float f) {
    unsigned u = __float_as_uint(f);
    return (u & 0x80000000u) ? ~u : (u | 0x80000000u);
}
__device__ inline unsigned short f2b(float f) {      // RNE f32->bf16
    unsigned u = __float_as_uint(f);
    return (unsigned short)((u + 0x7FFFu + ((u >> 16) & 1u)) >> 16);
}
__device__ inline float b2f(unsigned short u) {
    return __uint_as_float((unsigned)u << 16);
}

// ---------------- kernels ----------------
// all 3 stages' Wcat (bf16 concat) + pool-w norms in one launch
__global__ void k_prep3(const float* __restrict__ Wl1, const float* __restrict__ Wr1,
                        const float* __restrict__ Wl2, const float* __restrict__ Wr2,
                        const float* __restrict__ Wl3, const float* __restrict__ Wr3,
                        const float* __restrict__ p1, const float* __restrict__ p2,
                        const float* __restrict__ p3,
                        unsigned short* __restrict__ wcat, float* __restrict__ normv) {
    int b = blockIdx.x;
    if (b == 96) {
        int t = threadIdx.x;
        int which = t >> 6, lane = t & 63;
        if (which < 3) {
            const float* pw = (which == 0) ? p1 : (which == 1) ? p2 : p3;
            float v = 0.0f;
            for (int j = lane; j < F; j += 64) { float a = pw[j]; v += a * a; }
            for (int o = 32; o > 0; o >>= 1) v += __shfl_down(v, o);
            if (lane == 0) normv[which] = sqrtf(v);
        }
        return;
    }
    int stage = b >> 5;
    const float* Wl = (stage == 0) ? Wl1 : (stage == 1) ? Wl2 : Wl3;
    const float* Wr = (stage == 0) ? Wr1 : (stage == 1) ? Wr2 : Wr3;
    unsigned short* W = wcat + (size_t)stage * 128 * 256;
    int idx = ((b & 31) * 256 + threadIdx.x) * 4;
    int o = idx >> 8, k = idx & 255;
    const float* p = (k < 128) ? (Wl + o * 128 + k) : (Wr + o * 128 + (k - 128));
    float4 v = *(const float4*)p;
    ushort4 u;
    u.x = f2b(v.x); u.y = f2b(v.y); u.z = f2b(v.z); u.w = f2b(v.w);
    *(ushort4*)(W + idx) = u;
}

// x f32 -> bf16 into IN slab x-half
__global__ void k_cvt(const float* __restrict__ x, unsigned short* __restrict__ IN, int n) {
    long t = blockIdx.x * (long)blockDim.x + threadIdx.x;
    int i = (int)(t >> 5), lane = (int)(t & 31);
    if (i >= n) return;
    float4 v = ((const float4*)(x + (size_t)i * F))[lane];
    ushort4 u;
    u.x = f2b(v.x); u.y = f2b(v.y); u.z = f2b(v.z); u.w = f2b(v.w);
    *(ushort4*)(IN + (size_t)i * 256 + 128 + lane * 4) = u;
}

// -------- CSR build (stage 1). shard s == graph s == XCD s; dst ranges
// disjoint per shard so one hist/cursor array. nt loads keep the hot
// csr/cursor lines resident in the XCD-local L2 (kills write amplification).
__global__ void k_hist8(const int* __restrict__ dst, int* __restrict__ hist) {
    int s = blockIdx.x & 7, local = blockIdx.x >> 3;
    int e = s * ESH + local * 256 + threadIdx.x;
    int d = __builtin_nontemporal_load(dst + e);
    atomicAdd(&hist[d], 1);
}

__global__ __launch_bounds__(256) void k_scan1(const int* __restrict__ in, int n,
                                               int* __restrict__ incl, int* __restrict__ bsum) {
    __shared__ int s[256];
    int i = blockIdx.x * 256 + threadIdx.x;
    int v = (i < n) ? in[i] : 0;
    s[threadIdx.x] = v;
    __syncthreads();
    for (int off = 1; off < 256; off <<= 1) {
        int t = s[threadIdx.x] + ((threadIdx.x >= off) ? s[threadIdx.x - off] : 0);
        __syncthreads();
        s[threadIdx.x] = t;
        __syncthreads();
    }
    if (i < n) incl[i] = s[threadIdx.x];
    if (threadIdx.x == 255) bsum[blockIdx.x] = s[255];
}

__global__ __launch_bounds__(512) void k_scan2(int* __restrict__ bsum, int nb) {
    __shared__ int s[512];
    int t = threadIdx.x;
    int v = (t < nb) ? bsum[t] : 0;
    s[t] = v;
    __syncthreads();
    for (int off = 1; off < 512; off <<= 1) {
        int u = s[t] + ((t >= off) ? s[t - off] : 0);
        __syncthreads();
        s[t] = u;
        __syncthreads();
    }
    if (t < nb) bsum[t] = s[t] - v;   // exclusive
}

__global__ void k_scan3(const int* __restrict__ in, const int* __restrict__ incl,
                        const int* __restrict__ bsum, int n,
                        int* __restrict__ rowstart, int* __restrict__ cursor) {
    int i = blockIdx.x * 256 + threadIdx.x;
    if (i >= n) return;
    int ex = incl[i] - in[i] + bsum[blockIdx.x];
    rowstart[i] = ex;
    cursor[i] = ex;
    if (i == n - 1) rowstart[n] = ex + in[i];
}

__global__ void k_csr8(const int* __restrict__ src, const int* __restrict__ dst,
                       int* __restrict__ cur, int* __restrict__ csr) {
    int s = blockIdx.x & 7, local = blockIdx.x >> 3;
    int e = s * ESH + local * 256 + threadIdx.x;
    int d = __builtin_nontemporal_load(dst + e);
    int sv = __builtin_nontemporal_load(src + e);
    int p = atomicAdd(&cur[d], 1);
    csr[p] = sv;
}

// fused: compose orig->stage3 map; chain stage3->orig selection
__global__ void k_composechain(int* __restrict__ m1, const int* __restrict__ m2,
                               const int* __restrict__ s2, const int* __restrict__ s1,
                               int* __restrict__ soc, int n1, int n2) {
    int i = blockIdx.x * blockDim.x + threadIdx.x;
    if (i < n2) soc[i] = s1[s2[i]];
    if (i < n1) { int a = m1[i]; m1[i] = (a >= 0) ? m2[a] : -1; }
}

// stage-1 gather-aggregate bf16, graph->XCD swizzled (blockIdx&7 == graph):
// graph's touched feature bytes (~2.5MB) stay in the XCD-local L2.
__global__ __launch_bounds__(256) void k_agg2b(unsigned short* __restrict__ IN,
                                               const int* __restrict__ rowstart,
                                               const int* __restrict__ csr, int npg) {
    int g = blockIdx.x & 7;
    int local = (blockIdx.x >> 3) * 8 + (threadIdx.x >> 5);
    int lane = threadIdx.x & 31;
    if (local >= npg) return;
    int i = g * npg + local;
    int b = rowstart[i], e = rowstart[i + 1];
    float a0 = 0, a1 = 0, a2 = 0, a3 = 0;
    int j = b;
    for (; j + 4 <= e; j += 4) {      // 4-way MLP
        int s0 = __builtin_nontemporal_load(csr + j);
        int s1 = __builtin_nontemporal_load(csr + j + 1);
        int s2 = __builtin_nontemporal_load(csr + j + 2);
        int s3 = __builtin_nontemporal_load(csr + j + 3);
        ushort4 u0 = *(const ushort4*)(IN + (size_t)s0 * 256 + 128 + lane * 4);
        ushort4 u1 = *(const ushort4*)(IN + (size_t)s1 * 256 + 128 + lane * 4);
        ushort4 u2 = *(const ushort4*)(IN + (size_t)s2 * 256 + 128 + lane * 4);
        ushort4 u3 = *(const ushort4*)(IN + (size_t)s3 * 256 + 128 + lane * 4);
        a0 += (b2f(u0.x) + b2f(u1.x)) + (b2f(u2.x) + b2f(u3.x));
        a1 += (b2f(u0.y) + b2f(u1.y)) + (b2f(u2.y) + b2f(u3.y));
        a2 += (b2f(u0.z) + b2f(u1.z)) + (b2f(u2.z) + b2f(u3.z));
        a3 += (b2f(u0.w) + b2f(u1.w)) + (b2f(u2.w) + b2f(u3.w));
    }
    for (; j < e; j++) {
        int s0 = __builtin_nontemporal_load(csr + j);
        ushort4 u0 = *(const ushort4*)(IN + (size_t)s0 * 256 + 128 + lane * 4);
        a0 += b2f(u0.x); a1 += b2f(u0.y); a2 += b2f(u0.z); a3 += b2f(u0.w);
    }
    float rd = 1.0f / fmaxf((float)(e - b), 1.0f);
    ushort4 o;
    o.x = f2b(a0 * rd); o.y = f2b(a1 * rd); o.z = f2b(a2 * rd); o.w = f2b(a3 * rd);
    *(ushort4*)(IN + (size_t)i * 256 + lane * 4) = o;
}

// stages 2-3: pull over ORIGINAL neighbors of orig(i), predicated on map;
// same graph->XCD swizzle. deg = surviving in-edges (reference masked mean).
__global__ __launch_bounds__(256) void k_agg2m(unsigned short* __restrict__ IN,
                                               const int* __restrict__ rowstart,
                                               const int* __restrict__ csr,
                                               const int* __restrict__ map,
                                               const int* __restrict__ orig_of, int npg) {
    int g = blockIdx.x & 7;
    int local = (blockIdx.x >> 3) * 8 + (threadIdx.x >> 5);
    int lane = threadIdx.x & 31;
    if (local >= npg) return;
    int i = g * npg + local;
    int o = orig_of[i];
    int b = rowstart[o], e = rowstart[o + 1];
    float a0 = 0, a1 = 0, a2 = 0, a3 = 0;
    int d = 0;
    int j = b;
    for (; j + 2 <= e; j += 2) {
        int c0 = __builtin_nontemporal_load(csr + j);
        int c1 = __builtin_nontemporal_load(csr + j + 1);
        int s0 = map[c0], s1 = map[c1];
        if (s0 >= 0) {
            ushort4 u = *(const ushort4*)(IN + (size_t)s0 * 256 + 128 + lane * 4);
            a0 += b2f(u.x); a1 += b2f(u.y); a2 += b2f(u.z); a3 += b2f(u.w);
            d++;
        }
        if (s1 >= 0) {
            ushort4 u = *(const ushort4*)(IN + (size_t)s1 * 256 + 128 + lane * 4);
            a0 += b2f(u.x); a1 += b2f(u.y); a2 += b2f(u.z); a3 += b2f(u.w);
            d++;
        }
    }
    if (j < e) {
        int c0 = __builtin_nontemporal_load(csr + j);
        int s0 = map[c0];
        if (s0 >= 0) {
            ushort4 u = *(const ushort4*)(IN + (size_t)s0 * 256 + 128 + lane * 4);
            a0 += b2f(u.x); a1 += b2f(u.y); a2 += b2f(u.z); a3 += b2f(u.w);
            d++;
        }
    }
    float rd = 1.0f / fmaxf((float)d, 1.0f);
    ushort4 out;
    out.x = f2b(a0 * rd); out.y = f2b(a1 * rd); out.z = f2b(a2 * rd); out.w = f2b(a3 * rd);
    *(ushort4*)(IN + (size_t)i * 256 + lane * 4) = out;
}

// MFMA SAGE + fused scores (m89-verified fragment mapping)
__global__ __launch_bounds__(256) void k_sage_b(
    const unsigned short* __restrict__ IN, const unsigned short* __restrict__ Wcat,
    const float* __restrict__ bias, const float* __restrict__ poolw,
    const float* __restrict__ normv,
    unsigned short* __restrict__ hb, float* __restrict__ sc,
    unsigned* __restrict__ key, int n, int relu) {
    __shared__ float lds[64][132];
    int tid = threadIdx.x;
    int wid = tid >> 6, lane = tid & 63;
    int q = lane >> 4, l15 = lane & 15;
    int rowbase = blockIdx.x * 64 + wid * 16;

    floatx4 acc[8];
#pragma unroll
    for (int c = 0; c < 8; c++) acc[c] = (floatx4){0.f, 0.f, 0.f, 0.f};

    const unsigned short* abase = IN + (size_t)(rowbase + l15) * 256 + q * 8;
    const unsigned short* bbase = Wcat + (size_t)l15 * 256 + q * 8;
#pragma unroll
    for (int ks = 0; ks < 8; ks++) {
        short8 a = *(const short8*)(abase + (ks << 5));
#pragma unroll
        for (int c = 0; c < 8; c++) {
            short8 b = *(const short8*)(bbase + (c << 12) + (ks << 5));
            acc[c] = __builtin_amdgcn_mfma_f32_16x16x32_bf16(a, b, acc[c], 0, 0, 0);
        }
    }

    float p0 = 0, p1 = 0, p2 = 0, p3 = 0;
#pragma unroll
    for (int c = 0; c < 8; c++) {
        int col = (c << 4) + l15;
        float bv = bias[col];
        float wv = poolw[col];
        floatx4 v = acc[c];
        v[0] += bv; v[1] += bv; v[2] += bv; v[3] += bv;
        if (relu) {
            v[0] = fmaxf(v[0], 0.f); v[1] = fmaxf(v[1], 0.f);
            v[2] = fmaxf(v[2], 0.f); v[3] = fmaxf(v[3], 0.f);
        }
        p0 += v[0] * wv; p1 += v[1] * wv; p2 += v[2] * wv; p3 += v[3] * wv;
        int lr = wid * 16 + q * 4;
        lds[lr + 0][col] = v[0];
        lds[lr + 1][col] = v[1];
        lds[lr + 2][col] = v[2];
        lds[lr + 3][col] = v[3];
    }
#pragma unroll
    for (int off = 1; off < 16; off <<= 1) {
        p0 += __shfl_xor(p0, off);
        p1 += __shfl_xor(p1, off);
        p2 += __shfl_xor(p2, off);
        p3 += __shfl_xor(p3, off);
    }
    if (l15 == 0) {
        float invn = 1.0f / (*normv);
        int r0 = rowbase + q * 4;
        float ps[4] = {p0, p1, p2, p3};
#pragma unroll
        for (int j = 0; j < 4; j++) {
            int r = r0 + j;
            if (r < n) {
                float s = tanhf(ps[j] * invn);
                sc[r] = s;
                key[r] = f2key(s);
            }
        }
    }
    __syncthreads();
#pragma unroll
    for (int it = 0; it < 4; it++) {
        int task = it * 256 + tid;
        int r = task >> 4, grp = task & 15;
        int gr = blockIdx.x * 64 + r;
        if (gr < n) {
            float4 lo = *(const float4*)&lds[r][grp * 8];
            float4 hi = *(const float4*)&lds[r][grp * 8 + 4];
            short8 u;
            u[0] = (short)f2b(lo.x); u[1] = (short)f2b(lo.y);
            u[2] = (short)f2b(lo.z); u[3] = (short)f2b(lo.w);
            u[4] = (short)f2b(hi.x); u[5] = (short)f2b(hi.y);
            u[6] = (short)f2b(hi.z); u[7] = (short)f2b(hi.w);
            *(short8*)(hb + (size_t)gr * 128 + grp * 8) = u;
        }
    }
}

// merged per-graph top-k: radix select then deterministic compaction
__global__ __launch_bounds__(1024) void k_topk(
    const unsigned* __restrict__ keys, const float* __restrict__ sc,
    int n_per, int k,
    int* __restrict__ node_map, int* __restrict__ sel_old, float* __restrict__ vals) {
    int g = blockIdx.x, tid = threadIdx.x;
    int lane = tid & 63, wid = tid >> 6;      // 16 waves
    const unsigned* kk = keys + (size_t)g * n_per;
    const float* ss = sc + (size_t)g * n_per;
    __shared__ int hist[256];
    __shared__ int suf[256];
    __shared__ unsigned sprefix;
    __shared__ int sr, sfound;
    __shared__ int we2[16], ws2[16];
    __shared__ int carry_pos, carry_eq;
    if (tid == 0) { sprefix = 0; sr = k; carry_pos = 0; carry_eq = 0; }
    __syncthreads();

    for (int b = 3; b >= 0; b--) {
        if (tid < 256) hist[tid] = 0;
        __syncthreads();
        unsigned pfx = sprefix;
        unsigned maskhi = (b == 3) ? 0u : (0xFFFFFFFFu << ((b + 1) * 8));
        for (int i = tid * 4; i < n_per; i += 4096) {
            uint4 kv4 = *(const uint4*)(kk + i);
#pragma unroll
            for (int j = 0; j < 4; j++) {
                unsigned kv = (j == 0) ? kv4.x : (j == 1) ? kv4.y : (j == 2) ? kv4.z : kv4.w;
                if ((kv & maskhi) == (pfx & maskhi))
                    atomicAdd(&hist[(kv >> (b * 8)) & 255], 1);
            }
        }
        __syncthreads();
        if (tid < 256) suf[tid] = hist[tid];
        __syncthreads();
        for (int off = 1; off < 256; off <<= 1) {
            int t = 0;
            if (tid < 256) t = suf[tid] + ((tid + off < 256) ? suf[tid + off] : 0);
            __syncthreads();
            if (tid < 256) suf[tid] = t;
            __syncthreads();
        }
        int r = sr;
        if (tid < 256) {
            int hi = (tid == 255) ? 0 : suf[tid + 1];
            if (hi < r && suf[tid] >= r) sfound = tid;   // unique
        }
        __syncthreads();
        if (tid == 0) {
            int v = sfound;
            int hi = (v == 255) ? 0 : suf[v + 1];
            sr = r - hi;
            sprefix = pfx | ((unsigned)v << (b * 8));
        }
        __syncthreads();
    }
    unsigned K = sprefix;
    int need = sr;
    __syncthreads();

    int nch = (n_per + 1023) >> 10;
    for (int ch = 0; ch < nch; ch++) {
        int i = (ch << 10) + tid;
        int valid = (i < n_per);
        unsigned kv = valid ? kk[i] : 0u;
        int is_gt = valid && (kv > K);
        int is_eq = valid && (kv == K);
        int e_incl = is_eq;
#pragma unroll
        for (int off = 1; off < 64; off <<= 1) {
            int t = __shfl_up(e_incl, off);
            e_incl += (lane >= off) ? t : 0;
        }
        if (lane == 63) we2[wid] = e_incl;
        __syncthreads();
        if (tid < 16) {
            int v = we2[tid];
#pragma unroll
            for (int off = 1; off < 16; off <<= 1) {
                int t = __shfl_up(v, off);
                v += ((int)tid >= off) ? t : 0;
            }
            we2[tid] = v;
        }
        __syncthreads();
        int eq_before = carry_eq + (e_incl - is_eq) + (wid ? we2[wid - 1] : 0);
        int sel = is_gt || (is_eq && eq_before < need);
        int s_incl = sel;
#pragma unroll
        for (int off = 1; off < 64; off <<= 1) {
            int t = __shfl_up(s_incl, off);
            s_incl += (lane >= off) ? t : 0;
        }
        if (lane == 63) ws2[wid] = s_incl;
        __syncthreads();
        if (tid < 16) {
            int v = ws2[tid];
#pragma unroll
            for (int off = 1; off < 16; off <<= 1) {
                int t = __shfl_up(v, off);
                v += ((int)tid >= off) ? t : 0;
            }
            ws2[tid] = v;
        }
        __syncthreads();
        int pos = carry_pos + (s_incl - sel) + (wid ? ws2[wid - 1] : 0);
        if (valid) {
            if (sel) {
                int ni = g * k + pos;
                node_map[(size_t)g * n_per + i] = ni;
                sel_old[ni] = g * n_per + i;
                vals[ni] = ss[i];
            } else {
                node_map[(size_t)g * n_per + i] = -1;
            }
        }
        __syncthreads();
        if (tid == 0) { carry_pos += ws2[15]; carry_eq += we2[15]; }
        __syncthreads();
    }
}

// gather selected h rows, scale by score, write bf16 into next IN x-half
__global__ void k_gatherb(const unsigned short* __restrict__ hb,
                          const int* __restrict__ sel_old,
                          const float* __restrict__ vals,
                          unsigned short* __restrict__ INnext, int m) {
    long t = blockIdx.x * (long)blockDim.x + threadIdx.x;
    int i = (int)(t >> 5), lane = (int)(t & 31);
    if (i >= m) return;
    int oi = sel_old[i];
    float v = vals[i];
    ushort4 u = *(const ushort4*)(hb + (size_t)oi * 128 + lane * 4);
    ushort4 o;
    o.x = f2b(b2f(u.x) * v); o.y = f2b(b2f(u.y) * v);
    o.z = f2b(b2f(u.z) * v); o.w = f2b(b2f(u.w) * v);
    *(ushort4*)(INnext + (size_t)i * 256 + 128 + lane * 4) = o;
}

// summarize partials: B*PSPLIT wave-blocks, lane = 2 features (ushort2)
__global__ __launch_bounds__(64) void k_partial2(const unsigned short* __restrict__ IN,
                                                 int k, float* __restrict__ part) {
    int g = blockIdx.x >> 8, s = blockIdx.x & (PSPLIT - 1);
    int lane = threadIdx.x;               // 64 lanes x ushort2 = 128 feats
    int rows = (k + PSPLIT - 1) / PSPLIT;
    int r0 = s * rows, r1 = min(k, r0 + rows);
    float s0 = 0, s1 = 0, m0 = -INFINITY, m1 = -INFINITY;
    for (int r = r0; r < r1; r++) {
        ushort2 u = *(const ushort2*)(IN + (size_t)(g * k + r) * 256 + 128 + lane * 2);
        float v0 = b2f(u.x), v1 = b2f(u.y);
        s0 += v0; s1 += v1;
        m0 = fmaxf(m0, v0); m1 = fmaxf(m1, v1);
    }
    size_t base = ((size_t)(g * PSPLIT + s) * 2) * F;
    *(float2*)&part[base + lane * 2] = make_float2(s0, s1);
    *(float2*)&part[base + F + lane * 2] = make_float2(m0, m1);
}

__global__ __launch_bounds__(256) void k_sumreduce2(const float* __restrict__ part, int k,
                                                    float* __restrict__ summary, int accum) {
    int g = blockIdx.x;
    int half = threadIdx.x >> 7, f = threadIdx.x & 127;  // 0=sum 1=max
    float sum = 0.0f, mx = -INFINITY;
    for (int s = 0; s < PSPLIT; s++) {
        float v = part[((size_t)(g * PSPLIT + s) * 2 + half) * F + f];
        sum += v;
        mx = fmaxf(mx, v);
    }
    float res = half ? mx : (sum / (float)k);
    int idx = g * 2 * F + half * F + f;
    if (accum) summary[idx] += res; else summary[idx] = res;
}

__global__ void k_out(const float* __restrict__ summary, const float* __restrict__ W,
                      const float* __restrict__ bias, float* __restrict__ out) {
    int g = blockIdx.x, j = threadIdx.x;  // 8 blocks x 64 threads
    float acc = bias[j];
    for (int t = 0; t < 2 * F; t++) acc += summary[g * 2 * F + t] * W[j * 2 * F + t];
    out[g * OUTD + j] = acc;
}

// ---------------- host launch ----------------
static inline int cdiv(long a, long b) { return (int)((a + b - 1) / b); }

extern "C" void kernel_launch(void* const* d_in, const int* in_sizes, int n_in,
                              void* d_out, int out_size, void* d_ws, size_t ws_size,
                              hipStream_t stream) {
    const float* x_in = (const float*)d_in[0];
    const int* ei     = (const int*)d_in[1];    // [2, E] -> src = ei, dst = ei+E
    const float* w1lW = (const float*)d_in[2];
    const float* w1lb = (const float*)d_in[3];
    const float* w1rW = (const float*)d_in[4];
    const float* p1w  = (const float*)d_in[5];
    const float* w2lW = (const float*)d_in[6];
    const float* w2lb = (const float*)d_in[7];
    const float* w2rW = (const float*)d_in[8];
    const float* p2w  = (const float*)d_in[9];
    const float* w3lW = (const float*)d_in[10];
    const float* w3lb = (const float*)d_in[11];
    const float* w3rW = (const float*)d_in[12];
    const float* p3w  = (const float*)d_in[13];
    const float* outW = (const float*)d_in[14];
    const float* outb = (const float*)d_in[15];
    float* out = (float*)d_out;

    float* ws = (float*)d_ws;
    unsigned short* INb  = (unsigned short*)(ws + OFF_IN);
    unsigned short* hb   = (unsigned short*)(ws + OFF_HB);
    float* sc    = ws + OFF_SC;
    unsigned* key = (unsigned*)(ws + OFF_KEY);
    int* nmap1   = (int*)(ws + OFF_MAP);
    int* nmap2   = (int*)(ws + OFF_MAP2);
    int* selo1   = (int*)(ws + OFF_SEL1);
    int* selo2   = (int*)(ws + OFF_SEL2);
    int* selo3   = (int*)(ws + OFF_SEL3);
    int* soc     = (int*)(ws + OFF_SOC);
    float* vals  = ws + OFF_VAL;
    int* csr     = (int*)(ws + OFF_CSR);
    int* hist    = (int*)(ws + OFF_HIST);
    int* incl    = (int*)(ws + OFF_INCL);
    int* bsum    = (int*)(ws + OFF_BSUM);
    int* rs      = (int*)(ws + OFF_RS);
    int* cur     = (int*)(ws + OFF_CUR);
    float* part    = ws + OFF_PART;
    float* summary = ws + OFF_SUM;
    unsigned short* wcat = (unsigned short*)(ws + OFF_WCAT);
    int* misc_i  = (int*)(ws + OFF_MISC);
    float* normv = (float*)(misc_i + 20);

    const int* esrc = ei;
    const int* edst = ei + E;

    // ================= stage 1 =================
    {
        int n = N0, nb = cdiv(n, 256);
        k_prep3<<<97, 256, 0, stream>>>(w1lW, w1rW, w2lW, w2rW, w3lW, w3rW,
                                        p1w, p2w, p3w, wcat, normv);
        k_cvt<<<cdiv((long)n * 32, 256), 256, 0, stream>>>(x_in, INb, n);
        hipMemsetAsync(hist, 0, (size_t)N0 * sizeof(int), stream);
        k_hist8<<<NSH * BPS, 256, 0, stream>>>(edst, hist);
        k_scan1<<<nb, 256, 0, stream>>>(hist, n, incl, bsum);
        k_scan2<<<1, 512, 0, stream>>>(bsum, nb);
        k_scan3<<<nb, 256, 0, stream>>>(hist, incl, bsum, n, rs, cur);
        k_csr8<<<NSH * BPS, 256, 0, stream>>>(esrc, edst, cur, csr);
        k_agg2b<<<8 * cdiv(NPG, 8), 256, 0, stream>>>(INb, rs, csr, NPG);
        k_sage_b<<<cdiv(n, 64), 256, 0, stream>>>(INb, wcat, w1lb, p1w, normv, hb, sc, key, n, 0);
        k_topk<<<B, 1024, 0, stream>>>(key, sc, NPG, K1, nmap1, selo1, vals);
        k_gatherb<<<cdiv((long)N1 * 32, 256), 256, 0, stream>>>(hb, selo1, vals, INb, N1);
        k_partial2<<<B * PSPLIT, 64, 0, stream>>>(INb, K1, part);
        k_sumreduce2<<<B, 256, 0, stream>>>(part, K1, summary, 0);
    }

    // ================= stage 2 (stage-1 CSR + nmap1 predicate) =================
    {
        int n = N1;
        k_agg2m<<<8 * cdiv(K1, 8), 256, 0, stream>>>(INb, rs, csr, nmap1, selo1, K1);
        k_sage_b<<<cdiv(n, 64), 256, 0, stream>>>(INb, wcat + 32768, w2lb, p2w, normv + 1,
                                                  hb, sc, key, n, 1);
        k_topk<<<B, 1024, 0, stream>>>(key, sc, K1, K2, nmap2, selo2, vals);
        k_gatherb<<<cdiv((long)N2 * 32, 256), 256, 0, stream>>>(hb, selo2, vals, INb, N2);
        k_partial2<<<B * PSPLIT, 64, 0, stream>>>(INb, K2, part);
        k_sumreduce2<<<B, 256, 0, stream>>>(part, K2, summary, 1);
        k_composechain<<<cdiv(N0, 256), 256, 0, stream>>>(nmap1, nmap2, selo2, selo1, soc, N0, N2);
    }

    // ================= stage 3 (stage-1 CSR + composed map) =================
    {
        int n = N2;
        k_agg2m<<<8 * cdiv(K2, 8), 256, 0, stream>>>(INb, rs, csr, nmap1, soc, K2);
        k_sage_b<<<cdiv(n, 64), 256, 0, stream>>>(INb, wcat + 65536, w3lb, p3w, normv + 2,
                                                  hb, sc, key, n, 0);
        k_topk<<<B, 1024, 0, stream>>>(key, sc, K2, K3, nmap2, selo3, vals);
        k_gatherb<<<cdiv((long)N3 * 32, 256), 256, 0, stream>>>(hb, selo3, vals, INb, N3);
        k_partial2<<<B * PSPLIT, 64, 0, stream>>>(INb, K3, part);
        k_sumreduce2<<<B, 256, 0, stream>>>(part, K3, summary, 1);
    }

    // ================= output =================
    k_out<<<B, OUTD, 0, stream>>>(summary, outW, outb, out);
}

// Round 8
// 419.888 us; speedup vs baseline: 9.6403x; 1.1313x over previous
//
#include <hip/hip_runtime.h>
#include <hip/hip_bf16.h>
#include <math.h>

// ---------------- problem constants ----------------
constexpr int B    = 8;
constexpr int NPG  = 10000;           // nodes per graph (stage 1)
constexpr int F    = 128;             // feature dim (F_IN == H == 128)
constexpr int OUTD = 64;
constexpr int E    = B * NPG * 16;    // 1,280,000 edges
constexpr int N0   = B * NPG;         // 80000
constexpr int K1   = 5000, K2 = 2500, K3 = 1250;
constexpr int N1   = B * K1;          // 40000
constexpr int N2   = B * K2;          // 20000
constexpr int N3   = B * K3;          // 10000
constexpr int PSPLIT = 256;           // summarize row-split (per graph)
constexpr int ESH  = E / 8;           // 160000 edges per graph (edge list graph-contiguous)
constexpr int KCH  = 8;               // chunks per graph for CSR build
constexpr int CH   = ESH / KCH;       // 20000 edges per chunk

// ---------------- ws layout (float units) ----------------
constexpr size_t OFF_IN   = 0;                           // [80000][256] bf16 (mean|x)
constexpr size_t SZ_IN    = (size_t)N0 * 256 / 2;
constexpr size_t OFF_HB   = OFF_IN + SZ_IN;              // h bf16 [80000][128]
constexpr size_t SZ_HB    = (size_t)N0 * F / 2;
constexpr size_t OFF_SC   = OFF_HB + SZ_HB;              // 80000 f32
constexpr size_t OFF_KEY  = OFF_SC + N0;                 // 80000 u32 (16B-aligned)
constexpr size_t OFF_MAP  = OFF_KEY + N0;                // 80000 i32 (nmap1 -> composed)
constexpr size_t OFF_MAP2 = OFF_MAP + N0;                // 40000 i32
constexpr size_t OFF_SEL1 = OFF_MAP2 + N1;               // 40000 i32 stage2->orig
constexpr size_t OFF_SEL2 = OFF_SEL1 + N1;               // 20000 i32 stage3->stage2
constexpr size_t OFF_SEL3 = OFF_SEL2 + N2;               // 10000 i32 final->stage3
constexpr size_t OFF_SOC  = OFF_SEL3 + N3;               // 20000 i32 stage3->orig
constexpr size_t OFF_VAL  = OFF_SOC + N2;                // 40000 f32
constexpr size_t OFF_CSR  = OFF_VAL + N1;                // E i32
constexpr size_t OFF_CNT  = OFF_CSR + E;                 // [64][NPG] i32 partial counts
constexpr size_t OFF_CUR0 = OFF_CNT + (size_t)64 * NPG;  // [64][NPG] i32 cursor bases
constexpr size_t OFF_HSUM = OFF_CUR0 + (size_t)64 * NPG; // N0 i32
constexpr size_t OFF_INCL = OFF_HSUM + N0;               // N0 i32
constexpr size_t OFF_BSUM = OFF_INCL + N0;               // 512 i32
constexpr size_t OFF_RS   = OFF_BSUM + 512;              // N0+1 i32 (+pad)
constexpr size_t OFF_PART = OFF_RS + N0 + 64;            // B*PSPLIT*2*128 f32
constexpr size_t OFF_SUM  = OFF_PART + (size_t)B * PSPLIT * 2 * F;
constexpr size_t OFF_WCAT = OFF_SUM + (size_t)B * 2 * F; // 3 x [128][256] bf16
constexpr size_t OFF_MISC = OFF_WCAT + 3 * 128 * 256 / 2;

typedef __attribute__((ext_vector_type(8))) short short8;
typedef __attribute__((ext_vector_type(4))) float floatx4;

// ---------------- helpers ----------------
__device__ inline unsigned f2key(float f) {
    unsigned u = __float_as_uint(f);
    return (u & 0x80000000u) ? ~u : (u | 0x80000000u);
}
__device__ inline unsigned short f2b(float f) {      // RNE f32->bf16
    unsigned u = __float_as_uint(f);
    return (unsigned short)((u + 0x7FFFu + ((u >> 16) & 1u)) >> 16);
}
__device__ inline float b2f(unsigned short u) {
    return __uint_as_float((unsigned)u << 16);
}

// ---------------- kernels ----------------
// all 3 stages' Wcat (bf16 concat) + pool-w norms in one launch
__global__ void k_prep3(const float* __restrict__ Wl1, const float* __restrict__ Wr1,
                        const float* __restrict__ Wl2, const float* __restrict__ Wr2,
                        const float* __restrict__ Wl3, const float* __restrict__ Wr3,
                        const float* __restrict__ p1, const float* __restrict__ p2,
                        const float* __restrict__ p3,
                        unsigned short* __restrict__ wcat, float* __restrict__ normv) {
    int b = blockIdx.x;
    if (b == 96) {
        int t = threadIdx.x;
        int which = t >> 6, lane = t & 63;
        if (which < 3) {
            const float* pw = (which == 0) ? p1 : (which == 1) ? p2 : p3;
            float v = 0.0f;
            for (int j = lane; j < F; j += 64) { float a = pw[j]; v += a * a; }
            for (int o = 32; o > 0; o >>= 1) v += __shfl_down(v, o);
            if (lane == 0) normv[which] = sqrtf(v);
        }
        return;
    }
    int stage = b >> 5;
    const float* Wl = (stage == 0) ? Wl1 : (stage == 1) ? Wl2 : Wl3;
    const float* Wr = (stage == 0) ? Wr1 : (stage == 1) ? Wr2 : Wr3;
    unsigned short* W = wcat + (size_t)stage * 128 * 256;
    int idx = ((b & 31) * 256 + threadIdx.x) * 4;
    int o = idx >> 8, k = idx & 255;
    const float* p = (k < 128) ? (Wl + o * 128 + k) : (Wr + o * 128 + (k - 128));
    float4 v = *(const float4*)p;
    ushort4 u;
    u.x = f2b(v.x); u.y = f2b(v.y); u.z = f2b(v.z); u.w = f2b(v.w);
    *(ushort4*)(W + idx) = u;
}

// x f32 -> bf16 into IN slab x-half
__global__ void k_cvt(const float* __restrict__ x, unsigned short* __restrict__ IN, int n) {
    long t = blockIdx.x * (long)blockDim.x + threadIdx.x;
    int i = (int)(t >> 5), lane = (int)(t & 31);
    if (i >= n) return;
    float4 v = ((const float4*)(x + (size_t)i * F))[lane];
    ushort4 u;
    u.x = f2b(v.x); u.y = f2b(v.y); u.z = f2b(v.z); u.w = f2b(v.w);
    *(ushort4*)(IN + (size_t)i * 256 + 128 + lane * 4) = u;
}

// -------- atomic-free CSR build (stage 1) --------
// 64 blocks: graph g = b&7 (XCD-local), chunk k = b>>3. LDS hist per block;
// the ONLY atomics are LDS-scope. No global RMW -> no fabric write traffic.
__global__ __launch_bounds__(1024) void k_hist_p(const int* __restrict__ dst,
                                                 int* __restrict__ cnt) {
    __shared__ int h[NPG];
    int b = blockIdx.x, g = b & 7, k = b >> 3;
    for (int i = threadIdx.x; i < NPG; i += 1024) h[i] = 0;
    __syncthreads();
    int base = g * ESH + k * CH;
    for (int i = threadIdx.x; i < CH; i += 1024) {
        int d = __builtin_nontemporal_load(dst + base + i) - g * NPG;
        atomicAdd(&h[d], 1);                        // LDS atomic
    }
    __syncthreads();
    int* o = cnt + (size_t)(g * KCH + k) * NPG;
    for (int i = threadIdx.x; i < NPG; i += 1024) o[i] = h[i];
}

// hsum[i] = total degree of node i (sum over chunks)
__global__ void k_sumcnt(const int* __restrict__ cnt, int* __restrict__ hsum) {
    int i = blockIdx.x * blockDim.x + threadIdx.x;
    if (i >= N0) return;
    int g = i / NPG, l = i - g * NPG;
    const int* c = cnt + (size_t)g * KCH * NPG + l;
    int t = 0;
#pragma unroll
    for (int k = 0; k < KCH; k++) t += c[(size_t)k * NPG];
    hsum[i] = t;
}

__global__ __launch_bounds__(256) void k_scan1(const int* __restrict__ in, int n,
                                               int* __restrict__ incl, int* __restrict__ bsum) {
    __shared__ int s[256];
    int i = blockIdx.x * 256 + threadIdx.x;
    int v = (i < n) ? in[i] : 0;
    s[threadIdx.x] = v;
    __syncthreads();
    for (int off = 1; off < 256; off <<= 1) {
        int t = s[threadIdx.x] + ((threadIdx.x >= off) ? s[threadIdx.x - off] : 0);
        __syncthreads();
        s[threadIdx.x] = t;
        __syncthreads();
    }
    if (i < n) incl[i] = s[threadIdx.x];
    if (threadIdx.x == 255) bsum[blockIdx.x] = s[255];
}

__global__ __launch_bounds__(512) void k_scan2(int* __restrict__ bsum, int nb) {
    __shared__ int s[512];
    int t = threadIdx.x;
    int v = (t < nb) ? bsum[t] : 0;
    s[t] = v;
    __syncthreads();
    for (int off = 1; off < 512; off <<= 1) {
        int u = s[t] + ((t >= off) ? s[t - off] : 0);
        __syncthreads();
        s[t] = u;
        __syncthreads();
    }
    if (t < nb) bsum[t] = s[t] - v;   // exclusive
}

// rowstart + per-chunk cursor bases (prefix over chunks within each node)
__global__ void k_scan3c(const int* __restrict__ in, const int* __restrict__ incl,
                         const int* __restrict__ bsum, const int* __restrict__ cnt,
                         int* __restrict__ rowstart, int* __restrict__ cur0) {
    int i = blockIdx.x * 256 + threadIdx.x;
    if (i >= N0) return;
    int ex = incl[i] - in[i] + bsum[blockIdx.x];
    rowstart[i] = ex;
    if (i == N0 - 1) rowstart[N0] = ex + in[i];
    int g = i / NPG, l = i - g * NPG;
    const int* c = cnt + (size_t)g * KCH * NPG + l;
    int* u = cur0 + (size_t)g * KCH * NPG + l;
    int run = ex;
#pragma unroll
    for (int k = 0; k < KCH; k++) {
        u[(size_t)k * NPG] = run;
        run += c[(size_t)k * NPG];
    }
}

// scatter src ids into csr using LDS cursors (no global atomics)
__global__ __launch_bounds__(1024) void k_csr_p(const int* __restrict__ src,
                                                const int* __restrict__ dst,
                                                const int* __restrict__ cur0,
                                                int* __restrict__ csr) {
    __shared__ int h[NPG];
    int b = blockIdx.x, g = b & 7, k = b >> 3;
    const int* u = cur0 + (size_t)(g * KCH + k) * NPG;
    for (int i = threadIdx.x; i < NPG; i += 1024) h[i] = u[i];
    __syncthreads();
    int base = g * ESH + k * CH;
    for (int i = threadIdx.x; i < CH; i += 1024) {
        int d = __builtin_nontemporal_load(dst + base + i) - g * NPG;
        int s = __builtin_nontemporal_load(src + base + i);
        int p = atomicAdd(&h[d], 1);                // LDS atomic
        csr[p] = s;
    }
}

// fused: compose orig->stage3 map; chain stage3->orig selection
__global__ void k_composechain(int* __restrict__ m1, const int* __restrict__ m2,
                               const int* __restrict__ s2, const int* __restrict__ s1,
                               int* __restrict__ soc, int n1, int n2) {
    int i = blockIdx.x * blockDim.x + threadIdx.x;
    if (i < n2) soc[i] = s1[s2[i]];
    if (i < n1) { int a = m1[i]; m1[i] = (a >= 0) ? m2[a] : -1; }
}

// stage-1 gather-aggregate bf16, graph->XCD swizzled (blockIdx&7 == graph)
__global__ __launch_bounds__(256) void k_agg2b(unsigned short* __restrict__ IN,
                                               const int* __restrict__ rowstart,
                                               const int* __restrict__ csr, int npg) {
    int g = blockIdx.x & 7;
    int local = (blockIdx.x >> 3) * 8 + (threadIdx.x >> 5);
    int lane = threadIdx.x & 31;
    if (local >= npg) return;
    int i = g * npg + local;
    int b = rowstart[i], e = rowstart[i + 1];
    float a0 = 0, a1 = 0, a2 = 0, a3 = 0;
    int j = b;
    for (; j + 4 <= e; j += 4) {      // 4-way MLP
        int s0 = __builtin_nontemporal_load(csr + j);
        int s1 = __builtin_nontemporal_load(csr + j + 1);
        int s2 = __builtin_nontemporal_load(csr + j + 2);
        int s3 = __builtin_nontemporal_load(csr + j + 3);
        ushort4 u0 = *(const ushort4*)(IN + (size_t)s0 * 256 + 128 + lane * 4);
        ushort4 u1 = *(const ushort4*)(IN + (size_t)s1 * 256 + 128 + lane * 4);
        ushort4 u2 = *(const ushort4*)(IN + (size_t)s2 * 256 + 128 + lane * 4);
        ushort4 u3 = *(const ushort4*)(IN + (size_t)s3 * 256 + 128 + lane * 4);
        a0 += (b2f(u0.x) + b2f(u1.x)) + (b2f(u2.x) + b2f(u3.x));
        a1 += (b2f(u0.y) + b2f(u1.y)) + (b2f(u2.y) + b2f(u3.y));
        a2 += (b2f(u0.z) + b2f(u1.z)) + (b2f(u2.z) + b2f(u3.z));
        a3 += (b2f(u0.w) + b2f(u1.w)) + (b2f(u2.w) + b2f(u3.w));
    }
    for (; j < e; j++) {
        int s0 = __builtin_nontemporal_load(csr + j);
        ushort4 u0 = *(const ushort4*)(IN + (size_t)s0 * 256 + 128 + lane * 4);
        a0 += b2f(u0.x); a1 += b2f(u0.y); a2 += b2f(u0.z); a3 += b2f(u0.w);
    }
    float rd = 1.0f / fmaxf((float)(e - b), 1.0f);
    ushort4 o;
    o.x = f2b(a0 * rd); o.y = f2b(a1 * rd); o.z = f2b(a2 * rd); o.w = f2b(a3 * rd);
    *(ushort4*)(IN + (size_t)i * 256 + lane * 4) = o;
}

// stages 2-3: pull over ORIGINAL neighbors of orig(i), predicated on map
__global__ __launch_bounds__(256) void k_agg2m(unsigned short* __restrict__ IN,
                                               const int* __restrict__ rowstart,
                                               const int* __restrict__ csr,
                                               const int* __restrict__ map,
                                               const int* __restrict__ orig_of, int npg) {
    int g = blockIdx.x & 7;
    int local = (blockIdx.x >> 3) * 8 + (threadIdx.x >> 5);
    int lane = threadIdx.x & 31;
    if (local >= npg) return;
    int i = g * npg + local;
    int o = orig_of[i];
    int b = rowstart[o], e = rowstart[o + 1];
    float a0 = 0, a1 = 0, a2 = 0, a3 = 0;
    int d = 0;
    int j = b;
    for (; j + 2 <= e; j += 2) {
        int c0 = __builtin_nontemporal_load(csr + j);
        int c1 = __builtin_nontemporal_load(csr + j + 1);
        int s0 = map[c0], s1 = map[c1];
        if (s0 >= 0) {
            ushort4 u = *(const ushort4*)(IN + (size_t)s0 * 256 + 128 + lane * 4);
            a0 += b2f(u.x); a1 += b2f(u.y); a2 += b2f(u.z); a3 += b2f(u.w);
            d++;
        }
        if (s1 >= 0) {
            ushort4 u = *(const ushort4*)(IN + (size_t)s1 * 256 + 128 + lane * 4);
            a0 += b2f(u.x); a1 += b2f(u.y); a2 += b2f(u.z); a3 += b2f(u.w);
            d++;
        }
    }
    if (j < e) {
        int c0 = __builtin_nontemporal_load(csr + j);
        int s0 = map[c0];
        if (s0 >= 0) {
            ushort4 u = *(const ushort4*)(IN + (size_t)s0 * 256 + 128 + lane * 4);
            a0 += b2f(u.x); a1 += b2f(u.y); a2 += b2f(u.z); a3 += b2f(u.w);
            d++;
        }
    }
    float rd = 1.0f / fmaxf((float)d, 1.0f);
    ushort4 out;
    out.x = f2b(a0 * rd); out.y = f2b(a1 * rd); out.z = f2b(a2 * rd); out.w = f2b(a3 * rd);
    *(ushort4*)(IN + (size_t)i * 256 + lane * 4) = out;
}

// MFMA SAGE + fused scores (m89-verified fragment mapping)
__global__ __launch_bounds__(256) void k_sage_b(
    const unsigned short* __restrict__ IN, const unsigned short* __restrict__ Wcat,
    const float* __restrict__ bias, const float* __restrict__ poolw,
    const float* __restrict__ normv,
    unsigned short* __restrict__ hb, float* __restrict__ sc,
    unsigned* __restrict__ key, int n, int relu) {
    __shared__ float lds[64][132];
    int tid = threadIdx.x;
    int wid = tid >> 6, lane = tid & 63;
    int q = lane >> 4, l15 = lane & 15;
    int rowbase = blockIdx.x * 64 + wid * 16;

    floatx4 acc[8];
#pragma unroll
    for (int c = 0; c < 8; c++) acc[c] = (floatx4){0.f, 0.f, 0.f, 0.f};

    const unsigned short* abase = IN + (size_t)(rowbase + l15) * 256 + q * 8;
    const unsigned short* bbase = Wcat + (size_t)l15 * 256 + q * 8;
#pragma unroll
    for (int ks = 0; ks < 8; ks++) {
        short8 a = *(const short8*)(abase + (ks << 5));
#pragma unroll
        for (int c = 0; c < 8; c++) {
            short8 b = *(const short8*)(bbase + (c << 12) + (ks << 5));
            acc[c] = __builtin_amdgcn_mfma_f32_16x16x32_bf16(a, b, acc[c], 0, 0, 0);
        }
    }

    float p0 = 0, p1 = 0, p2 = 0, p3 = 0;
#pragma unroll
    for (int c = 0; c < 8; c++) {
        int col = (c << 4) + l15;
        float bv = bias[col];
        float wv = poolw[col];
        floatx4 v = acc[c];
        v[0] += bv; v[1] += bv; v[2] += bv; v[3] += bv;
        if (relu) {
            v[0] = fmaxf(v[0], 0.f); v[1] = fmaxf(v[1], 0.f);
            v[2] = fmaxf(v[2], 0.f); v[3] = fmaxf(v[3], 0.f);
        }
        p0 += v[0] * wv; p1 += v[1] * wv; p2 += v[2] * wv; p3 += v[3] * wv;
        int lr = wid * 16 + q * 4;
        lds[lr + 0][col] = v[0];
        lds[lr + 1][col] = v[1];
        lds[lr + 2][col] = v[2];
        lds[lr + 3][col] = v[3];
    }
#pragma unroll
    for (int off = 1; off < 16; off <<= 1) {
        p0 += __shfl_xor(p0, off);
        p1 += __shfl_xor(p1, off);
        p2 += __shfl_xor(p2, off);
        p3 += __shfl_xor(p3, off);
    }
    if (l15 == 0) {
        float invn = 1.0f / (*normv);
        int r0 = rowbase + q * 4;
        float ps[4] = {p0, p1, p2, p3};
#pragma unroll
        for (int j = 0; j < 4; j++) {
            int r = r0 + j;
            if (r < n) {
                float s = tanhf(ps[j] * invn);
                sc[r] = s;
                key[r] = f2key(s);
            }
        }
    }
    __syncthreads();
#pragma unroll
    for (int it = 0; it < 4; it++) {
        int task = it * 256 + tid;
        int r = task >> 4, grp = task & 15;
        int gr = blockIdx.x * 64 + r;
        if (gr < n) {
            float4 lo = *(const float4*)&lds[r][grp * 8];
            float4 hi = *(const float4*)&lds[r][grp * 8 + 4];
            short8 u;
            u[0] = (short)f2b(lo.x); u[1] = (short)f2b(lo.y);
            u[2] = (short)f2b(lo.z); u[3] = (short)f2b(lo.w);
            u[4] = (short)f2b(hi.x); u[5] = (short)f2b(hi.y);
            u[6] = (short)f2b(hi.z); u[7] = (short)f2b(hi.w);
            *(short8*)(hb + (size_t)gr * 128 + grp * 8) = u;
        }
    }
}

// merged per-graph top-k: radix select then deterministic compaction
__global__ __launch_bounds__(1024) void k_topk(
    const unsigned* __restrict__ keys, const float* __restrict__ sc,
    int n_per, int k,
    int* __restrict__ node_map, int* __restrict__ sel_old, float* __restrict__ vals) {
    int g = blockIdx.x, tid = threadIdx.x;
    int lane = tid & 63, wid = tid >> 6;      // 16 waves
    const unsigned* kk = keys + (size_t)g * n_per;
    const float* ss = sc + (size_t)g * n_per;
    __shared__ int hist[256];
    __shared__ int suf[256];
    __shared__ unsigned sprefix;
    __shared__ int sr, sfound;
    __shared__ int we2[16], ws2[16];
    __shared__ int carry_pos, carry_eq;
    if (tid == 0) { sprefix = 0; sr = k; carry_pos = 0; carry_eq = 0; }
    __syncthreads();

    for (int b = 3; b >= 0; b--) {
        if (tid < 256) hist[tid] = 0;
        __syncthreads();
        unsigned pfx = sprefix;
        unsigned maskhi = (b == 3) ? 0u : (0xFFFFFFFFu << ((b + 1) * 8));
        for (int i = tid * 4; i < n_per; i += 4096) {
            uint4 kv4 = *(const uint4*)(kk + i);
#pragma unroll
            for (int j = 0; j < 4; j++) {
                unsigned kv = (j == 0) ? kv4.x : (j == 1) ? kv4.y : (j == 2) ? kv4.z : kv4.w;
                if ((kv & maskhi) == (pfx & maskhi))
                    atomicAdd(&hist[(kv >> (b * 8)) & 255], 1);
            }
        }
        __syncthreads();
        if (tid < 256) suf[tid] = hist[tid];
        __syncthreads();
        for (int off = 1; off < 256; off <<= 1) {
            int t = 0;
            if (tid < 256) t = suf[tid] + ((tid + off < 256) ? suf[tid + off] : 0);
            __syncthreads();
            if (tid < 256) suf[tid] = t;
            __syncthreads();
        }
        int r = sr;
        if (tid < 256) {
            int hi = (tid == 255) ? 0 : suf[tid + 1];
            if (hi < r && suf[tid] >= r) sfound = tid;   // unique
        }
        __syncthreads();
        if (tid == 0) {
            int v = sfound;
            int hi = (v == 255) ? 0 : suf[v + 1];
            sr = r - hi;
            sprefix = pfx | ((unsigned)v << (b * 8));
        }
        __syncthreads();
    }
    unsigned K = sprefix;
    int need = sr;
    __syncthreads();

    int nch = (n_per + 1023) >> 10;
    for (int ch = 0; ch < nch; ch++) {
        int i = (ch << 10) + tid;
        int valid = (i < n_per);
        unsigned kv = valid ? kk[i] : 0u;
        int is_gt = valid && (kv > K);
        int is_eq = valid && (kv == K);
        int e_incl = is_eq;
#pragma unroll
        for (int off = 1; off < 64; off <<= 1) {
            int t = __shfl_up(e_incl, off);
            e_incl += (lane >= off) ? t : 0;
        }
        if (lane == 63) we2[wid] = e_incl;
        __syncthreads();
        if (tid < 16) {
            int v = we2[tid];
#pragma unroll
            for (int off = 1; off < 16; off <<= 1) {
                int t = __shfl_up(v, off);
                v += ((int)tid >= off) ? t : 0;
            }
            we2[tid] = v;
        }
        __syncthreads();
        int eq_before = carry_eq + (e_incl - is_eq) + (wid ? we2[wid - 1] : 0);
        int sel = is_gt || (is_eq && eq_before < need);
        int s_incl = sel;
#pragma unroll
        for (int off = 1; off < 64; off <<= 1) {
            int t = __shfl_up(s_incl, off);
            s_incl += (lane >= off) ? t : 0;
        }
        if (lane == 63) ws2[wid] = s_incl;
        __syncthreads();
        if (tid < 16) {
            int v = ws2[tid];
#pragma unroll
            for (int off = 1; off < 16; off <<= 1) {
                int t = __shfl_up(v, off);
                v += ((int)tid >= off) ? t : 0;
            }
            ws2[tid] = v;
        }
        __syncthreads();
        int pos = carry_pos + (s_incl - sel) + (wid ? ws2[wid - 1] : 0);
        if (valid) {
            if (sel) {
                int ni = g * k + pos;
                node_map[(size_t)g * n_per + i] = ni;
                sel_old[ni] = g * n_per + i;
                vals[ni] = ss[i];
            } else {
                node_map[(size_t)g * n_per + i] = -1;
            }
        }
        __syncthreads();
        if (tid == 0) { carry_pos += ws2[15]; carry_eq += we2[15]; }
        __syncthreads();
    }
}

// gather selected h rows, scale by score, write bf16 into next IN x-half
__global__ void k_gatherb(const unsigned short* __restrict__ hb,
                          const int* __restrict__ sel_old,
                          const float* __restrict__ vals,
                          unsigned short* __restrict__ INnext, int m) {
    long t = blockIdx.x * (long)blockDim.x + threadIdx.x;
    int i = (int)(t >> 5), lane = (int)(t & 31);
    if (i >= m) return;
    int oi = sel_old[i];
    float v = vals[i];
    ushort4 u = *(const ushort4*)(hb + (size_t)oi * 128 + lane * 4);
    ushort4 o;
    o.x = f2b(b2f(u.x) * v); o.y = f2b(b2f(u.y) * v);
    o.z = f2b(b2f(u.z) * v); o.w = f2b(b2f(u.w) * v);
    *(ushort4*)(INnext + (size_t)i * 256 + 128 + lane * 4) = o;
}

// summarize partials: B*PSPLIT wave-blocks, lane = 2 features (ushort2)
__global__ __launch_bounds__(64) void k_partial2(const unsigned short* __restrict__ IN,
                                                 int k, float* __restrict__ part) {
    int g = blockIdx.x >> 8, s = blockIdx.x & (PSPLIT - 1);
    int lane = threadIdx.x;               // 64 lanes x ushort2 = 128 feats
    int rows = (k + PSPLIT - 1) / PSPLIT;
    int r0 = s * rows, r1 = min(k, r0 + rows);
    float s0 = 0, s1 = 0, m0 = -INFINITY, m1 = -INFINITY;
    for (int r = r0; r < r1; r++) {
        ushort2 u = *(const ushort2*)(IN + (size_t)(g * k + r) * 256 + 128 + lane * 2);
        float v0 = b2f(u.x), v1 = b2f(u.y);
        s0 += v0; s1 += v1;
        m0 = fmaxf(m0, v0); m1 = fmaxf(m1, v1);
    }
    size_t base = ((size_t)(g * PSPLIT + s) * 2) * F;
    *(float2*)&part[base + lane * 2] = make_float2(s0, s1);
    *(float2*)&part[base + F + lane * 2] = make_float2(m0, m1);
}

__global__ __launch_bounds__(256) void k_sumreduce2(const float* __restrict__ part, int k,
                                                    float* __restrict__ summary, int accum) {
    int g = blockIdx.x;
    int half = threadIdx.x >> 7, f = threadIdx.x & 127;  // 0=sum 1=max
    float sum = 0.0f, mx = -INFINITY;
    for (int s = 0; s < PSPLIT; s++) {
        float v = part[((size_t)(g * PSPLIT + s) * 2 + half) * F + f];
        sum += v;
        mx = fmaxf(mx, v);
    }
    float res = half ? mx : (sum / (float)k);
    int idx = g * 2 * F + half * F + f;
    if (accum) summary[idx] += res; else summary[idx] = res;
}

__global__ void k_out(const float* __restrict__ summary, const float* __restrict__ W,
                      const float* __restrict__ bias, float* __restrict__ out) {
    int g = blockIdx.x, j = threadIdx.x;  // 8 blocks x 64 threads
    float acc = bias[j];
    for (int t = 0; t < 2 * F; t++) acc += summary[g * 2 * F + t] * W[j * 2 * F + t];
    out[g * OUTD + j] = acc;
}

// ---------------- host launch ----------------
static inline int cdiv(long a, long b) { return (int)((a + b - 1) / b); }

extern "C" void kernel_launch(void* const* d_in, const int* in_sizes, int n_in,
                              void* d_out, int out_size, void* d_ws, size_t ws_size,
                              hipStream_t stream) {
    const float* x_in = (const float*)d_in[0];
    const int* ei     = (const int*)d_in[1];    // [2, E] -> src = ei, dst = ei+E
    const float* w1lW = (const float*)d_in[2];
    const float* w1lb = (const float*)d_in[3];
    const float* w1rW = (const float*)d_in[4];
    const float* p1w  = (const float*)d_in[5];
    const float* w2lW = (const float*)d_in[6];
    const float* w2lb = (const float*)d_in[7];
    const float* w2rW = (const float*)d_in[8];
    const float* p2w  = (const float*)d_in[9];
    const float* w3lW = (const float*)d_in[10];
    const float* w3lb = (const float*)d_in[11];
    const float* w3rW = (const float*)d_in[12];
    const float* p3w  = (const float*)d_in[13];
    const float* outW = (const float*)d_in[14];
    const float* outb = (const float*)d_in[15];
    float* out = (float*)d_out;

    float* ws = (float*)d_ws;
    unsigned short* INb  = (unsigned short*)(ws + OFF_IN);
    unsigned short* hb   = (unsigned short*)(ws + OFF_HB);
    float* sc    = ws + OFF_SC;
    unsigned* key = (unsigned*)(ws + OFF_KEY);
    int* nmap1   = (int*)(ws + OFF_MAP);
    int* nmap2   = (int*)(ws + OFF_MAP2);
    int* selo1   = (int*)(ws + OFF_SEL1);
    int* selo2   = (int*)(ws + OFF_SEL2);
    int* selo3   = (int*)(ws + OFF_SEL3);
    int* soc     = (int*)(ws + OFF_SOC);
    float* vals  = ws + OFF_VAL;
    int* csr     = (int*)(ws + OFF_CSR);
    int* cnt     = (int*)(ws + OFF_CNT);
    int* cur0    = (int*)(ws + OFF_CUR0);
    int* hsum    = (int*)(ws + OFF_HSUM);
    int* incl    = (int*)(ws + OFF_INCL);
    int* bsum    = (int*)(ws + OFF_BSUM);
    int* rs      = (int*)(ws + OFF_RS);
    float* part    = ws + OFF_PART;
    float* summary = ws + OFF_SUM;
    unsigned short* wcat = (unsigned short*)(ws + OFF_WCAT);
    int* misc_i  = (int*)(ws + OFF_MISC);
    float* normv = (float*)(misc_i + 20);

    const int* esrc = ei;
    const int* edst = ei + E;

    // ================= stage 1 =================
    {
        int n = N0, nb = cdiv(n, 256);
        k_prep3<<<97, 256, 0, stream>>>(w1lW, w1rW, w2lW, w2rW, w3lW, w3rW,
                                        p1w, p2w, p3w, wcat, normv);
        k_cvt<<<cdiv((long)n * 32, 256), 256, 0, stream>>>(x_in, INb, n);
        k_hist_p<<<64, 1024, 0, stream>>>(edst, cnt);
        k_sumcnt<<<nb, 256, 0, stream>>>(cnt, hsum);
        k_scan1<<<nb, 256, 0, stream>>>(hsum, n, incl, bsum);
        k_scan2<<<1, 512, 0, stream>>>(bsum, nb);
        k_scan3c<<<nb, 256, 0, stream>>>(hsum, incl, bsum, cnt, rs, cur0);
        k_csr_p<<<64, 1024, 0, stream>>>(esrc, edst, cur0, csr);
        k_agg2b<<<8 * cdiv(NPG, 8), 256, 0, stream>>>(INb, rs, csr, NPG);
        k_sage_b<<<cdiv(n, 64), 256, 0, stream>>>(INb, wcat, w1lb, p1w, normv, hb, sc, key, n, 0);
        k_topk<<<B, 1024, 0, stream>>>(key, sc, NPG, K1, nmap1, selo1, vals);
        k_gatherb<<<cdiv((long)N1 * 32, 256), 256, 0, stream>>>(hb, selo1, vals, INb, N1);
        k_partial2<<<B * PSPLIT, 64, 0, stream>>>(INb, K1, part);
        k_sumreduce2<<<B, 256, 0, stream>>>(part, K1, summary, 0);
    }

    // ================= stage 2 (stage-1 CSR + nmap1 predicate) =================
    {
        int n = N1;
        k_agg2m<<<8 * cdiv(K1, 8), 256, 0, stream>>>(INb, rs, csr, nmap1, selo1, K1);
        k_sage_b<<<cdiv(n, 64), 256, 0, stream>>>(INb, wcat + 32768, w2lb, p2w, normv + 1,
                                                  hb, sc, key, n, 1);
        k_topk<<<B, 1024, 0, stream>>>(key, sc, K1, K2, nmap2, selo2, vals);
        k_gatherb<<<cdiv((long)N2 * 32, 256), 256, 0, stream>>>(hb, selo2, vals, INb, N2);
        k_partial2<<<B * PSPLIT, 64, 0, stream>>>(INb, K2, part);
        k_sumreduce2<<<B, 256, 0, stream>>>(part, K2, summary, 1);
        k_composechain<<<cdiv(N0, 256), 256, 0, stream>>>(nmap1, nmap2, selo2, selo1, soc, N0, N2);
    }

    // ================= stage 3 (stage-1 CSR + composed map) =================
    {
        int n = N2;
        k_agg2m<<<8 * cdiv(K2, 8), 256, 0, stream>>>(INb, rs, csr, nmap1, soc, K2);
        k_sage_b<<<cdiv(n, 64), 256, 0, stream>>>(INb, wcat + 65536, w3lb, p3w, normv + 2,
                                                  hb, sc, key, n, 0);
        k_topk<<<B, 1024, 0, stream>>>(key, sc, K2, K3, nmap2, selo3, vals);
        k_gatherb<<<cdiv((long)N3 * 32, 256), 256, 0, stream>>>(hb, selo3, vals, INb, N3);
        k_partial2<<<B * PSPLIT, 64, 0, stream>>>(INb, K3, part);
        k_sumreduce2<<<B, 256, 0, stream>>>(part, K3, summary, 1);
    }

    // ================= output =================
    k_out<<<B, OUTD, 0, stream>>>(summary, outW, outb, out);
}